// Round 3
// baseline (787.237 us; speedup 1.0000x reference)
//
#include <hip/hip_runtime.h>
#include <hip/hip_bf16.h>
#include <cstddef>

typedef __hip_bfloat16 bf16;
typedef __bf16 bfv8 __attribute__((ext_vector_type(8)));
typedef __bf16 bfv4 __attribute__((ext_vector_type(4)));
typedef float f4 __attribute__((ext_vector_type(4)));

#define EPSN 1e-5f
#define SQRT3_INV 0.57735026918962576f
#define SQRT2_INV 0.70710678118654752f

__device__ __forceinline__ float b2f(bf16 x) { return __bfloat162float(x); }

template<int BF> __device__ __forceinline__ float ldf(const void* p, size_t i) {
    if (BF) return __bfloat162float(((const bf16*)p)[i]);
    return ((const float*)p)[i];
}
__device__ __forceinline__ float ldr(const void* p, size_t i, int bfm) {
    return bfm ? __bfloat162float(((const bf16*)p)[i]) : ((const float*)p)[i];
}
template<int BF> __device__ __forceinline__ void stf(void* p, size_t i, float v) {
    if (BF) ((bf16*)p)[i] = __float2bfloat16(v);
    else    ((float*)p)[i] = v;
}

__device__ __forceinline__ float wave_sum64(float x) {
    #pragma unroll
    for (int m = 1; m < 64; m <<= 1) x += __shfl_xor(x, m, 64);
    return x;
}

__device__ __forceinline__ f4 mf(bfv8 a, bfv8 b, f4 c) {
    return __builtin_amdgcn_mfma_f32_16x16x32_bf16(a, b, c, 0, 0, 0);
}

// ---------------- Sniffer ----------------
__global__ __launch_bounds__(256) void k_sniff(const void* node, const void* eidx, int* flags)
{
    int t = threadIdx.x;
    __shared__ int cnt;
    __shared__ unsigned orr;
    if (t == 0) { cnt = 0; orr = 0u; }
    __syncthreads();
    unsigned w  = ((const unsigned*)node)[t];
    unsigned lo = w & 0xFFFFu;
    int e_lo = (int)((lo >> 7) & 0xFF);
    if (e_lo >= 96 && e_lo <= 140) atomicAdd(&cnt, 1);
    unsigned odd = ((const unsigned*)eidx)[2 * t + 1];
    atomicOr(&orr, odd);
    __syncthreads();
    if (t == 0) {
        flags[0] = (cnt >= 128) ? 1 : 0;   // 1 = bf16 inputs
        flags[1] = (orr == 0u) ? 1 : 0;    // 1 = int64 edge_index
    }
}

__global__ __launch_bounds__(256) void k_zero(float* p, int n)
{
    int i = blockIdx.x * 256 + threadIdx.x;
    if (i < n) p[i] = 0.f;
}

// ---------------- Counting sort by dst ----------------
__global__ __launch_bounds__(256) void k_hist(const void* eidx, int* cnt,
                                              const int* flags, int E)
{
    int e = blockIdx.x * 256 + threadIdx.x;
    if (e >= E) return;
    int d = flags[1] ? (int)((const long long*)eidx)[(long long)E + e]
                     : ((const int*)eidx)[(size_t)E + e];
    atomicAdd(&cnt[d], 1);
}

__global__ __launch_bounds__(1024) void k_scan(int* cnt, int N)
{
    __shared__ int wsum[16];
    int t = threadIdx.x;
    int lane = t & 63, w = t >> 6;
    int chunk = (N + 1023) >> 10;
    int lo = t * chunk, hi = lo + chunk;
    if (hi > N) hi = N; if (lo > N) lo = N;
    int sum = 0;
    for (int i = lo; i < hi; ++i) sum += cnt[i];
    int x = sum;
    #pragma unroll
    for (int off = 1; off < 64; off <<= 1) {
        int y = __shfl_up(x, off, 64);
        if (lane >= off) x += y;
    }
    if (lane == 63) wsum[w] = x;
    __syncthreads();
    if (t < 64) {
        int v = (lane < 16) ? wsum[lane] : 0;
        #pragma unroll
        for (int off = 1; off < 16; off <<= 1) {
            int y = __shfl_up(v, off, 64);
            if (lane >= off) v += y;
        }
        if (lane < 16) wsum[lane] = v;
    }
    __syncthreads();
    int acc = x - sum + (w ? wsum[w - 1] : 0);
    for (int i = lo; i < hi; ++i) { int v = cnt[i]; cnt[i] = acc; acc += v; }
}

__global__ __launch_bounds__(256) void k_perm(const void* eidx, int* cnt, int* perm,
                                              const int* flags, int E)
{
    int e = blockIdx.x * 256 + threadIdx.x;
    if (e >= E) return;
    int d = flags[1] ? (int)((const long long*)eidx)[(long long)E + e]
                     : ((const int*)eidx)[(size_t)E + e];
    int pos = atomicAdd(&cnt[d], 1);
    perm[pos] = e;
}

// ---------------- Prep: transpose weights to bf16 [n][k] ----------------
template<int BF>
__device__ __forceinline__ void prep_impl(
    const void* Walpha, const void* Wsval, const void* Wsvlin,
    const void* Wvval, const void* Wvvlin, const void* Wg,
    const void* Wrbf, const void* adot,
    const void* w2ss, const void* w2sv, const void* w2vs,
    const void* w2vv0, const void* w2vv1,
    bf16* WalphaT, bf16* WsvalT, bf16* WsvlinT,
    bf16* WvvalT, bf16* WvvlinT, bf16* WgT,
    bf16* WrbfT, bf16* adotB, bf16* w2B)
{
    int t = threadIdx.x + blockIdx.x * 256;
    int T = gridDim.x * 256;
    for (int i = t; i < 96 * 64; i += T) {
        int c = i >> 6, n = i & 63;
        WalphaT[n * 96 + c] = __float2bfloat16(ldf<BF>(Walpha, i));
        WsvalT [n * 96 + c] = __float2bfloat16(ldf<BF>(Wsval,  i));
        WsvlinT[n * 96 + c] = __float2bfloat16(ldf<BF>(Wsvlin, i));
    }
    for (int i = t; i < 128 * 32; i += T) {
        int c = i >> 5, n = i & 31;
        WvvalT [n * 128 + c] = __float2bfloat16(ldf<BF>(Wvval,  i));
        WvvlinT[n * 128 + c] = __float2bfloat16(ldf<BF>(Wvvlin, i));
    }
    for (int i = t; i < 64 * 32; i += T) {
        int c = i >> 5, n = i & 31;
        WgT[n * 64 + c] = __float2bfloat16(ldf<BF>(Wg, i));
    }
    for (int i = t; i < 224 * 32; i += T) {
        int c = i >> 5, b = i & 31;
        WrbfT[i] = __float2bfloat16(b < 16 ? ldf<BF>(Wrbf, b * 224 + c) : 0.f);
    }
    if (t < 64) adotB[t] = __float2bfloat16(ldf<BF>(adot, t));
    if (t < 64) w2B[t]      = __float2bfloat16(ldf<BF>(w2ss, t));
    if (t < 64) w2B[64 + t] = __float2bfloat16(ldf<BF>(w2sv, t));
    if (t < 32) {
        w2B[128 + t] = __float2bfloat16(ldf<BF>(w2vs, t));
        w2B[160 + t] = __float2bfloat16(ldf<BF>(w2vv0, t));
        w2B[192 + t] = __float2bfloat16(ldf<BF>(w2vv1, t));
    }
}

__global__ __launch_bounds__(256) void k_prep(
    const void* Walpha, const void* Wsval, const void* Wsvlin,
    const void* Wvval, const void* Wvvlin, const void* Wg,
    const void* Wrbf, const void* adot,
    const void* w2ss, const void* w2sv, const void* w2vs,
    const void* w2vv0, const void* w2vv1,
    bf16* WalphaT, bf16* WsvalT, bf16* WsvlinT,
    bf16* WvvalT, bf16* WvvlinT, bf16* WgT,
    bf16* WrbfT, bf16* adotB, bf16* w2B, const int* flags)
{
    if (flags[0])
        prep_impl<1>(Walpha, Wsval, Wsvlin, Wvval, Wvvlin, Wg, Wrbf, adot,
                     w2ss, w2sv, w2vs, w2vv0, w2vv1,
                     WalphaT, WsvalT, WsvlinT, WvvalT, WvvlinT, WgT, WrbfT, adotB, w2B);
    else
        prep_impl<0>(Walpha, Wsval, Wsvlin, Wvval, Wvvlin, Wg, Wrbf, adot,
                     w2ss, w2sv, w2vs, w2vv0, w2vv1,
                     WalphaT, WsvalT, WsvlinT, WvvalT, WvvlinT, WgT, WrbfT, adotB, w2B);
}

// ---------------- Kernel 1: per-node layernorm + projections (4 nodes/block) ----------------
// Outputs are stored SWIZZLED for vectorized gather in k_edge:
//   ssrc/sdst [n][64]: channel c at position (c&15)*4 + (c>>4)      (bfv4 per lane)
//   vsrc/vdst [n][128]: channel c at position (c&15)*8 + (c>>4)     (bfv8 per lane; slots 6,7 unused)
template<int BF>
__device__ __forceinline__ void node_impl(
    const void* node, const void* gs, const void* bs, const void* gv,
    const void* Wss, const void* Wvs, const void* Wsd, const void* Wvd,
    bf16* ssrc, bf16* sdst, bf16* vsrc, bf16* vdst,
    float* shs, float* shv, int n, int lane)
{
    size_t nb = (size_t)n * 160;

    float s  = ldf<BF>(node, nb + lane);
    float mu = wave_sum64(s) * (1.f / 64.f);
    float d  = s - mu;
    float var = wave_sum64(d * d) * (1.f / 64.f);
    float sn  = d * rsqrtf(var + EPSN) * ldf<BF>(gs, lane) + ldf<BF>(bs, lane);
    shs[lane] = sn;

    float v0 = 0.f, v1 = 0.f, v2 = 0.f, qq = 0.f;
    if (lane < 32) {
        v0 = ldf<BF>(node, nb + 64 + lane * 3 + 0);
        v1 = ldf<BF>(node, nb + 64 + lane * 3 + 1);
        v2 = ldf<BF>(node, nb + 64 + lane * 3 + 2);
        qq = v0 * v0 + v1 * v1 + v2 * v2;
    }
    float msq = wave_sum64(qq) * (1.f / 32.f);
    float inv = rsqrtf(msq + EPSN);
    if (lane < 32) {
        float g = ldf<BF>(gv, lane);
        shv[0 * 32 + lane] = v0 * inv * g;
        shv[1 * 32 + lane] = v1 * inv * g;
        shv[2 * 32 + lane] = v2 * inv * g;
    }
    // same-wave LDS write->read: in-order, no barrier needed

    float a1 = 0.f, a2 = 0.f;
    for (int c = 0; c < 64; ++c) {
        float sc = shs[c];
        a1 += sc * ldf<BF>(Wss, c * 64 + lane);
        a2 += sc * ldf<BF>(Wsd, c * 64 + lane);
    }
    {
        int cs = lane;
        int pos = (cs & 15) * 4 + (cs >> 4);
        ssrc[(size_t)n * 64 + pos] = __float2bfloat16(a1);
        sdst[(size_t)n * 64 + pos] = __float2bfloat16(a2);
    }

    {
        int x = lane >> 5, dd = lane & 31;
        float p1 = 0.f, p2 = 0.f;
        for (int c = 0; c < 32; ++c) {
            float vc = shv[x * 32 + c];
            p1 += vc * ldf<BF>(Wvs, c * 32 + dd);
            p2 += vc * ldf<BF>(Wvd, c * 32 + dd);
        }
        int cv = x * 32 + dd;
        int pos = (cv & 15) * 8 + (cv >> 4);
        vsrc[(size_t)n * 128 + pos] = __float2bfloat16(p1);
        vdst[(size_t)n * 128 + pos] = __float2bfloat16(p2);
    }
    if (lane < 32) {
        int dd = lane;
        float p1 = 0.f, p2 = 0.f;
        for (int c = 0; c < 32; ++c) {
            float vc = shv[2 * 32 + c];
            p1 += vc * ldf<BF>(Wvs, c * 32 + dd);
            p2 += vc * ldf<BF>(Wvd, c * 32 + dd);
        }
        int cv = 64 + dd;
        int pos = (cv & 15) * 8 + (cv >> 4);
        vsrc[(size_t)n * 128 + pos] = __float2bfloat16(p1);
        vdst[(size_t)n * 128 + pos] = __float2bfloat16(p2);
    }
}

__global__ __launch_bounds__(256) void k_node(
    const void* node, const void* gs, const void* bs, const void* gv,
    const void* Wss, const void* Wvs, const void* Wsd, const void* Wvd,
    bf16* ssrc, bf16* sdst, bf16* vsrc, bf16* vdst,
    const int* flags, int N)
{
    __shared__ float shs[4][64];
    __shared__ float shv[4][96];
    int wv = threadIdx.x >> 6, lane = threadIdx.x & 63;
    int n = blockIdx.x * 4 + wv; if (n >= N) return;
    if (flags[0])
        node_impl<1>(node, gs, bs, gv, Wss, Wvs, Wsd, Wvd, ssrc, sdst, vsrc, vdst,
                     shs[wv], shv[wv], n, lane);
    else
        node_impl<0>(node, gs, bs, gv, Wss, Wvs, Wsd, Wvd, ssrc, sdst, vsrc, vdst,
                     shs[wv], shv[wv], n, lane);
}

// ---------------- Kernel 2: fused MFMA edge pass over dst-sorted edges ----------------
// 4 waves/block, 16 edges/wave. Per-wave LDS (bf16 elems):
//   A1S [16][104] (3,328 B)  -- m1_s / m2_s; aliased by VAL [16][72]
//   P0  [16][136] (4,352 B)  -- SINGLE plane buffer (V-planes strictly serialized)
// No fp32 S8 staging: segmented dst-reduction done in registers per q-group
// with direct atomics. Per-wave: 7,680 B H + 256 sY + 192 sSD -> 32,512 B/block
// -> 5 blocks/CU = 20 waves/CU. __launch_bounds__(256,5) caps VGPR at 102.
static constexpr int SS  = 104;
static constexpr int A1S = 0;
static constexpr int SV  = 136;
static constexpr int P0  = 16 * SS;           // 1664
static constexpr int VAL = 0;                 // alias of A1S region (16x72=1152 <= 1664)
static constexpr int SA  = 72;
static constexpr int HSZ = P0 + 16 * SV;      // 3840 elems = 7,680 B

// m1_v plane X write into buffer PB (uses sv_, qv_, pv_, sY)
#define W_M1(X, PB) do { \
    constexpr int x_ = (X), x1_ = ((X)+1)%3, x2_ = ((X)+2)%3; \
    _Pragma("unroll") \
    for (int r = 0; r < 4; ++r) { \
        int e = q * 4 + r; \
        float4 yy = *(const float4*)&sY[wv][e][0]; \
        float y0 = yy.x; float yv[3] = {yy.y, yy.z, yy.w}; \
        _Pragma("unroll") \
        for (int nt = 0; nt < 4; ++nt) \
            H[(PB) + e * SV + nt * 16 + m] = (__bf16)(sv_[r][nt] * yv[x_]); \
        _Pragma("unroll") \
        for (int n2 = 0; n2 < 2; ++n2) { \
            int c = 64 + n2 * 16 + m; \
            H[(PB) + e * SV + c] = (__bf16)(qv_[r][n2][x_] * y0); \
            float cr = pv_[r][n2][x1_] * yv[x2_] - pv_[r][n2][x2_] * yv[x1_]; \
            H[(PB) + e * SV + 32 + c] = (__bf16)(cr * SQRT2_INV); \
        } \
    } \
} while (0)

// m2_v plane X write into buffer PB (uses vals, vv, c2*, sY)
#define W_M2(X, PB) do { \
    constexpr int x_ = (X), x1_ = ((X)+1)%3, x2_ = ((X)+2)%3; \
    _Pragma("unroll") \
    for (int r = 0; r < 4; ++r) { \
        int e = q * 4 + r; \
        float4 yy = *(const float4*)&sY[wv][e][0]; \
        float y0 = yy.x; float yv[3] = {yy.y, yy.z, yy.w}; \
        _Pragma("unroll") \
        for (int nt = 0; nt < 4; ++nt) \
            H[(PB) + e * SV + nt * 16 + m] = (__bf16)(c2sv[nt] * vals[nt][r] * yv[x_]); \
        _Pragma("unroll") \
        for (int n2 = 0; n2 < 2; ++n2) { \
            int c = 64 + n2 * 16 + m; \
            H[(PB) + e * SV + c] = (__bf16)(c2vs[n2] * vv[x_][n2][r] * y0); \
            float cr = vv[x1_][n2][r] * yv[x2_] - vv[x2_][n2][r] * yv[x1_]; \
            H[(PB) + e * SV + 32 + c] = (__bf16)(c2v1[n2] * cr * SQRT2_INV); \
        } \
    } \
} while (0)

// read A-frags from plane buffer PB and accumulate 2 output tiles with weights WB
#define MMA_V(PB, WB, O0, O1) do { \
    bfv8 fg_[4]; \
    _Pragma("unroll") \
    for (int kt = 0; kt < 4; ++kt) \
        fg_[kt] = *(const bfv8*)(H + (PB) + m * SV + kt * 32 + kq); \
    _Pragma("unroll") \
    for (int kt = 0; kt < 4; ++kt) { \
        O0 = mf(fg_[kt], *(const bfv8*)((WB) + (size_t)(0 * 16 + m) * 128 + kt * 32 + kq), O0); \
        O1 = mf(fg_[kt], *(const bfv8*)((WB) + (size_t)(1 * 16 + m) * 128 + kt * 32 + kq), O1); \
    } \
} while (0)

__global__ __launch_bounds__(256, 5) void k_edge(
    const void* __restrict__ eidx, const void* __restrict__ rbf, const void* __restrict__ rsh,
    const bf16* __restrict__ WalphaT, const bf16* __restrict__ WsvalT, const bf16* __restrict__ WsvlinT,
    const bf16* __restrict__ WvvalT, const bf16* __restrict__ WvvlinT, const bf16* __restrict__ WgT,
    const bf16* __restrict__ WrbfT, const bf16* __restrict__ adotB, const bf16* __restrict__ w2B,
    const bf16* __restrict__ ssrc, const bf16* __restrict__ sdst,
    const bf16* __restrict__ vsrc, const bf16* __restrict__ vdst,
    const int* __restrict__ perm,
    float* __restrict__ den, float* __restrict__ agg,
    const int* __restrict__ flags, int E)
{
    const int bfm = flags[0];
    const int i64 = flags[1];

    __shared__ __align__(16) __bf16 sH[4][HSZ];
    __shared__ __align__(16) float sY[4][16][4];
    __shared__ int sSD[4][48];   // [0..15]=src, [16..31]=dst, [32..47]=permuted edge id

    int wv = threadIdx.x >> 6, l = threadIdx.x & 63;
    int q = l >> 4, m = l & 15;
    const int kq = q * 8;
    long long eb = ((long long)blockIdx.x * 4 + wv) * 16;
    if (eb >= E) return;        // wave-uniform; no barriers in this kernel
    __bf16* H = &sH[wv][0];

    // ---- edge metadata (sorted position -> edge id via perm) ----
    if (l < 16) {
        long long p = eb + l; if (p > (long long)E - 1) p = E - 1;
        sSD[wv][32 + l] = perm[p];
    }
    if (l < 32) {
        int pe = sSD[wv][32 + (l & 15)];
        long long off = (l < 16) ? (long long)pe : ((long long)E + pe);
        sSD[wv][l] = i64 ? (int)((const long long*)eidx)[off] : ((const int*)eidx)[off];
    }
    {
        int pe = sSD[wv][32 + (l >> 2)];
        sY[wv][l >> 2][l & 3] = ldr(rsh, (size_t)pe * 4 + (l & 3), bfm);
    }

    // ---- S1a: w1 = rbf @ Wrbf via 14 MFMAs (K=32, k>=16 zero-padded) ----
    f4 w1f[14];
    {
        bfv8 arb;
        #pragma unroll
        for (int i = 0; i < 8; ++i) arb[i] = (__bf16)0.f;
        if (q < 2) {
            int pe = sSD[wv][32 + m];
            if (bfm) {
                arb = *(const bfv8*)((const __bf16*)rbf + (size_t)pe * 16 + kq);
            } else {
                const float* rp = (const float*)rbf + (size_t)pe * 16 + kq;
                #pragma unroll
                for (int i = 0; i < 8; ++i) arb[i] = (__bf16)rp[i];
            }
        }
        const __bf16* wb = (const __bf16*)WrbfT;
        #pragma unroll
        for (int nt = 0; nt < 14; ++nt) {
            bfv8 bb = *(const bfv8*)(wb + (size_t)(nt * 16 + m) * 32 + kq);
            f4 z = {0.f, 0.f, 0.f, 0.f};
            w1f[nt] = mf(arb, bb, z);
        }
    }

    // ---- gather messages (vectorized via swizzled node arrays, batched) ----
    bfv4 gs_[4], gd_[4];
    bfv8 gv_[4], gw_[4];
    #pragma unroll
    for (int r = 0; r < 4; ++r) {
        int e = q * 4 + r;
        int s = sSD[wv][e], d = sSD[wv][16 + e];
        gs_[r] = *(const bfv4*)((const __bf16*)ssrc + (size_t)s * 64 + m * 4);
        gd_[r] = *(const bfv4*)((const __bf16*)sdst + (size_t)d * 64 + m * 4);
        gv_[r] = *(const bfv8*)((const __bf16*)vsrc + (size_t)s * 128 + m * 8);
        gw_[r] = *(const bfv8*)((const __bf16*)vdst + (size_t)d * 128 + m * 8);
    }
    float ms_[4][4], mv_[4][2][3];
    #pragma unroll
    for (int r = 0; r < 4; ++r) {
        #pragma unroll
        for (int nt = 0; nt < 4; ++nt)
            ms_[r][nt] = (float)gs_[r][nt] + (float)gd_[r][nt];
        #pragma unroll
        for (int x = 0; x < 3; ++x)
            #pragma unroll
            for (int n2 = 0; n2 < 2; ++n2)
                mv_[r][n2][x] = (float)gv_[r][2 * x + n2] + (float)gw_[r][2 * x + n2];
    }

    // ---- m1_s -> A1S; precompute plane products ----
    float sv_[4][4], qv_[4][2][3], pv_[4][2][3];
    #pragma unroll
    for (int r = 0; r < 4; ++r) {
        int e = q * 4 + r;
        float4 yy = *(const float4*)&sY[wv][e][0];
        float y0 = yy.x, yx = yy.y, yh = yy.z, yz = yy.w;
        #pragma unroll
        for (int nt = 0; nt < 4; ++nt) {
            H[A1S + e * SS + nt * 16 + m] = (__bf16)(w1f[nt][r] * ms_[r][nt] * y0);
            sv_[r][nt] = w1f[4 + nt][r] * ms_[r][nt];
        }
        #pragma unroll
        for (int n2 = 0; n2 < 2; ++n2) {
            float dot = mv_[r][n2][0] * yx + mv_[r][n2][1] * yh + mv_[r][n2][2] * yz;
            H[A1S + e * SS + 64 + n2 * 16 + m] = (__bf16)(w1f[10 + n2][r] * dot * SQRT3_INV);
            #pragma unroll
            for (int x = 0; x < 3; ++x) {
                qv_[r][n2][x] = w1f[8 + n2][r]  * mv_[r][n2][x];
                pv_[r][n2][x] = w1f[12 + n2][r] * mv_[r][n2][x];
            }
        }
    }

    // ---- S5 (moved early so sv_/qv_/pv_ die): m1_v planes -> vv (ungated) ----
    f4 vv[3][2];
    #pragma unroll
    for (int x = 0; x < 3; ++x)
        #pragma unroll
        for (int nt = 0; nt < 2; ++nt)
            vv[x][nt] = (f4){0.f, 0.f, 0.f, 0.f};
    W_M1(0, P0);
    MMA_V(P0, (const __bf16*)WvvalT, vv[0][0], vv[0][1]);
    W_M1(1, P0);
    MMA_V(P0, (const __bf16*)WvvalT, vv[1][0], vv[1][1]);
    W_M1(2, P0);
    MMA_V(P0, (const __bf16*)WvvalT, vv[2][0], vv[2][1]);

    // ---- a1s fragments (A1S region then reusable) ----
    bfv8 a1s0 = *(const bfv8*)(H + A1S + m * SS + 0  + kq);
    bfv8 a1s1 = *(const bfv8*)(H + A1S + m * SS + 32 + kq);
    bfv8 a1s2 = *(const bfv8*)(H + A1S + m * SS + 64 + kq);

    // ---- S2: val_s = m1_s @ Ws_val; PRE-sigmoid -> VAL (alias A1S), sigmoid -> regs ----
    f4 vals[4];
    #pragma unroll
    for (int nt = 0; nt < 4; ++nt) {
        const __bf16* bp = (const __bf16*)WsvalT + (size_t)(nt * 16 + m) * 96 + kq;
        f4 acc = {0.f, 0.f, 0.f, 0.f};
        acc = mf(a1s0, *(const bfv8*)(bp),      acc);
        acc = mf(a1s1, *(const bfv8*)(bp + 32), acc);
        acc = mf(a1s2, *(const bfv8*)(bp + 64), acc);
        vals[nt] = acc;
    }
    #pragma unroll
    for (int nt = 0; nt < 4; ++nt)
        #pragma unroll
        for (int r = 0; r < 4; ++r) {
            float v = vals[nt][r];
            H[VAL + (q * 4 + r) * SA + nt * 16 + m] = (__bf16)v;   // PRE-sigmoid
            vals[nt][r] = 1.f / (1.f + __expf(-v));
        }

    // ---- S3: gate = sigmoid(val_s_pre @ Wg); gate vv ----
    {
        bfv8 av0 = *(const bfv8*)(H + VAL + m * SA + 0  + kq);
        bfv8 av1 = *(const bfv8*)(H + VAL + m * SA + 32 + kq);
        f4 gate[2];
        #pragma unroll
        for (int nt = 0; nt < 2; ++nt) {
            const __bf16* bp = (const __bf16*)WgT + (size_t)(nt * 16 + m) * 64 + kq;
            f4 acc = {0.f, 0.f, 0.f, 0.f};
            acc = mf(av0, *(const bfv8*)(bp),      acc);
            acc = mf(av1, *(const bfv8*)(bp + 32), acc);
            gate[nt] = acc;
        }
        #pragma unroll
        for (int nt = 0; nt < 2; ++nt)
            #pragma unroll
            for (int r = 0; r < 4; ++r)
                gate[nt][r] = 1.f / (1.f + __expf(-gate[nt][r]));
        #pragma unroll
        for (int x = 0; x < 3; ++x)
            #pragma unroll
            for (int nt = 0; nt < 2; ++nt)
                #pragma unroll
                for (int r = 0; r < 4; ++r)
                    vv[x][nt][r] *= gate[nt][r];
    }

    // ---- S4: attention logits + ex ----
    float ex_[4][4];
    #pragma unroll
    for (int nt = 0; nt < 4; ++nt) {
        const __bf16* bp = (const __bf16*)WalphaT + (size_t)(nt * 16 + m) * 96 + kq;
        f4 acc = {0.f, 0.f, 0.f, 0.f};
        acc = mf(a1s0, *(const bfv8*)(bp),      acc);
        acc = mf(a1s1, *(const bfv8*)(bp + 32), acc);
        acc = mf(a1s2, *(const bfv8*)(bp + 64), acc);
        float ad = b2f(adotB[nt * 16 + m]);
        #pragma unroll
        for (int r = 0; r < 4; ++r) {
            float tv = acc[r];
            tv = tv > 0.f ? tv : 0.2f * tv;
            tv *= ad;
            tv += __shfl_xor(tv, 1); tv += __shfl_xor(tv, 2);
            tv += __shfl_xor(tv, 4); tv += __shfl_xor(tv, 8);
            tv = fminf(fmaxf(tv, -60.f), 60.f);
            ex_[nt][r] = __expf(tv);
        }
    }

    // ---- S6/S7 scalar part: m2_s -> A1S (VAL now dead), project -> hs ----
    float c2ss[4], c2sv[4];
    #pragma unroll
    for (int nt = 0; nt < 4; ++nt) {
        c2ss[nt] = b2f(w2B[nt * 16 + m]);
        c2sv[nt] = b2f(w2B[64 + nt * 16 + m]);
    }
    float c2vs[2], c2v0[2], c2v1[2];
    #pragma unroll
    for (int nt = 0; nt < 2; ++nt) {
        c2vs[nt] = b2f(w2B[128 + nt * 16 + m]);
        c2v0[nt] = b2f(w2B[160 + nt * 16 + m]);
        c2v1[nt] = b2f(w2B[192 + nt * 16 + m]);
    }
    #pragma unroll
    for (int r = 0; r < 4; ++r) {
        int e = q * 4 + r;
        float4 yy = *(const float4*)&sY[wv][e][0];
        float y0 = yy.x, yx = yy.y, yh = yy.z, yz = yy.w;
        #pragma unroll
        for (int nt = 0; nt < 4; ++nt)
            H[A1S + e * SS + nt * 16 + m] = (__bf16)(c2ss[nt] * vals[nt][r] * y0);
        #pragma unroll
        for (int n2 = 0; n2 < 2; ++n2) {
            float dotv = vv[0][n2][r] * yx + vv[1][n2][r] * yh + vv[2][n2][r] * yz;
            H[A1S + e * SS + 64 + n2 * 16 + m] = (__bf16)(c2v0[n2] * dotv * SQRT3_INV);
        }
    }
    f4 hs[4];
    {
        bfv8 a2s0 = *(const bfv8*)(H + A1S + m * SS + 0  + kq);
        bfv8 a2s1 = *(const bfv8*)(H + A1S + m * SS + 32 + kq);
        bfv8 a2s2 = *(const bfv8*)(H + A1S + m * SS + 64 + kq);
        #pragma unroll
        for (int nt = 0; nt < 4; ++nt) {
            const __bf16* bp = (const __bf16*)WsvlinT + (size_t)(nt * 16 + m) * 96 + kq;
            f4 acc = {0.f, 0.f, 0.f, 0.f};
            acc = mf(a2s0, *(const bfv8*)(bp),      acc);
            acc = mf(a2s1, *(const bfv8*)(bp + 32), acc);
            acc = mf(a2s2, *(const bfv8*)(bp + 64), acc);
            hs[nt] = acc;
        }
    }

    // ---- S6/S7 vector part: m2_v planes through single buffer -> hv ----
    f4 hv[3][2];
    #pragma unroll
    for (int x = 0; x < 3; ++x)
        #pragma unroll
        for (int nt = 0; nt < 2; ++nt)
            hv[x][nt] = (f4){0.f, 0.f, 0.f, 0.f};
    W_M2(0, P0);
    MMA_V(P0, (const __bf16*)WvvlinT, hv[0][0], hv[0][1]);
    W_M2(1, P0);
    MMA_V(P0, (const __bf16*)WvvlinT, hv[1][0], hv[1][1]);
    W_M2(2, P0);
    MMA_V(P0, (const __bf16*)WvvlinT, hv[2][0], hv[2][1]);

    // ---- S8: register-space segmented reduction per q-group, direct atomics ----
    // lane (q,m) holds for edges e=q*4+r: s-ch nt*16+m -> agg pos nt*40+m;
    // v-ch c=nt*16+m (c<32), comp x -> agg pos (nt*2+(m>>3))*40+16+(m&7)*3+x.
    // Segment boundaries (sorted dst) are uniform per q-group; static r-unroll,
    // flush on run end (rule #20: no runtime indexing of f4 arrays).
    {
        int nval = (int)((E - eb) < 16 ? (E - eb) : 16);
        const int e0 = q * 4;
        float as_[4] = {0.f, 0.f, 0.f, 0.f};
        float av_[3][2] = {{0.f,0.f},{0.f,0.f},{0.f,0.f}};
        float de_ = 0.f;
        #pragma unroll
        for (int r = 0; r < 4; ++r) {
            int e = e0 + r;
            bool valid = (e < nval);
            int d = sSD[wv][16 + (valid ? e : 0)];
            if (valid) {
                #pragma unroll
                for (int nt = 0; nt < 4; ++nt) as_[nt] += ex_[nt][r] * hs[nt][r];
                #pragma unroll
                for (int nt = 0; nt < 2; ++nt) {
                    float exv = (m >= 8) ? ex_[2 * nt + 1][r] : ex_[2 * nt][r];
                    #pragma unroll
                    for (int x = 0; x < 3; ++x) av_[x][nt] += exv * hv[x][nt][r];
                }
                if (m < 4) de_ += ex_[m][r];
            }
            bool last;
            if (r == 3) {
                last = valid;
            } else {
                int en = e + 1;
                last = valid && ((en >= nval) || (sSD[wv][16 + en] != d));
            }
            if (last) {
                float* rowp = agg + (size_t)d * 160;
                #pragma unroll
                for (int nt = 0; nt < 4; ++nt)
                    unsafeAtomicAdd(rowp + nt * 40 + m, as_[nt]);
                #pragma unroll
                for (int nt = 0; nt < 2; ++nt) {
                    int hh = nt * 2 + (m >> 3), dd2 = m & 7;
                    #pragma unroll
                    for (int x = 0; x < 3; ++x)
                        unsafeAtomicAdd(rowp + hh * 40 + 16 + dd2 * 3 + x, av_[x][nt]);
                }
                if (m < 4) unsafeAtomicAdd(den + (size_t)d * 4 + m, de_);
                #pragma unroll
                for (int nt = 0; nt < 4; ++nt) as_[nt] = 0.f;
                #pragma unroll
                for (int nt = 0; nt < 2; ++nt)
                    #pragma unroll
                    for (int x = 0; x < 3; ++x) av_[x][nt] = 0.f;
                de_ = 0.f;
            }
        }
    }
}

// ---------------- Kernel 3: normalize + output projection + residual (4 nodes/block) ----------------
template<int BF>
__device__ __forceinline__ void out_impl(
    const void* node, const float* den, const float* agg,
    const void* Wps, const void* Wpv, void* out,
    float* shs, float* shv, float* sinv, int n, int lane)
{
    if (lane < 4) sinv[lane] = 1.f / (den[(size_t)n * 4 + lane] + 1e-16f);
    for (int idx = lane; idx < 160; idx += 64) {
        int h = idx / 40, r = idx - h * 40;
        float val = agg[(size_t)n * 160 + idx] * sinv[h];
        if (r < 16) shs[h * 16 + r] = val;
        else { int rr = r - 16; int dd = rr / 3, x = rr - dd * 3; shv[x * 32 + h * 8 + dd] = val; }
    }

    float acc = ldf<BF>(node, (size_t)n * 160 + lane);
    for (int c = 0; c < 64; ++c) acc += shs[c] * ldf<BF>(Wps, c * 64 + lane);
    stf<BF>(out, (size_t)n * 160 + lane, acc);

    {
        int idx = lane; int dd = idx / 3, x = idx - dd * 3;
        float a = ldf<BF>(node, (size_t)n * 160 + 64 + idx);
        for (int c = 0; c < 32; ++c) a += shv[x * 32 + c] * ldf<BF>(Wpv, c * 32 + dd);
        stf<BF>(out, (size_t)n * 160 + 64 + idx, a);
    }
    if (lane < 32) {
        int idx = 64 + lane; int dd = idx / 3, x = idx - dd * 3;
        float a = ldf<BF>(node, (size_t)n * 160 + 64 + idx);
        for (int c = 0; c < 32; ++c) a += shv[x * 32 + c] * ldf<BF>(Wpv, c * 32 + dd);
        stf<BF>(out, (size_t)n * 160 + 64 + idx, a);
    }
}

__global__ __launch_bounds__(256) void k_out(
    const void* node, const float* den, const float* agg,
    const void* Wps, const void* Wpv, void* out,
    const int* flags, int N)
{
    __shared__ float shs[4][64];
    __shared__ float shv[4][96];
    __shared__ float sinv[4][4];
    int wv = threadIdx.x >> 6, lane = threadIdx.x & 63;
    int n = blockIdx.x * 4 + wv; if (n >= N) return;
    if (flags[0])
        out_impl<1>(node, den, agg, Wps, Wpv, out, shs[wv], shv[wv], sinv[wv], n, lane);
    else
        out_impl<0>(node, den, agg, Wps, Wpv, out, shs[wv], shv[wv], sinv[wv], n, lane);
}

// ---------------- Launch ----------------
extern "C" void kernel_launch(void* const* d_in, const int* in_sizes, int n_in,
                              void* d_out, int out_size, void* d_ws, size_t ws_size,
                              hipStream_t stream)
{
    const void* node   = d_in[0];
    const void* eidx   = d_in[1];
    const void* rbf    = d_in[2];
    const void* rsh    = d_in[3];
    const void* gs     = d_in[4];
    const void* bs     = d_in[5];
    const void* gv     = d_in[6];
    const void* Wss    = d_in[7];
    const void* Wvs    = d_in[8];
    const void* Wsd    = d_in[9];
    const void* Wvd    = d_in[10];
    const void* Wrbf   = d_in[11];
    const void* Walpha = d_in[12];
    const void* adot   = d_in[13];
    const void* Wsval  = d_in[14];
    const void* Wvval  = d_in[15];
    const void* Wg     = d_in[16];
    const void* w2ss   = d_in[17];
    const void* w2sv   = d_in[18];
    const void* w2vs   = d_in[19];
    const void* w2vv0  = d_in[20];
    const void* w2vv1  = d_in[21];
    const void* Wsvlin = d_in[22];
    const void* Wvvlin = d_in[23];
    const void* Wps    = d_in[24];
    const void* Wpv    = d_in[25];

    int N = in_sizes[0] / 160;
    int E = in_sizes[1] / 2;

    char* base = (char*)d_ws;
    int*  flags   = (int*)base;                  // 16 B
    bf16* WalphaT = (bf16*)(base + 16);
    bf16* WsvalT  = WalphaT + 6144;
    bf16* WsvlinT = WsvalT  + 6144;
    bf16* WvvalT  = WsvlinT + 6144;
    bf16* WvvlinT = WvvalT  + 4096;
    bf16* WgT     = WvvlinT + 4096;
    bf16* WrbfT   = WgT     + 2048;
    bf16* adotB   = WrbfT   + 7168;              // 224 x 32 zero-padded
    bf16* w2B     = adotB   + 64;
    bf16* ssrc    = w2B     + 224;
    bf16* sdst    = ssrc + (size_t)N * 64;
    bf16* vsrc    = sdst + (size_t)N * 64;       // swizzled, stride 128
    bf16* vdst    = vsrc + (size_t)N * 128;
    float* den    = (float*)(vdst + (size_t)N * 128);
    float* agg    = den + (size_t)N * 4;
    int*  cnt     = (int*)(agg + (size_t)N * 160);
    int*  perm    = cnt + N;

    k_sniff<<<1, 256, 0, stream>>>(node, eidx, flags);
    // den (4N) + agg (160N) + cnt (N) are contiguous: zero all in one launch
    int zn = N * 165;
    k_zero<<<(zn + 255) / 256, 256, 0, stream>>>(den, zn);

    // counting sort of edges by dst
    int nbe = (E + 255) / 256;
    k_hist<<<nbe, 256, 0, stream>>>(eidx, cnt, flags, E);
    k_scan<<<1, 1024, 0, stream>>>(cnt, N);
    k_perm<<<nbe, 256, 0, stream>>>(eidx, cnt, perm, flags, E);

    k_prep<<<16, 256, 0, stream>>>(Walpha, Wsval, Wsvlin, Wvval, Wvvlin, Wg, Wrbf, adot,
                                   w2ss, w2sv, w2vs, w2vv0, w2vv1,
                                   WalphaT, WsvalT, WsvlinT, WvvalT, WvvlinT, WgT, WrbfT,
                                   adotB, w2B, flags);

    int nbn = (N + 3) / 4;
    k_node<<<nbn, 256, 0, stream>>>(node, gs, bs, gv, Wss, Wvs, Wsd, Wvd,
                                    ssrc, sdst, vsrc, vdst, flags, N);

    int nb = (E + 63) / 64;
    k_edge<<<nb, 256, 0, stream>>>(eidx, rbf, rsh,
                                   WalphaT, WsvalT, WsvlinT, WvvalT, WvvlinT, WgT, WrbfT,
                                   adotB, w2B, ssrc, sdst, vsrc, vdst, perm, den, agg, flags, E);

    int nbo = (N + 3) / 4;
    k_out<<<nbo, 256, 0, stream>>>(node, den, agg, Wps, Wpv, d_out, flags, N);
}

// Round 4
// 636.209 us; speedup vs baseline: 1.2374x; 1.2374x over previous
//
#include <hip/hip_runtime.h>
#include <hip/hip_bf16.h>
#include <cstddef>

typedef __hip_bfloat16 bf16;
typedef __bf16 bfv8 __attribute__((ext_vector_type(8)));
typedef __bf16 bfv4 __attribute__((ext_vector_type(4)));
typedef float f4 __attribute__((ext_vector_type(4)));

#define EPSN 1e-5f
#define SQRT3_INV 0.57735026918962576f
#define SQRT2_INV 0.70710678118654752f

__device__ __forceinline__ float b2f(bf16 x) { return __bfloat162float(x); }

template<int BF> __device__ __forceinline__ float ldf(const void* p, size_t i) {
    if (BF) return __bfloat162float(((const bf16*)p)[i]);
    return ((const float*)p)[i];
}
__device__ __forceinline__ float ldr(const void* p, size_t i, int bfm) {
    return bfm ? __bfloat162float(((const bf16*)p)[i]) : ((const float*)p)[i];
}
template<int BF> __device__ __forceinline__ void stf(void* p, size_t i, float v) {
    if (BF) ((bf16*)p)[i] = __float2bfloat16(v);
    else    ((float*)p)[i] = v;
}

__device__ __forceinline__ float wave_sum64(float x) {
    #pragma unroll
    for (int m = 1; m < 64; m <<= 1) x += __shfl_xor(x, m, 64);
    return x;
}

__device__ __forceinline__ f4 mf(bfv8 a, bfv8 b, f4 c) {
    return __builtin_amdgcn_mfma_f32_16x16x32_bf16(a, b, c, 0, 0, 0);
}

// ---------------- Sniffer ----------------
__global__ __launch_bounds__(256) void k_sniff(const void* node, const void* eidx, int* flags)
{
    int t = threadIdx.x;
    __shared__ int cnt;
    __shared__ unsigned orr;
    if (t == 0) { cnt = 0; orr = 0u; }
    __syncthreads();
    unsigned w  = ((const unsigned*)node)[t];
    unsigned lo = w & 0xFFFFu;
    int e_lo = (int)((lo >> 7) & 0xFF);
    if (e_lo >= 96 && e_lo <= 140) atomicAdd(&cnt, 1);
    unsigned odd = ((const unsigned*)eidx)[2 * t + 1];
    atomicOr(&orr, odd);
    __syncthreads();
    if (t == 0) {
        flags[0] = (cnt >= 128) ? 1 : 0;   // 1 = bf16 inputs
        flags[1] = (orr == 0u) ? 1 : 0;    // 1 = int64 edge_index
    }
}

__global__ __launch_bounds__(256) void k_zero(float* p, int n)
{
    int i = blockIdx.x * 256 + threadIdx.x;
    if (i < n) p[i] = 0.f;
}

// ---------------- Counting sort by dst ----------------
__global__ __launch_bounds__(256) void k_hist(const void* eidx, int* cnt,
                                              const int* flags, int E)
{
    int e = blockIdx.x * 256 + threadIdx.x;
    if (e >= E) return;
    int d = flags[1] ? (int)((const long long*)eidx)[(long long)E + e]
                     : ((const int*)eidx)[(size_t)E + e];
    atomicAdd(&cnt[d], 1);
}

__global__ __launch_bounds__(1024) void k_scan(int* cnt, int N)
{
    __shared__ int wsum[16];
    int t = threadIdx.x;
    int lane = t & 63, w = t >> 6;
    int chunk = (N + 1023) >> 10;
    int lo = t * chunk, hi = lo + chunk;
    if (hi > N) hi = N; if (lo > N) lo = N;
    int sum = 0;
    for (int i = lo; i < hi; ++i) sum += cnt[i];
    int x = sum;
    #pragma unroll
    for (int off = 1; off < 64; off <<= 1) {
        int y = __shfl_up(x, off, 64);
        if (lane >= off) x += y;
    }
    if (lane == 63) wsum[w] = x;
    __syncthreads();
    if (t < 64) {
        int v = (lane < 16) ? wsum[lane] : 0;
        #pragma unroll
        for (int off = 1; off < 16; off <<= 1) {
            int y = __shfl_up(v, off, 64);
            if (lane >= off) v += y;
        }
        if (lane < 16) wsum[lane] = v;
    }
    __syncthreads();
    int acc = x - sum + (w ? wsum[w - 1] : 0);
    for (int i = lo; i < hi; ++i) { int v = cnt[i]; cnt[i] = acc; acc += v; }
}

__global__ __launch_bounds__(256) void k_perm(const void* eidx, int* cnt, int* perm,
                                              const int* flags, int E)
{
    int e = blockIdx.x * 256 + threadIdx.x;
    if (e >= E) return;
    int d = flags[1] ? (int)((const long long*)eidx)[(long long)E + e]
                     : ((const int*)eidx)[(size_t)E + e];
    int pos = atomicAdd(&cnt[d], 1);
    perm[pos] = e;
}

// ---------------- Prep: transpose weights to bf16 [n][k] ----------------
template<int BF>
__device__ __forceinline__ void prep_impl(
    const void* Walpha, const void* Wsval, const void* Wsvlin,
    const void* Wvval, const void* Wvvlin, const void* Wg,
    const void* Wrbf, const void* adot,
    const void* w2ss, const void* w2sv, const void* w2vs,
    const void* w2vv0, const void* w2vv1,
    bf16* WalphaT, bf16* WsvalT, bf16* WsvlinT,
    bf16* WvvalT, bf16* WvvlinT, bf16* WgT,
    bf16* WrbfT, bf16* adotB, bf16* w2B)
{
    int t = threadIdx.x + blockIdx.x * 256;
    int T = gridDim.x * 256;
    for (int i = t; i < 96 * 64; i += T) {
        int c = i >> 6, n = i & 63;
        WalphaT[n * 96 + c] = __float2bfloat16(ldf<BF>(Walpha, i));
        WsvalT [n * 96 + c] = __float2bfloat16(ldf<BF>(Wsval,  i));
        WsvlinT[n * 96 + c] = __float2bfloat16(ldf<BF>(Wsvlin, i));
    }
    for (int i = t; i < 128 * 32; i += T) {
        int c = i >> 5, n = i & 31;
        WvvalT [n * 128 + c] = __float2bfloat16(ldf<BF>(Wvval,  i));
        WvvlinT[n * 128 + c] = __float2bfloat16(ldf<BF>(Wvvlin, i));
    }
    for (int i = t; i < 64 * 32; i += T) {
        int c = i >> 5, n = i & 31;
        WgT[n * 64 + c] = __float2bfloat16(ldf<BF>(Wg, i));
    }
    for (int i = t; i < 224 * 32; i += T) {
        int c = i >> 5, b = i & 31;
        WrbfT[i] = __float2bfloat16(b < 16 ? ldf<BF>(Wrbf, b * 224 + c) : 0.f);
    }
    if (t < 64) adotB[t] = __float2bfloat16(ldf<BF>(adot, t));
    if (t < 64) w2B[t]      = __float2bfloat16(ldf<BF>(w2ss, t));
    if (t < 64) w2B[64 + t] = __float2bfloat16(ldf<BF>(w2sv, t));
    if (t < 32) {
        w2B[128 + t] = __float2bfloat16(ldf<BF>(w2vs, t));
        w2B[160 + t] = __float2bfloat16(ldf<BF>(w2vv0, t));
        w2B[192 + t] = __float2bfloat16(ldf<BF>(w2vv1, t));
    }
}

__global__ __launch_bounds__(256) void k_prep(
    const void* Walpha, const void* Wsval, const void* Wsvlin,
    const void* Wvval, const void* Wvvlin, const void* Wg,
    const void* Wrbf, const void* adot,
    const void* w2ss, const void* w2sv, const void* w2vs,
    const void* w2vv0, const void* w2vv1,
    bf16* WalphaT, bf16* WsvalT, bf16* WsvlinT,
    bf16* WvvalT, bf16* WvvlinT, bf16* WgT,
    bf16* WrbfT, bf16* adotB, bf16* w2B, const int* flags)
{
    if (flags[0])
        prep_impl<1>(Walpha, Wsval, Wsvlin, Wvval, Wvvlin, Wg, Wrbf, adot,
                     w2ss, w2sv, w2vs, w2vv0, w2vv1,
                     WalphaT, WsvalT, WsvlinT, WvvalT, WvvlinT, WgT, WrbfT, adotB, w2B);
    else
        prep_impl<0>(Walpha, Wsval, Wsvlin, Wvval, Wvvlin, Wg, Wrbf, adot,
                     w2ss, w2sv, w2vs, w2vv0, w2vv1,
                     WalphaT, WsvalT, WsvlinT, WvvalT, WvvlinT, WgT, WrbfT, adotB, w2B);
}

// ---------------- Kernel 1: per-node layernorm + projections (4 nodes/block) ----------------
// Outputs are stored SWIZZLED for vectorized gather in k_edge:
//   ssrc/sdst [n][64]: channel c at position (c&15)*4 + (c>>4)      (bfv4 per lane)
//   vsrc/vdst [n][128]: channel c at position (c&15)*8 + (c>>4)     (bfv8 per lane; slots 6,7 unused)
template<int BF>
__device__ __forceinline__ void node_impl(
    const void* node, const void* gs, const void* bs, const void* gv,
    const void* Wss, const void* Wvs, const void* Wsd, const void* Wvd,
    bf16* ssrc, bf16* sdst, bf16* vsrc, bf16* vdst,
    float* shs, float* shv, int n, int lane)
{
    size_t nb = (size_t)n * 160;

    float s  = ldf<BF>(node, nb + lane);
    float mu = wave_sum64(s) * (1.f / 64.f);
    float d  = s - mu;
    float var = wave_sum64(d * d) * (1.f / 64.f);
    float sn  = d * rsqrtf(var + EPSN) * ldf<BF>(gs, lane) + ldf<BF>(bs, lane);
    shs[lane] = sn;

    float v0 = 0.f, v1 = 0.f, v2 = 0.f, qq = 0.f;
    if (lane < 32) {
        v0 = ldf<BF>(node, nb + 64 + lane * 3 + 0);
        v1 = ldf<BF>(node, nb + 64 + lane * 3 + 1);
        v2 = ldf<BF>(node, nb + 64 + lane * 3 + 2);
        qq = v0 * v0 + v1 * v1 + v2 * v2;
    }
    float msq = wave_sum64(qq) * (1.f / 32.f);
    float inv = rsqrtf(msq + EPSN);
    if (lane < 32) {
        float g = ldf<BF>(gv, lane);
        shv[0 * 32 + lane] = v0 * inv * g;
        shv[1 * 32 + lane] = v1 * inv * g;
        shv[2 * 32 + lane] = v2 * inv * g;
    }
    // same-wave LDS write->read: in-order, no barrier needed

    float a1 = 0.f, a2 = 0.f;
    for (int c = 0; c < 64; ++c) {
        float sc = shs[c];
        a1 += sc * ldf<BF>(Wss, c * 64 + lane);
        a2 += sc * ldf<BF>(Wsd, c * 64 + lane);
    }
    {
        int cs = lane;
        int pos = (cs & 15) * 4 + (cs >> 4);
        ssrc[(size_t)n * 64 + pos] = __float2bfloat16(a1);
        sdst[(size_t)n * 64 + pos] = __float2bfloat16(a2);
    }

    {
        int x = lane >> 5, dd = lane & 31;
        float p1 = 0.f, p2 = 0.f;
        for (int c = 0; c < 32; ++c) {
            float vc = shv[x * 32 + c];
            p1 += vc * ldf<BF>(Wvs, c * 32 + dd);
            p2 += vc * ldf<BF>(Wvd, c * 32 + dd);
        }
        int cv = x * 32 + dd;
        int pos = (cv & 15) * 8 + (cv >> 4);
        vsrc[(size_t)n * 128 + pos] = __float2bfloat16(p1);
        vdst[(size_t)n * 128 + pos] = __float2bfloat16(p2);
    }
    if (lane < 32) {
        int dd = lane;
        float p1 = 0.f, p2 = 0.f;
        for (int c = 0; c < 32; ++c) {
            float vc = shv[2 * 32 + c];
            p1 += vc * ldf<BF>(Wvs, c * 32 + dd);
            p2 += vc * ldf<BF>(Wvd, c * 32 + dd);
        }
        int cv = 64 + dd;
        int pos = (cv & 15) * 8 + (cv >> 4);
        vsrc[(size_t)n * 128 + pos] = __float2bfloat16(p1);
        vdst[(size_t)n * 128 + pos] = __float2bfloat16(p2);
    }
}

__global__ __launch_bounds__(256) void k_node(
    const void* node, const void* gs, const void* bs, const void* gv,
    const void* Wss, const void* Wvs, const void* Wsd, const void* Wvd,
    bf16* ssrc, bf16* sdst, bf16* vsrc, bf16* vdst,
    const int* flags, int N)
{
    __shared__ float shs[4][64];
    __shared__ float shv[4][96];
    int wv = threadIdx.x >> 6, lane = threadIdx.x & 63;
    int n = blockIdx.x * 4 + wv; if (n >= N) return;
    if (flags[0])
        node_impl<1>(node, gs, bs, gv, Wss, Wvs, Wsd, Wvd, ssrc, sdst, vsrc, vdst,
                     shs[wv], shv[wv], n, lane);
    else
        node_impl<0>(node, gs, bs, gv, Wss, Wvs, Wsd, Wvd, ssrc, sdst, vsrc, vdst,
                     shs[wv], shv[wv], n, lane);
}

// ---------------- Kernel 2: fused MFMA edge pass over dst-sorted edges ----------------
// 4 waves/block, 16 edges/wave. Per-wave LDS (bf16 elems):
//   A1S [16][100] (3,200 B)  -- m1_s / m2_s; aliased by VAL [16][72]
//   P0  [16][132] (4,224 B)  -- SINGLE plane buffer (V-planes strictly serialized)
// Block LDS: 4x7,424 + sY 1,024 + sSD 768 = 31,488 B -> 4 blocks/CU at VGPR<=128,
// 5 blocks (158,720 B) if allocator lands <=102 VGPR.
// __launch_bounds__(256,4): cap 128 -- R3's (256,5)/cap-102 forced catastrophic
// spill (VGPR 48, 791 MB scratch writes); true peak liveness is ~120-130.
static constexpr int SS  = 100;
static constexpr int A1S = 0;
static constexpr int SV  = 132;
static constexpr int P0  = 16 * SS;           // 1600
static constexpr int VAL = 0;                 // alias of A1S region (16x72=1152 <= 1600)
static constexpr int SA  = 72;
static constexpr int HSZ = P0 + 16 * SV;      // 3712 elems = 7,424 B

// m1_v plane X write into buffer PB (uses sv_, qv_, pv_, sY)
#define W_M1(X, PB) do { \
    constexpr int x_ = (X), x1_ = ((X)+1)%3, x2_ = ((X)+2)%3; \
    _Pragma("unroll") \
    for (int r = 0; r < 4; ++r) { \
        int e = q * 4 + r; \
        float4 yy = *(const float4*)&sY[wv][e][0]; \
        float y0 = yy.x; float yv[3] = {yy.y, yy.z, yy.w}; \
        _Pragma("unroll") \
        for (int nt = 0; nt < 4; ++nt) \
            H[(PB) + e * SV + nt * 16 + m] = (__bf16)(sv_[r][nt] * yv[x_]); \
        _Pragma("unroll") \
        for (int n2 = 0; n2 < 2; ++n2) { \
            int c = 64 + n2 * 16 + m; \
            H[(PB) + e * SV + c] = (__bf16)(qv_[r][n2][x_] * y0); \
            float cr = pv_[r][n2][x1_] * yv[x2_] - pv_[r][n2][x2_] * yv[x1_]; \
            H[(PB) + e * SV + 32 + c] = (__bf16)(cr * SQRT2_INV); \
        } \
    } \
} while (0)

// m2_v plane X write into buffer PB (uses vals, vv, c2*, sY)
#define W_M2(X, PB) do { \
    constexpr int x_ = (X), x1_ = ((X)+1)%3, x2_ = ((X)+2)%3; \
    _Pragma("unroll") \
    for (int r = 0; r < 4; ++r) { \
        int e = q * 4 + r; \
        float4 yy = *(const float4*)&sY[wv][e][0]; \
        float y0 = yy.x; float yv[3] = {yy.y, yy.z, yy.w}; \
        _Pragma("unroll") \
        for (int nt = 0; nt < 4; ++nt) \
            H[(PB) + e * SV + nt * 16 + m] = (__bf16)(c2sv[nt] * vals[nt][r] * yv[x_]); \
        _Pragma("unroll") \
        for (int n2 = 0; n2 < 2; ++n2) { \
            int c = 64 + n2 * 16 + m; \
            H[(PB) + e * SV + c] = (__bf16)(c2vs[n2] * vv[x_][n2][r] * y0); \
            float cr = vv[x1_][n2][r] * yv[x2_] - vv[x2_][n2][r] * yv[x1_]; \
            H[(PB) + e * SV + 32 + c] = (__bf16)(c2v1[n2] * cr * SQRT2_INV); \
        } \
    } \
} while (0)

// read A-frags from plane buffer PB and accumulate 2 output tiles with weights WB
#define MMA_V(PB, WB, O0, O1) do { \
    bfv8 fg_[4]; \
    _Pragma("unroll") \
    for (int kt = 0; kt < 4; ++kt) \
        fg_[kt] = *(const bfv8*)(H + (PB) + m * SV + kt * 32 + kq); \
    _Pragma("unroll") \
    for (int kt = 0; kt < 4; ++kt) { \
        O0 = mf(fg_[kt], *(const bfv8*)((WB) + (size_t)(0 * 16 + m) * 128 + kt * 32 + kq), O0); \
        O1 = mf(fg_[kt], *(const bfv8*)((WB) + (size_t)(1 * 16 + m) * 128 + kt * 32 + kq), O1); \
    } \
} while (0)

__global__ __launch_bounds__(256, 4) void k_edge(
    const void* __restrict__ eidx, const void* __restrict__ rbf, const void* __restrict__ rsh,
    const bf16* __restrict__ WalphaT, const bf16* __restrict__ WsvalT, const bf16* __restrict__ WsvlinT,
    const bf16* __restrict__ WvvalT, const bf16* __restrict__ WvvlinT, const bf16* __restrict__ WgT,
    const bf16* __restrict__ WrbfT, const bf16* __restrict__ adotB, const bf16* __restrict__ w2B,
    const bf16* __restrict__ ssrc, const bf16* __restrict__ sdst,
    const bf16* __restrict__ vsrc, const bf16* __restrict__ vdst,
    const int* __restrict__ perm,
    float* __restrict__ den, float* __restrict__ agg,
    const int* __restrict__ flags, int E)
{
    const int bfm = flags[0];
    const int i64 = flags[1];

    __shared__ __align__(16) __bf16 sH[4][HSZ];
    __shared__ __align__(16) float sY[4][16][4];
    __shared__ int sSD[4][48];   // [0..15]=src, [16..31]=dst, [32..47]=permuted edge id

    int wv = threadIdx.x >> 6, l = threadIdx.x & 63;
    int q = l >> 4, m = l & 15;
    const int kq = q * 8;

    // XCD-chunked bijective block swizzle (T1, m204): contiguous sorted-dst
    // ranges per XCD -> dst-side gather slice becomes L2-resident per XCD.
    int bid;
    {
        int nwg = gridDim.x, orig = blockIdx.x;
        int qq_ = nwg >> 3, rr_ = nwg & 7;
        int xcd = orig & 7, off = orig >> 3;
        bid = (xcd < rr_ ? xcd * (qq_ + 1) : rr_ * (qq_ + 1) + (xcd - rr_) * qq_) + off;
    }
    long long eb = ((long long)bid * 4 + wv) * 16;
    if (eb >= E) return;        // wave-uniform; no barriers in this kernel
    __bf16* H = &sH[wv][0];

    // ---- edge metadata (sorted position -> edge id via perm) ----
    if (l < 16) {
        long long p = eb + l; if (p > (long long)E - 1) p = E - 1;
        sSD[wv][32 + l] = perm[p];
    }
    if (l < 32) {
        int pe = sSD[wv][32 + (l & 15)];
        long long off = (l < 16) ? (long long)pe : ((long long)E + pe);
        sSD[wv][l] = i64 ? (int)((const long long*)eidx)[off] : ((const int*)eidx)[off];
    }
    {
        int pe = sSD[wv][32 + (l >> 2)];
        sY[wv][l >> 2][l & 3] = ldr(rsh, (size_t)pe * 4 + (l & 3), bfm);
    }

    // ---- S1a: w1 = rbf @ Wrbf via 14 MFMAs (K=32, k>=16 zero-padded) ----
    f4 w1f[14];
    {
        bfv8 arb;
        #pragma unroll
        for (int i = 0; i < 8; ++i) arb[i] = (__bf16)0.f;
        if (q < 2) {
            int pe = sSD[wv][32 + m];
            if (bfm) {
                arb = *(const bfv8*)((const __bf16*)rbf + (size_t)pe * 16 + kq);
            } else {
                const float* rp = (const float*)rbf + (size_t)pe * 16 + kq;
                #pragma unroll
                for (int i = 0; i < 8; ++i) arb[i] = (__bf16)rp[i];
            }
        }
        const __bf16* wb = (const __bf16*)WrbfT;
        #pragma unroll
        for (int nt = 0; nt < 14; ++nt) {
            bfv8 bb = *(const bfv8*)(wb + (size_t)(nt * 16 + m) * 32 + kq);
            f4 z = {0.f, 0.f, 0.f, 0.f};
            w1f[nt] = mf(arb, bb, z);
        }
    }

    // ---- gather messages (vectorized via swizzled node arrays, batched) ----
    bfv4 gs_[4], gd_[4];
    bfv8 gv_[4], gw_[4];
    #pragma unroll
    for (int r = 0; r < 4; ++r) {
        int e = q * 4 + r;
        int s = sSD[wv][e], d = sSD[wv][16 + e];
        gs_[r] = *(const bfv4*)((const __bf16*)ssrc + (size_t)s * 64 + m * 4);
        gd_[r] = *(const bfv4*)((const __bf16*)sdst + (size_t)d * 64 + m * 4);
        gv_[r] = *(const bfv8*)((const __bf16*)vsrc + (size_t)s * 128 + m * 8);
        gw_[r] = *(const bfv8*)((const __bf16*)vdst + (size_t)d * 128 + m * 8);
    }
    float ms_[4][4], mv_[4][2][3];
    #pragma unroll
    for (int r = 0; r < 4; ++r) {
        #pragma unroll
        for (int nt = 0; nt < 4; ++nt)
            ms_[r][nt] = (float)gs_[r][nt] + (float)gd_[r][nt];
        #pragma unroll
        for (int x = 0; x < 3; ++x)
            #pragma unroll
            for (int n2 = 0; n2 < 2; ++n2)
                mv_[r][n2][x] = (float)gv_[r][2 * x + n2] + (float)gw_[r][2 * x + n2];
    }

    // ---- m1_s -> A1S; precompute plane products ----
    float sv_[4][4], qv_[4][2][3], pv_[4][2][3];
    #pragma unroll
    for (int r = 0; r < 4; ++r) {
        int e = q * 4 + r;
        float4 yy = *(const float4*)&sY[wv][e][0];
        float y0 = yy.x, yx = yy.y, yh = yy.z, yz = yy.w;
        #pragma unroll
        for (int nt = 0; nt < 4; ++nt) {
            H[A1S + e * SS + nt * 16 + m] = (__bf16)(w1f[nt][r] * ms_[r][nt] * y0);
            sv_[r][nt] = w1f[4 + nt][r] * ms_[r][nt];
        }
        #pragma unroll
        for (int n2 = 0; n2 < 2; ++n2) {
            float dot = mv_[r][n2][0] * yx + mv_[r][n2][1] * yh + mv_[r][n2][2] * yz;
            H[A1S + e * SS + 64 + n2 * 16 + m] = (__bf16)(w1f[10 + n2][r] * dot * SQRT3_INV);
            #pragma unroll
            for (int x = 0; x < 3; ++x) {
                qv_[r][n2][x] = w1f[8 + n2][r]  * mv_[r][n2][x];
                pv_[r][n2][x] = w1f[12 + n2][r] * mv_[r][n2][x];
            }
        }
    }

    // ---- S5 (early so sv_/qv_/pv_ die): m1_v planes -> vv (ungated) ----
    f4 vv[3][2];
    #pragma unroll
    for (int x = 0; x < 3; ++x)
        #pragma unroll
        for (int nt = 0; nt < 2; ++nt)
            vv[x][nt] = (f4){0.f, 0.f, 0.f, 0.f};
    W_M1(0, P0);
    MMA_V(P0, (const __bf16*)WvvalT, vv[0][0], vv[0][1]);
    W_M1(1, P0);
    MMA_V(P0, (const __bf16*)WvvalT, vv[1][0], vv[1][1]);
    W_M1(2, P0);
    MMA_V(P0, (const __bf16*)WvvalT, vv[2][0], vv[2][1]);

    // ---- a1s fragments (A1S region then reusable) ----
    bfv8 a1s0 = *(const bfv8*)(H + A1S + m * SS + 0  + kq);
    bfv8 a1s1 = *(const bfv8*)(H + A1S + m * SS + 32 + kq);
    bfv8 a1s2 = *(const bfv8*)(H + A1S + m * SS + 64 + kq);

    // ---- S2: val_s = m1_s @ Ws_val; PRE-sigmoid -> VAL (alias A1S), sigmoid -> regs ----
    f4 vals[4];
    #pragma unroll
    for (int nt = 0; nt < 4; ++nt) {
        const __bf16* bp = (const __bf16*)WsvalT + (size_t)(nt * 16 + m) * 96 + kq;
        f4 acc = {0.f, 0.f, 0.f, 0.f};
        acc = mf(a1s0, *(const bfv8*)(bp),      acc);
        acc = mf(a1s1, *(const bfv8*)(bp + 32), acc);
        acc = mf(a1s2, *(const bfv8*)(bp + 64), acc);
        vals[nt] = acc;
    }
    #pragma unroll
    for (int nt = 0; nt < 4; ++nt)
        #pragma unroll
        for (int r = 0; r < 4; ++r) {
            float v = vals[nt][r];
            H[VAL + (q * 4 + r) * SA + nt * 16 + m] = (__bf16)v;   // PRE-sigmoid
            vals[nt][r] = 1.f / (1.f + __expf(-v));
        }

    // ---- S3: gate = sigmoid(val_s_pre @ Wg); gate vv ----
    {
        bfv8 av0 = *(const bfv8*)(H + VAL + m * SA + 0  + kq);
        bfv8 av1 = *(const bfv8*)(H + VAL + m * SA + 32 + kq);
        f4 gate[2];
        #pragma unroll
        for (int nt = 0; nt < 2; ++nt) {
            const __bf16* bp = (const __bf16*)WgT + (size_t)(nt * 16 + m) * 64 + kq;
            f4 acc = {0.f, 0.f, 0.f, 0.f};
            acc = mf(av0, *(const bfv8*)(bp),      acc);
            acc = mf(av1, *(const bfv8*)(bp + 32), acc);
            gate[nt] = acc;
        }
        #pragma unroll
        for (int nt = 0; nt < 2; ++nt)
            #pragma unroll
            for (int r = 0; r < 4; ++r)
                gate[nt][r] = 1.f / (1.f + __expf(-gate[nt][r]));
        #pragma unroll
        for (int x = 0; x < 3; ++x)
            #pragma unroll
            for (int nt = 0; nt < 2; ++nt)
                #pragma unroll
                for (int r = 0; r < 4; ++r)
                    vv[x][nt][r] *= gate[nt][r];
    }

    // ---- S4: attention logits + ex ----
    float ex_[4][4];
    #pragma unroll
    for (int nt = 0; nt < 4; ++nt) {
        const __bf16* bp = (const __bf16*)WalphaT + (size_t)(nt * 16 + m) * 96 + kq;
        f4 acc = {0.f, 0.f, 0.f, 0.f};
        acc = mf(a1s0, *(const bfv8*)(bp),      acc);
        acc = mf(a1s1, *(const bfv8*)(bp + 32), acc);
        acc = mf(a1s2, *(const bfv8*)(bp + 64), acc);
        float ad = b2f(adotB[nt * 16 + m]);
        #pragma unroll
        for (int r = 0; r < 4; ++r) {
            float tv = acc[r];
            tv = tv > 0.f ? tv : 0.2f * tv;
            tv *= ad;
            tv += __shfl_xor(tv, 1); tv += __shfl_xor(tv, 2);
            tv += __shfl_xor(tv, 4); tv += __shfl_xor(tv, 8);
            tv = fminf(fmaxf(tv, -60.f), 60.f);
            ex_[nt][r] = __expf(tv);
        }
    }

    // ---- S6/S7 scalar part: m2_s -> A1S (VAL now dead), project -> hs ----
    float c2ss[4], c2sv[4];
    #pragma unroll
    for (int nt = 0; nt < 4; ++nt) {
        c2ss[nt] = b2f(w2B[nt * 16 + m]);
        c2sv[nt] = b2f(w2B[64 + nt * 16 + m]);
    }
    float c2vs[2], c2v0[2], c2v1[2];
    #pragma unroll
    for (int nt = 0; nt < 2; ++nt) {
        c2vs[nt] = b2f(w2B[128 + nt * 16 + m]);
        c2v0[nt] = b2f(w2B[160 + nt * 16 + m]);
        c2v1[nt] = b2f(w2B[192 + nt * 16 + m]);
    }
    #pragma unroll
    for (int r = 0; r < 4; ++r) {
        int e = q * 4 + r;
        float4 yy = *(const float4*)&sY[wv][e][0];
        float y0 = yy.x, yx = yy.y, yh = yy.z, yz = yy.w;
        #pragma unroll
        for (int nt = 0; nt < 4; ++nt)
            H[A1S + e * SS + nt * 16 + m] = (__bf16)(c2ss[nt] * vals[nt][r] * y0);
        #pragma unroll
        for (int n2 = 0; n2 < 2; ++n2) {
            float dotv = vv[0][n2][r] * yx + vv[1][n2][r] * yh + vv[2][n2][r] * yz;
            H[A1S + e * SS + 64 + n2 * 16 + m] = (__bf16)(c2v0[n2] * dotv * SQRT3_INV);
        }
    }
    f4 hs[4];
    {
        bfv8 a2s0 = *(const bfv8*)(H + A1S + m * SS + 0  + kq);
        bfv8 a2s1 = *(const bfv8*)(H + A1S + m * SS + 32 + kq);
        bfv8 a2s2 = *(const bfv8*)(H + A1S + m * SS + 64 + kq);
        #pragma unroll
        for (int nt = 0; nt < 4; ++nt) {
            const __bf16* bp = (const __bf16*)WsvlinT + (size_t)(nt * 16 + m) * 96 + kq;
            f4 acc = {0.f, 0.f, 0.f, 0.f};
            acc = mf(a2s0, *(const bfv8*)(bp),      acc);
            acc = mf(a2s1, *(const bfv8*)(bp + 32), acc);
            acc = mf(a2s2, *(const bfv8*)(bp + 64), acc);
            hs[nt] = acc;
        }
    }

    // ---- S6/S7 vector part: m2_v planes through single buffer -> hv ----
    f4 hv[3][2];
    #pragma unroll
    for (int x = 0; x < 3; ++x)
        #pragma unroll
        for (int nt = 0; nt < 2; ++nt)
            hv[x][nt] = (f4){0.f, 0.f, 0.f, 0.f};
    W_M2(0, P0);
    MMA_V(P0, (const __bf16*)WvvlinT, hv[0][0], hv[0][1]);
    W_M2(1, P0);
    MMA_V(P0, (const __bf16*)WvvlinT, hv[1][0], hv[1][1]);
    W_M2(2, P0);
    MMA_V(P0, (const __bf16*)WvvlinT, hv[2][0], hv[2][1]);

    // ---- S8: register-space segmented reduction per q-group, direct atomics ----
    {
        int nval = (int)((E - eb) < 16 ? (E - eb) : 16);
        const int e0 = q * 4;
        float as_[4] = {0.f, 0.f, 0.f, 0.f};
        float av_[3][2] = {{0.f,0.f},{0.f,0.f},{0.f,0.f}};
        float de_ = 0.f;
        #pragma unroll
        for (int r = 0; r < 4; ++r) {
            int e = e0 + r;
            bool valid = (e < nval);
            int d = sSD[wv][16 + (valid ? e : 0)];
            if (valid) {
                #pragma unroll
                for (int nt = 0; nt < 4; ++nt) as_[nt] += ex_[nt][r] * hs[nt][r];
                #pragma unroll
                for (int nt = 0; nt < 2; ++nt) {
                    float exv = (m >= 8) ? ex_[2 * nt + 1][r] : ex_[2 * nt][r];
                    #pragma unroll
                    for (int x = 0; x < 3; ++x) av_[x][nt] += exv * hv[x][nt][r];
                }
                if (m < 4) de_ += ex_[m][r];
            }
            bool last;
            if (r == 3) {
                last = valid;
            } else {
                int en = e + 1;
                last = valid && ((en >= nval) || (sSD[wv][16 + en] != d));
            }
            if (last) {
                float* rowp = agg + (size_t)d * 160;
                #pragma unroll
                for (int nt = 0; nt < 4; ++nt)
                    unsafeAtomicAdd(rowp + nt * 40 + m, as_[nt]);
                #pragma unroll
                for (int nt = 0; nt < 2; ++nt) {
                    int hh = nt * 2 + (m >> 3), dd2 = m & 7;
                    #pragma unroll
                    for (int x = 0; x < 3; ++x)
                        unsafeAtomicAdd(rowp + hh * 40 + 16 + dd2 * 3 + x, av_[x][nt]);
                }
                if (m < 4) unsafeAtomicAdd(den + (size_t)d * 4 + m, de_);
                #pragma unroll
                for (int nt = 0; nt < 4; ++nt) as_[nt] = 0.f;
                #pragma unroll
                for (int nt = 0; nt < 2; ++nt)
                    #pragma unroll
                    for (int x = 0; x < 3; ++x) av_[x][nt] = 0.f;
                de_ = 0.f;
            }
        }
    }
}

// ---------------- Kernel 3: normalize + output projection + residual (4 nodes/block) ----------------
template<int BF>
__device__ __forceinline__ void out_impl(
    const void* node, const float* den, const float* agg,
    const void* Wps, const void* Wpv, void* out,
    float* shs, float* shv, float* sinv, int n, int lane)
{
    if (lane < 4) sinv[lane] = 1.f / (den[(size_t)n * 4 + lane] + 1e-16f);
    for (int idx = lane; idx < 160; idx += 64) {
        int h = idx / 40, r = idx - h * 40;
        float val = agg[(size_t)n * 160 + idx] * sinv[h];
        if (r < 16) shs[h * 16 + r] = val;
        else { int rr = r - 16; int dd = rr / 3, x = rr - dd * 3; shv[x * 32 + h * 8 + dd] = val; }
    }

    float acc = ldf<BF>(node, (size_t)n * 160 + lane);
    for (int c = 0; c < 64; ++c) acc += shs[c] * ldf<BF>(Wps, c * 64 + lane);
    stf<BF>(out, (size_t)n * 160 + lane, acc);

    {
        int idx = lane; int dd = idx / 3, x = idx - dd * 3;
        float a = ldf<BF>(node, (size_t)n * 160 + 64 + idx);
        for (int c = 0; c < 32; ++c) a += shv[x * 32 + c] * ldf<BF>(Wpv, c * 32 + dd);
        stf<BF>(out, (size_t)n * 160 + 64 + idx, a);
    }
    if (lane < 32) {
        int idx = 64 + lane; int dd = idx / 3, x = idx - dd * 3;
        float a = ldf<BF>(node, (size_t)n * 160 + 64 + idx);
        for (int c = 0; c < 32; ++c) a += shv[x * 32 + c] * ldf<BF>(Wpv, c * 32 + dd);
        stf<BF>(out, (size_t)n * 160 + 64 + idx, a);
    }
}

__global__ __launch_bounds__(256) void k_out(
    const void* node, const float* den, const float* agg,
    const void* Wps, const void* Wpv, void* out,
    const int* flags, int N)
{
    __shared__ float shs[4][64];
    __shared__ float shv[4][96];
    __shared__ float sinv[4][4];
    int wv = threadIdx.x >> 6, lane = threadIdx.x & 63;
    int n = blockIdx.x * 4 + wv; if (n >= N) return;
    if (flags[0])
        out_impl<1>(node, den, agg, Wps, Wpv, out, shs[wv], shv[wv], sinv[wv], n, lane);
    else
        out_impl<0>(node, den, agg, Wps, Wpv, out, shs[wv], shv[wv], sinv[wv], n, lane);
}

// ---------------- Launch ----------------
extern "C" void kernel_launch(void* const* d_in, const int* in_sizes, int n_in,
                              void* d_out, int out_size, void* d_ws, size_t ws_size,
                              hipStream_t stream)
{
    const void* node   = d_in[0];
    const void* eidx   = d_in[1];
    const void* rbf    = d_in[2];
    const void* rsh    = d_in[3];
    const void* gs     = d_in[4];
    const void* bs     = d_in[5];
    const void* gv     = d_in[6];
    const void* Wss    = d_in[7];
    const void* Wvs    = d_in[8];
    const void* Wsd    = d_in[9];
    const void* Wvd    = d_in[10];
    const void* Wrbf   = d_in[11];
    const void* Walpha = d_in[12];
    const void* adot   = d_in[13];
    const void* Wsval  = d_in[14];
    const void* Wvval  = d_in[15];
    const void* Wg     = d_in[16];
    const void* w2ss   = d_in[17];
    const void* w2sv   = d_in[18];
    const void* w2vs   = d_in[19];
    const void* w2vv0  = d_in[20];
    const void* w2vv1  = d_in[21];
    const void* Wsvlin = d_in[22];
    const void* Wvvlin = d_in[23];
    const void* Wps    = d_in[24];
    const void* Wpv    = d_in[25];

    int N = in_sizes[0] / 160;
    int E = in_sizes[1] / 2;

    char* base = (char*)d_ws;
    int*  flags   = (int*)base;                  // 16 B
    bf16* WalphaT = (bf16*)(base + 16);
    bf16* WsvalT  = WalphaT + 6144;
    bf16* WsvlinT = WsvalT  + 6144;
    bf16* WvvalT  = WsvlinT + 6144;
    bf16* WvvlinT = WvvalT  + 4096;
    bf16* WgT     = WvvlinT + 4096;
    bf16* WrbfT   = WgT     + 2048;
    bf16* adotB   = WrbfT   + 7168;              // 224 x 32 zero-padded
    bf16* w2B     = adotB   + 64;
    bf16* ssrc    = w2B     + 224;
    bf16* sdst    = ssrc + (size_t)N * 64;
    bf16* vsrc    = sdst + (size_t)N * 64;       // swizzled, stride 128
    bf16* vdst    = vsrc + (size_t)N * 128;
    float* den    = (float*)(vdst + (size_t)N * 128);
    float* agg    = den + (size_t)N * 4;
    int*  cnt     = (int*)(agg + (size_t)N * 160);
    int*  perm    = cnt + N;

    k_sniff<<<1, 256, 0, stream>>>(node, eidx, flags);
    // den (4N) + agg (160N) + cnt (N) are contiguous: zero all in one launch
    int zn = N * 165;
    k_zero<<<(zn + 255) / 256, 256, 0, stream>>>(den, zn);

    // counting sort of edges by dst
    int nbe = (E + 255) / 256;
    k_hist<<<nbe, 256, 0, stream>>>(eidx, cnt, flags, E);
    k_scan<<<1, 1024, 0, stream>>>(cnt, N);
    k_perm<<<nbe, 256, 0, stream>>>(eidx, cnt, perm, flags, E);

    k_prep<<<16, 256, 0, stream>>>(Walpha, Wsval, Wsvlin, Wvval, Wvvlin, Wg, Wrbf, adot,
                                   w2ss, w2sv, w2vs, w2vv0, w2vv1,
                                   WalphaT, WsvalT, WsvlinT, WvvalT, WvvlinT, WgT, WrbfT,
                                   adotB, w2B, flags);

    int nbn = (N + 3) / 4;
    k_node<<<nbn, 256, 0, stream>>>(node, gs, bs, gv, Wss, Wvs, Wsd, Wvd,
                                    ssrc, sdst, vsrc, vdst, flags, N);

    int nb = (E + 63) / 64;
    k_edge<<<nb, 256, 0, stream>>>(eidx, rbf, rsh,
                                   WalphaT, WsvalT, WsvlinT, WvvalT, WvvlinT, WgT, WrbfT,
                                   adotB, w2B, ssrc, sdst, vsrc, vdst, perm, den, agg, flags, E);

    int nbo = (N + 3) / 4;
    k_out<<<nbo, 256, 0, stream>>>(node, den, agg, Wps, Wpv, d_out, flags, N);
}

// Round 5
// 468.587 us; speedup vs baseline: 1.6800x; 1.3577x over previous
//
#include <hip/hip_runtime.h>
#include <hip/hip_bf16.h>
#include <cstddef>

typedef __hip_bfloat16 bf16;
typedef __bf16 bfv8 __attribute__((ext_vector_type(8)));
typedef __bf16 bfv4 __attribute__((ext_vector_type(4)));
typedef __bf16 bfv2 __attribute__((ext_vector_type(2)));
typedef float f4 __attribute__((ext_vector_type(4)));

#define EPSN 1e-5f
#define SQRT3_INV 0.57735026918962576f
#define SQRT2_INV 0.70710678118654752f

__device__ __forceinline__ float b2f(bf16 x) { return __bfloat162float(x); }

template<int BF> __device__ __forceinline__ float ldf(const void* p, size_t i) {
    if (BF) return __bfloat162float(((const bf16*)p)[i]);
    return ((const float*)p)[i];
}
__device__ __forceinline__ float ldr(const void* p, size_t i, int bfm) {
    return bfm ? __bfloat162float(((const bf16*)p)[i]) : ((const float*)p)[i];
}
template<int BF> __device__ __forceinline__ void stf(void* p, size_t i, float v) {
    if (BF) ((bf16*)p)[i] = __float2bfloat16(v);
    else    ((float*)p)[i] = v;
}

__device__ __forceinline__ float wave_sum64(float x) {
    #pragma unroll
    for (int m = 1; m < 64; m <<= 1) x += __shfl_xor(x, m, 64);
    return x;
}

__device__ __forceinline__ f4 mf(bfv8 a, bfv8 b, f4 c) {
    return __builtin_amdgcn_mfma_f32_16x16x32_bf16(a, b, c, 0, 0, 0);
}

// ---------------- Sniffer ----------------
__global__ __launch_bounds__(256) void k_sniff(const void* node, const void* eidx, int* flags)
{
    int t = threadIdx.x;
    __shared__ int cnt;
    __shared__ unsigned orr;
    if (t == 0) { cnt = 0; orr = 0u; }
    __syncthreads();
    unsigned w  = ((const unsigned*)node)[t];
    unsigned lo = w & 0xFFFFu;
    int e_lo = (int)((lo >> 7) & 0xFF);
    if (e_lo >= 96 && e_lo <= 140) atomicAdd(&cnt, 1);
    unsigned odd = ((const unsigned*)eidx)[2 * t + 1];
    atomicOr(&orr, odd);
    __syncthreads();
    if (t == 0) {
        flags[0] = (cnt >= 128) ? 1 : 0;   // 1 = bf16 inputs
        flags[1] = (orr == 0u) ? 1 : 0;    // 1 = int64 edge_index
    }
}

__global__ __launch_bounds__(256) void k_zero(float* p, int n)
{
    int i = blockIdx.x * 256 + threadIdx.x;
    if (i < n) p[i] = 0.f;
}

// ---------------- Counting sort by dst ----------------
__global__ __launch_bounds__(256) void k_hist(const void* eidx, int* cnt,
                                              const int* flags, int E)
{
    int e = blockIdx.x * 256 + threadIdx.x;
    if (e >= E) return;
    int d = flags[1] ? (int)((const long long*)eidx)[(long long)E + e]
                     : ((const int*)eidx)[(size_t)E + e];
    atomicAdd(&cnt[d], 1);
}

__global__ __launch_bounds__(1024) void k_scan(int* cnt, int N)
{
    __shared__ int wsum[16];
    int t = threadIdx.x;
    int lane = t & 63, w = t >> 6;
    int chunk = (N + 1023) >> 10;
    int lo = t * chunk, hi = lo + chunk;
    if (hi > N) hi = N; if (lo > N) lo = N;
    int sum = 0;
    for (int i = lo; i < hi; ++i) sum += cnt[i];
    int x = sum;
    #pragma unroll
    for (int off = 1; off < 64; off <<= 1) {
        int y = __shfl_up(x, off, 64);
        if (lane >= off) x += y;
    }
    if (lane == 63) wsum[w] = x;
    __syncthreads();
    if (t < 64) {
        int v = (lane < 16) ? wsum[lane] : 0;
        #pragma unroll
        for (int off = 1; off < 16; off <<= 1) {
            int y = __shfl_up(v, off, 64);
            if (lane >= off) v += y;
        }
        if (lane < 16) wsum[lane] = v;
    }
    __syncthreads();
    int acc = x - sum + (w ? wsum[w - 1] : 0);
    for (int i = lo; i < hi; ++i) { int v = cnt[i]; cnt[i] = acc; acc += v; }
}

__global__ __launch_bounds__(256) void k_perm(const void* eidx, int* cnt, int* perm,
                                              const int* flags, int E)
{
    int e = blockIdx.x * 256 + threadIdx.x;
    if (e >= E) return;
    int d = flags[1] ? (int)((const long long*)eidx)[(long long)E + e]
                     : ((const int*)eidx)[(size_t)E + e];
    int pos = atomicAdd(&cnt[d], 1);
    perm[pos] = e;
}

// ---------------- Prep: transpose weights to bf16 [n][k] ----------------
template<int BF>
__device__ __forceinline__ void prep_impl(
    const void* Walpha, const void* Wsval, const void* Wsvlin,
    const void* Wvval, const void* Wvvlin, const void* Wg,
    const void* Wrbf, const void* adot,
    const void* w2ss, const void* w2sv, const void* w2vs,
    const void* w2vv0, const void* w2vv1,
    bf16* WalphaT, bf16* WsvalT, bf16* WsvlinT,
    bf16* WvvalT, bf16* WvvlinT, bf16* WgT,
    bf16* WrbfT, bf16* adotB, bf16* w2B)
{
    int t = threadIdx.x + blockIdx.x * 256;
    int T = gridDim.x * 256;
    for (int i = t; i < 96 * 64; i += T) {
        int c = i >> 6, n = i & 63;
        WalphaT[n * 96 + c] = __float2bfloat16(ldf<BF>(Walpha, i));
        WsvalT [n * 96 + c] = __float2bfloat16(ldf<BF>(Wsval,  i));
        WsvlinT[n * 96 + c] = __float2bfloat16(ldf<BF>(Wsvlin, i));
    }
    for (int i = t; i < 128 * 32; i += T) {
        int c = i >> 5, n = i & 31;
        WvvalT [n * 128 + c] = __float2bfloat16(ldf<BF>(Wvval,  i));
        WvvlinT[n * 128 + c] = __float2bfloat16(ldf<BF>(Wvvlin, i));
    }
    for (int i = t; i < 64 * 32; i += T) {
        int c = i >> 5, n = i & 31;
        WgT[n * 64 + c] = __float2bfloat16(ldf<BF>(Wg, i));
    }
    for (int i = t; i < 224 * 32; i += T) {
        int c = i >> 5, b = i & 31;
        WrbfT[i] = __float2bfloat16(b < 16 ? ldf<BF>(Wrbf, b * 224 + c) : 0.f);
    }
    if (t < 64) adotB[t] = __float2bfloat16(ldf<BF>(adot, t));
    if (t < 64) w2B[t]      = __float2bfloat16(ldf<BF>(w2ss, t));
    if (t < 64) w2B[64 + t] = __float2bfloat16(ldf<BF>(w2sv, t));
    if (t < 32) {
        w2B[128 + t] = __float2bfloat16(ldf<BF>(w2vs, t));
        w2B[160 + t] = __float2bfloat16(ldf<BF>(w2vv0, t));
        w2B[192 + t] = __float2bfloat16(ldf<BF>(w2vv1, t));
    }
}

__global__ __launch_bounds__(256) void k_prep(
    const void* Walpha, const void* Wsval, const void* Wsvlin,
    const void* Wvval, const void* Wvvlin, const void* Wg,
    const void* Wrbf, const void* adot,
    const void* w2ss, const void* w2sv, const void* w2vs,
    const void* w2vv0, const void* w2vv1,
    bf16* WalphaT, bf16* WsvalT, bf16* WsvlinT,
    bf16* WvvalT, bf16* WvvlinT, bf16* WgT,
    bf16* WrbfT, bf16* adotB, bf16* w2B, const int* flags)
{
    if (flags[0])
        prep_impl<1>(Walpha, Wsval, Wsvlin, Wvval, Wvvlin, Wg, Wrbf, adot,
                     w2ss, w2sv, w2vs, w2vv0, w2vv1,
                     WalphaT, WsvalT, WsvlinT, WvvalT, WvvlinT, WgT, WrbfT, adotB, w2B);
    else
        prep_impl<0>(Walpha, Wsval, Wsvlin, Wvval, Wvvlin, Wg, Wrbf, adot,
                     w2ss, w2sv, w2vs, w2vv0, w2vv1,
                     WalphaT, WsvalT, WsvlinT, WvvalT, WvvlinT, WgT, WrbfT, adotB, w2B);
}

// ---------------- Kernel 1: per-node layernorm + projections (4 nodes/block) ----------------
// Outputs are stored SWIZZLED for vectorized gather in k_edge:
//   ssrc/sdst [n][64]: channel c at position (c&15)*4 + (c>>4)          (bfv4 per lane)
//   vA [n][64]: x in {0,1}: channel x*32+cc at (cc&15)*4 + x*2 + (cc>>4) (bfv4 per lane)
//   vB [n][32]: x == 2:     channel 64+cc   at (cc&15)*2 + (cc>>4)       (bfv2 per lane)
// (v packed to 192 B/node vs 256 B: kills the 2 dead slots -> -64 B per random src fetch)
template<int BF>
__device__ __forceinline__ void node_impl(
    const void* node, const void* gs, const void* bs, const void* gv,
    const void* Wss, const void* Wvs, const void* Wsd, const void* Wvd,
    bf16* ssrc, bf16* sdst, bf16* vsrcA, bf16* vdstA, bf16* vsrcB, bf16* vdstB,
    float* shs, float* shv, int n, int lane)
{
    size_t nb = (size_t)n * 160;

    float s  = ldf<BF>(node, nb + lane);
    float mu = wave_sum64(s) * (1.f / 64.f);
    float d  = s - mu;
    float var = wave_sum64(d * d) * (1.f / 64.f);
    float sn  = d * rsqrtf(var + EPSN) * ldf<BF>(gs, lane) + ldf<BF>(bs, lane);
    shs[lane] = sn;

    float v0 = 0.f, v1 = 0.f, v2 = 0.f, qq = 0.f;
    if (lane < 32) {
        v0 = ldf<BF>(node, nb + 64 + lane * 3 + 0);
        v1 = ldf<BF>(node, nb + 64 + lane * 3 + 1);
        v2 = ldf<BF>(node, nb + 64 + lane * 3 + 2);
        qq = v0 * v0 + v1 * v1 + v2 * v2;
    }
    float msq = wave_sum64(qq) * (1.f / 32.f);
    float inv = rsqrtf(msq + EPSN);
    if (lane < 32) {
        float g = ldf<BF>(gv, lane);
        shv[0 * 32 + lane] = v0 * inv * g;
        shv[1 * 32 + lane] = v1 * inv * g;
        shv[2 * 32 + lane] = v2 * inv * g;
    }
    // same-wave LDS write->read: in-order, no barrier needed

    float a1 = 0.f, a2 = 0.f;
    for (int c = 0; c < 64; ++c) {
        float sc = shs[c];
        a1 += sc * ldf<BF>(Wss, c * 64 + lane);
        a2 += sc * ldf<BF>(Wsd, c * 64 + lane);
    }
    {
        int cs = lane;
        int pos = (cs & 15) * 4 + (cs >> 4);
        ssrc[(size_t)n * 64 + pos] = __float2bfloat16(a1);
        sdst[(size_t)n * 64 + pos] = __float2bfloat16(a2);
    }

    {
        int x = lane >> 5, dd = lane & 31;
        float p1 = 0.f, p2 = 0.f;
        for (int c = 0; c < 32; ++c) {
            float vc = shv[x * 32 + c];
            p1 += vc * ldf<BF>(Wvs, c * 32 + dd);
            p2 += vc * ldf<BF>(Wvd, c * 32 + dd);
        }
        int mm = dd & 15, n2 = dd >> 4;
        int pos = mm * 4 + x * 2 + n2;
        vsrcA[(size_t)n * 64 + pos] = __float2bfloat16(p1);
        vdstA[(size_t)n * 64 + pos] = __float2bfloat16(p2);
    }
    if (lane < 32) {
        int dd = lane;
        float p1 = 0.f, p2 = 0.f;
        for (int c = 0; c < 32; ++c) {
            float vc = shv[2 * 32 + c];
            p1 += vc * ldf<BF>(Wvs, c * 32 + dd);
            p2 += vc * ldf<BF>(Wvd, c * 32 + dd);
        }
        int mm = dd & 15, n2 = dd >> 4;
        int pos = mm * 2 + n2;
        vsrcB[(size_t)n * 32 + pos] = __float2bfloat16(p1);
        vdstB[(size_t)n * 32 + pos] = __float2bfloat16(p2);
    }
}

__global__ __launch_bounds__(256) void k_node(
    const void* node, const void* gs, const void* bs, const void* gv,
    const void* Wss, const void* Wvs, const void* Wsd, const void* Wvd,
    bf16* ssrc, bf16* sdst, bf16* vsrcA, bf16* vdstA, bf16* vsrcB, bf16* vdstB,
    const int* flags, int N)
{
    __shared__ float shs[4][64];
    __shared__ float shv[4][96];
    int wv = threadIdx.x >> 6, lane = threadIdx.x & 63;
    int n = blockIdx.x * 4 + wv; if (n >= N) return;
    if (flags[0])
        node_impl<1>(node, gs, bs, gv, Wss, Wvs, Wsd, Wvd,
                     ssrc, sdst, vsrcA, vdstA, vsrcB, vdstB, shs[wv], shv[wv], n, lane);
    else
        node_impl<0>(node, gs, bs, gv, Wss, Wvs, Wsd, Wvd,
                     ssrc, sdst, vsrcA, vdstA, vsrcB, vdstB, shs[wv], shv[wv], n, lane);
}

// ---------------- Kernel 2: fused MFMA edge pass over dst-sorted edges ----------------
// R2 structure (known-good, 256us): 4 waves/block, 16 edges/wave, ping-pong plane
// buffers, LDS-staged S8, __launch_bounds__(256,3) (natural ~84-130 VGPR, NO tight cap
// -- R3/R4 proved caps <=128 force catastrophic spill). LDS 50,176 -> 3 blocks/CU;
// VGPR headroom up to ~170 is free, spent on held weight fragments (S5/S7v reuse).
static constexpr int SS  = 104;
static constexpr int A1S = 0;
static constexpr int SV  = 136;
static constexpr int P0  = 16 * SS;           // 1664
static constexpr int P1  = P0 + 16 * SV;      // 3840
static constexpr int VAL = 0;                 // alias of A1S region
static constexpr int SA  = 72;
static constexpr int HSZ = P1 + 16 * SV;      // 6016 elems = 12,032 B

// m1_v plane X write into buffer PB (uses sv_, qv_, pv_, sY)
#define W_M1(X, PB) do { \
    constexpr int x_ = (X), x1_ = ((X)+1)%3, x2_ = ((X)+2)%3; \
    _Pragma("unroll") \
    for (int r = 0; r < 4; ++r) { \
        int e = q * 4 + r; \
        float4 yy = *(const float4*)&sY[wv][e][0]; \
        float y0 = yy.x; float yv[3] = {yy.y, yy.z, yy.w}; \
        _Pragma("unroll") \
        for (int nt = 0; nt < 4; ++nt) \
            H[(PB) + e * SV + nt * 16 + m] = (__bf16)(sv_[r][nt] * yv[x_]); \
        _Pragma("unroll") \
        for (int n2 = 0; n2 < 2; ++n2) { \
            int c = 64 + n2 * 16 + m; \
            H[(PB) + e * SV + c] = (__bf16)(qv_[r][n2][x_] * y0); \
            float cr = pv_[r][n2][x1_] * yv[x2_] - pv_[r][n2][x2_] * yv[x1_]; \
            H[(PB) + e * SV + 32 + c] = (__bf16)(cr * SQRT2_INV); \
        } \
    } \
} while (0)

// m2_v plane X write into buffer PB (uses vals, vv, c2*, sY)
#define W_M2(X, PB) do { \
    constexpr int x_ = (X), x1_ = ((X)+1)%3, x2_ = ((X)+2)%3; \
    _Pragma("unroll") \
    for (int r = 0; r < 4; ++r) { \
        int e = q * 4 + r; \
        float4 yy = *(const float4*)&sY[wv][e][0]; \
        float y0 = yy.x; float yv[3] = {yy.y, yy.z, yy.w}; \
        _Pragma("unroll") \
        for (int nt = 0; nt < 4; ++nt) \
            H[(PB) + e * SV + nt * 16 + m] = (__bf16)(c2sv[nt] * vals[nt][r] * yv[x_]); \
        _Pragma("unroll") \
        for (int n2 = 0; n2 < 2; ++n2) { \
            int c = 64 + n2 * 16 + m; \
            H[(PB) + e * SV + c] = (__bf16)(c2vs[n2] * vv[x_][n2][r] * y0); \
            float cr = vv[x1_][n2][r] * yv[x2_] - vv[x2_][n2][r] * yv[x1_]; \
            H[(PB) + e * SV + 32 + c] = (__bf16)(c2v1[n2] * cr * SQRT2_INV); \
        } \
    } \
} while (0)

// read A-frags from plane buffer PB, accumulate with HELD weight fragments WH[8]
#define MMA_H(PB, WH, O0, O1) do { \
    bfv8 fg_[4]; \
    _Pragma("unroll") \
    for (int kt = 0; kt < 4; ++kt) \
        fg_[kt] = *(const bfv8*)(H + (PB) + m * SV + kt * 32 + kq); \
    _Pragma("unroll") \
    for (int kt = 0; kt < 4; ++kt) { \
        O0 = mf(fg_[kt], WH[kt],     O0); \
        O1 = mf(fg_[kt], WH[4 + kt], O1); \
    } \
} while (0)

__global__ __launch_bounds__(256, 3) void k_edge(
    const void* __restrict__ eidx, const void* __restrict__ rbf, const void* __restrict__ rsh,
    const bf16* __restrict__ WalphaT, const bf16* __restrict__ WsvalT, const bf16* __restrict__ WsvlinT,
    const bf16* __restrict__ WvvalT, const bf16* __restrict__ WvvlinT, const bf16* __restrict__ WgT,
    const bf16* __restrict__ WrbfT, const bf16* __restrict__ adotB, const bf16* __restrict__ w2B,
    const bf16* __restrict__ ssrc, const bf16* __restrict__ sdst,
    const bf16* __restrict__ vsrcA, const bf16* __restrict__ vdstA,
    const bf16* __restrict__ vsrcB, const bf16* __restrict__ vdstB,
    const int* __restrict__ perm,
    float* __restrict__ den, float* __restrict__ agg,
    const int* __restrict__ flags, int E)
{
    const int bfm = flags[0];
    const int i64 = flags[1];

    __shared__ __align__(16) __bf16 sH[4][HSZ];
    __shared__ __align__(16) float sY[4][16][4];
    __shared__ int sSD[4][48];   // [0..15]=src, [16..31]=dst, [32..47]=permuted edge id

    int wv = threadIdx.x >> 6, l = threadIdx.x & 63;
    int q = l >> 4, m = l & 15;
    const int kq = q * 8;

    // XCD-chunked bijective block swizzle (T1, m204): contiguous sorted-dst
    // ranges per XCD -> dst-side gather slice (~1 MB) becomes L2-resident per XCD.
    int bid;
    {
        int nwg = gridDim.x, orig = blockIdx.x;
        int qq_ = nwg >> 3, rr_ = nwg & 7;
        int xcd = orig & 7, off = orig >> 3;
        bid = (xcd < rr_ ? xcd * (qq_ + 1) : rr_ * (qq_ + 1) + (xcd - rr_) * qq_) + off;
    }
    long long eb = ((long long)bid * 4 + wv) * 16;
    if (eb >= E) return;        // wave-uniform; no barriers in this kernel
    __bf16* H = &sH[wv][0];

    // ---- edge metadata (sorted position -> edge id via perm) ----
    if (l < 16) {
        long long p = eb + l; if (p > (long long)E - 1) p = E - 1;
        sSD[wv][32 + l] = perm[p];
    }
    if (l < 32) {
        int pe = sSD[wv][32 + (l & 15)];
        long long off = (l < 16) ? (long long)pe : ((long long)E + pe);
        sSD[wv][l] = i64 ? (int)((const long long*)eidx)[off] : ((const int*)eidx)[off];
    }
    {
        int pe = sSD[wv][32 + (l >> 2)];
        sY[wv][l >> 2][l & 3] = ldr(rsh, (size_t)pe * 4 + (l & 3), bfm);
    }

    // ---- S1a: w1 = rbf @ Wrbf via 14 MFMAs (K=32, k>=16 zero-padded) ----
    // D layout: lane(q,m), reg r -> w1[edge q*4+r][channel nt*16+m]
    // channels: nt 0-3 wss | 4-7 wsv | 8-9 wvs | 10-11 wv0 | 12-13 wv1
    f4 w1f[14];
    {
        bfv8 arb;
        #pragma unroll
        for (int i = 0; i < 8; ++i) arb[i] = (__bf16)0.f;
        if (q < 2) {
            int pe = sSD[wv][32 + m];
            if (bfm) {
                arb = *(const bfv8*)((const __bf16*)rbf + (size_t)pe * 16 + kq);
            } else {
                const float* rp = (const float*)rbf + (size_t)pe * 16 + kq;
                #pragma unroll
                for (int i = 0; i < 8; ++i) arb[i] = (__bf16)rp[i];
            }
        }
        const __bf16* wb = (const __bf16*)WrbfT;
        #pragma unroll
        for (int nt = 0; nt < 14; ++nt) {
            bfv8 bb = *(const bfv8*)(wb + (size_t)(nt * 16 + m) * 32 + kq);
            f4 z = {0.f, 0.f, 0.f, 0.f};
            w1f[nt] = mf(arb, bb, z);
        }
    }

    // ---- gather messages (vectorized via swizzled node arrays, batched) ----
    bfv4 gs_[4], gd_[4], gvA[4], gwA[4];
    bfv2 gvB[4], gwB[4];
    #pragma unroll
    for (int r = 0; r < 4; ++r) {
        int e = q * 4 + r;
        int s = sSD[wv][e], d = sSD[wv][16 + e];
        gs_[r] = *(const bfv4*)((const __bf16*)ssrc  + (size_t)s * 64 + m * 4);
        gd_[r] = *(const bfv4*)((const __bf16*)sdst  + (size_t)d * 64 + m * 4);
        gvA[r] = *(const bfv4*)((const __bf16*)vsrcA + (size_t)s * 64 + m * 4);
        gwA[r] = *(const bfv4*)((const __bf16*)vdstA + (size_t)d * 64 + m * 4);
        gvB[r] = *(const bfv2*)((const __bf16*)vsrcB + (size_t)s * 32 + m * 2);
        gwB[r] = *(const bfv2*)((const __bf16*)vdstB + (size_t)d * 32 + m * 2);
    }
    float ms_[4][4], mv_[4][2][3];
    #pragma unroll
    for (int r = 0; r < 4; ++r) {
        #pragma unroll
        for (int nt = 0; nt < 4; ++nt)
            ms_[r][nt] = (float)gs_[r][nt] + (float)gd_[r][nt];
        #pragma unroll
        for (int n2 = 0; n2 < 2; ++n2) {
            mv_[r][n2][0] = (float)gvA[r][0 * 2 + n2] + (float)gwA[r][0 * 2 + n2];
            mv_[r][n2][1] = (float)gvA[r][1 * 2 + n2] + (float)gwA[r][1 * 2 + n2];
            mv_[r][n2][2] = (float)gvB[r][n2]         + (float)gwB[r][n2];
        }
    }

    // ---- m1_s -> A1S; precompute plane products ----
    float sv_[4][4], qv_[4][2][3], pv_[4][2][3];
    #pragma unroll
    for (int r = 0; r < 4; ++r) {
        int e = q * 4 + r;
        float4 yy = *(const float4*)&sY[wv][e][0];
        float y0 = yy.x, yx = yy.y, yh = yy.z, yz = yy.w;
        #pragma unroll
        for (int nt = 0; nt < 4; ++nt) {
            H[A1S + e * SS + nt * 16 + m] = (__bf16)(w1f[nt][r] * ms_[r][nt] * y0);
            sv_[r][nt] = w1f[4 + nt][r] * ms_[r][nt];
        }
        #pragma unroll
        for (int n2 = 0; n2 < 2; ++n2) {
            float dot = mv_[r][n2][0] * yx + mv_[r][n2][1] * yh + mv_[r][n2][2] * yz;
            H[A1S + e * SS + 64 + n2 * 16 + m] = (__bf16)(w1f[10 + n2][r] * dot * SQRT3_INV);
            #pragma unroll
            for (int x = 0; x < 3; ++x) {
                qv_[r][n2][x] = w1f[8 + n2][r]  * mv_[r][n2][x];
                pv_[r][n2][x] = w1f[12 + n2][r] * mv_[r][n2][x];
            }
        }
    }

    // ---- a1s fragments (A1S region then reusable) ----
    bfv8 a1s0 = *(const bfv8*)(H + A1S + m * SS + 0  + kq);
    bfv8 a1s1 = *(const bfv8*)(H + A1S + m * SS + 32 + kq);
    bfv8 a1s2 = *(const bfv8*)(H + A1S + m * SS + 64 + kq);

    // ---- S2: val_s = m1_s @ Ws_val; PRE-sigmoid -> VAL (alias A1S), sigmoid -> regs ----
    f4 vals[4];
    #pragma unroll
    for (int nt = 0; nt < 4; ++nt) {
        const __bf16* bp = (const __bf16*)WsvalT + (size_t)(nt * 16 + m) * 96 + kq;
        f4 acc = {0.f, 0.f, 0.f, 0.f};
        acc = mf(a1s0, *(const bfv8*)(bp),      acc);
        acc = mf(a1s1, *(const bfv8*)(bp + 32), acc);
        acc = mf(a1s2, *(const bfv8*)(bp + 64), acc);
        vals[nt] = acc;
    }
    #pragma unroll
    for (int nt = 0; nt < 4; ++nt)
        #pragma unroll
        for (int r = 0; r < 4; ++r) {
            float v = vals[nt][r];
            H[VAL + (q * 4 + r) * SA + nt * 16 + m] = (__bf16)v;   // PRE-sigmoid
            vals[nt][r] = 1.f / (1.f + __expf(-v));
        }

    // ---- S3: gate = sigmoid(val_s_pre @ Wg) ----
    f4 gate[2];
    {
        bfv8 av0 = *(const bfv8*)(H + VAL + m * SA + 0  + kq);
        bfv8 av1 = *(const bfv8*)(H + VAL + m * SA + 32 + kq);
        #pragma unroll
        for (int nt = 0; nt < 2; ++nt) {
            const __bf16* bp = (const __bf16*)WgT + (size_t)(nt * 16 + m) * 64 + kq;
            f4 acc = {0.f, 0.f, 0.f, 0.f};
            acc = mf(av0, *(const bfv8*)(bp),      acc);
            acc = mf(av1, *(const bfv8*)(bp + 32), acc);
            gate[nt] = acc;
        }
        #pragma unroll
        for (int nt = 0; nt < 2; ++nt)
            #pragma unroll
            for (int r = 0; r < 4; ++r)
                gate[nt][r] = 1.f / (1.f + __expf(-gate[nt][r]));
    }

    // ---- S4: attention logits + ex ----
    float ex_[4][4];
    #pragma unroll
    for (int nt = 0; nt < 4; ++nt) {
        const __bf16* bp = (const __bf16*)WalphaT + (size_t)(nt * 16 + m) * 96 + kq;
        f4 acc = {0.f, 0.f, 0.f, 0.f};
        acc = mf(a1s0, *(const bfv8*)(bp),      acc);
        acc = mf(a1s1, *(const bfv8*)(bp + 32), acc);
        acc = mf(a1s2, *(const bfv8*)(bp + 64), acc);
        float ad = b2f(adotB[nt * 16 + m]);
        #pragma unroll
        for (int r = 0; r < 4; ++r) {
            float tv = acc[r];
            tv = tv > 0.f ? tv : 0.2f * tv;
            tv *= ad;
            tv += __shfl_xor(tv, 1); tv += __shfl_xor(tv, 2);
            tv += __shfl_xor(tv, 4); tv += __shfl_xor(tv, 8);
            tv = fminf(fmaxf(tv, -60.f), 60.f);
            ex_[nt][r] = __expf(tv);
        }
    }

    // ---- S5: m1_v planes through ping-pong; WvvalT fragments HELD in regs ----
    f4 vv[3][2];
    #pragma unroll
    for (int x = 0; x < 3; ++x)
        #pragma unroll
        for (int nt = 0; nt < 2; ++nt)
            vv[x][nt] = (f4){0.f, 0.f, 0.f, 0.f};
    {
        bfv8 wh[8];
        #pragma unroll
        for (int nt = 0; nt < 2; ++nt)
            #pragma unroll
            for (int kt = 0; kt < 4; ++kt)
                wh[nt * 4 + kt] = *(const bfv8*)((const __bf16*)WvvalT
                                   + (size_t)(nt * 16 + m) * 128 + kt * 32 + kq);
        W_M1(0, P0);
        W_M1(1, P1);
        MMA_H(P0, wh, vv[0][0], vv[0][1]);
        W_M1(2, P0);
        MMA_H(P1, wh, vv[1][0], vv[1][1]);
        MMA_H(P0, wh, vv[2][0], vv[2][1]);
    }
    #pragma unroll
    for (int x = 0; x < 3; ++x)
        #pragma unroll
        for (int nt = 0; nt < 2; ++nt)
            #pragma unroll
            for (int r = 0; r < 4; ++r)
                vv[x][nt][r] *= gate[nt][r];

    // ---- S6/S7 scalar part: m2_s -> A1S (VAL now dead), project -> hs ----
    float c2ss[4], c2sv[4];
    #pragma unroll
    for (int nt = 0; nt < 4; ++nt) {
        c2ss[nt] = b2f(w2B[nt * 16 + m]);
        c2sv[nt] = b2f(w2B[64 + nt * 16 + m]);
    }
    float c2vs[2], c2v0[2], c2v1[2];
    #pragma unroll
    for (int nt = 0; nt < 2; ++nt) {
        c2vs[nt] = b2f(w2B[128 + nt * 16 + m]);
        c2v0[nt] = b2f(w2B[160 + nt * 16 + m]);
        c2v1[nt] = b2f(w2B[192 + nt * 16 + m]);
    }
    #pragma unroll
    for (int r = 0; r < 4; ++r) {
        int e = q * 4 + r;
        float4 yy = *(const float4*)&sY[wv][e][0];
        float y0 = yy.x, yx = yy.y, yh = yy.z, yz = yy.w;
        #pragma unroll
        for (int nt = 0; nt < 4; ++nt)
            H[A1S + e * SS + nt * 16 + m] = (__bf16)(c2ss[nt] * vals[nt][r] * y0);
        #pragma unroll
        for (int n2 = 0; n2 < 2; ++n2) {
            float dotv = vv[0][n2][r] * yx + vv[1][n2][r] * yh + vv[2][n2][r] * yz;
            H[A1S + e * SS + 64 + n2 * 16 + m] = (__bf16)(c2v0[n2] * dotv * SQRT3_INV);
        }
    }
    f4 hs[4];
    {
        bfv8 a2s0 = *(const bfv8*)(H + A1S + m * SS + 0  + kq);
        bfv8 a2s1 = *(const bfv8*)(H + A1S + m * SS + 32 + kq);
        bfv8 a2s2 = *(const bfv8*)(H + A1S + m * SS + 64 + kq);
        #pragma unroll
        for (int nt = 0; nt < 4; ++nt) {
            const __bf16* bp = (const __bf16*)WsvlinT + (size_t)(nt * 16 + m) * 96 + kq;
            f4 acc = {0.f, 0.f, 0.f, 0.f};
            acc = mf(a2s0, *(const bfv8*)(bp),      acc);
            acc = mf(a2s1, *(const bfv8*)(bp + 32), acc);
            acc = mf(a2s2, *(const bfv8*)(bp + 64), acc);
            hs[nt] = acc;
        }
    }

    // ---- S6/S7 vector part: m2_v planes through ping-pong; WvvlinT HELD ----
    f4 hv[3][2];
    #pragma unroll
    for (int x = 0; x < 3; ++x)
        #pragma unroll
        for (int nt = 0; nt < 2; ++nt)
            hv[x][nt] = (f4){0.f, 0.f, 0.f, 0.f};
    {
        bfv8 wh[8];
        #pragma unroll
        for (int nt = 0; nt < 2; ++nt)
            #pragma unroll
            for (int kt = 0; kt < 4; ++kt)
                wh[nt * 4 + kt] = *(const bfv8*)((const __bf16*)WvvlinT
                                   + (size_t)(nt * 16 + m) * 128 + kt * 32 + kq);
        W_M2(0, P0);
        W_M2(1, P1);
        MMA_H(P0, wh, hv[0][0], hv[0][1]);
        W_M2(2, P0);
        MMA_H(P1, wh, hv[1][0], hv[1][1]);
        MMA_H(P0, wh, hv[2][0], hv[2][1]);
    }

    // ---- S8: in-wave segmented reduction over sorted dst, then few atomics ----
    // Reuse whole H as fp32 [16][168]: ch 0..159 = agg row, 160..163 = den.
    float* Hf = (float*)H;
    #pragma unroll
    for (int r = 0; r < 4; ++r) {
        int e = q * 4 + r;
        float* row = Hf + e * 168;
        #pragma unroll
        for (int nt = 0; nt < 4; ++nt)
            row[nt * 40 + m] = ex_[nt][r] * hs[nt][r];
        #pragma unroll
        for (int nt = 0; nt < 2; ++nt) {
            int c = nt * 16 + m;
            int hh = c >> 3, dd = c & 7;
            float exv = (m >= 8) ? ex_[2 * nt + 1][r] : ex_[2 * nt][r];
            float* vb = row + hh * 40 + 16 + dd * 3;
            vb[0] = exv * hv[0][nt][r];
            vb[1] = exv * hv[1][nt][r];
            vb[2] = exv * hv[2][nt][r];
        }
        if (m < 4) row[160 + m] = ex_[m][r];
    }
    // same-wave LDS ordering: writes above retire before reads below
    int nval = (int)((E - eb) < 16 ? (E - eb) : 16);
    {
        int s = 0;
        while (s < nval) {
            int d = sSD[wv][16 + s];
            int t = s + 1;
            while (t < nval && sSD[wv][16 + t] == d) ++t;
            float s0 = 0.f, s1 = 0.f, s2 = 0.f;
            for (int e = s; e < t; ++e) {
                const float* row = Hf + e * 168;
                s0 += row[l];
                s1 += row[64 + l];
                if (l < 36) s2 += row[128 + l];
            }
            float* rowp = agg + (size_t)d * 160;
            unsafeAtomicAdd(rowp + l, s0);
            unsafeAtomicAdd(rowp + 64 + l, s1);
            if (l < 32)      unsafeAtomicAdd(rowp + 128 + l, s2);
            else if (l < 36) unsafeAtomicAdd(den + (size_t)d * 4 + (l - 32), s2);
            s = t;
        }
    }
}

// ---------------- Kernel 3: normalize + output projection + residual (4 nodes/block) ----------------
template<int BF>
__device__ __forceinline__ void out_impl(
    const void* node, const float* den, const float* agg,
    const void* Wps, const void* Wpv, void* out,
    float* shs, float* shv, float* sinv, int n, int lane)
{
    if (lane < 4) sinv[lane] = 1.f / (den[(size_t)n * 4 + lane] + 1e-16f);
    for (int idx = lane; idx < 160; idx += 64) {
        int h = idx / 40, r = idx - h * 40;
        float val = agg[(size_t)n * 160 + idx] * sinv[h];
        if (r < 16) shs[h * 16 + r] = val;
        else { int rr = r - 16; int dd = rr / 3, x = rr - dd * 3; shv[x * 32 + h * 8 + dd] = val; }
    }

    float acc = ldf<BF>(node, (size_t)n * 160 + lane);
    for (int c = 0; c < 64; ++c) acc += shs[c] * ldf<BF>(Wps, c * 64 + lane);
    stf<BF>(out, (size_t)n * 160 + lane, acc);

    {
        int idx = lane; int dd = idx / 3, x = idx - dd * 3;
        float a = ldf<BF>(node, (size_t)n * 160 + 64 + idx);
        for (int c = 0; c < 32; ++c) a += shv[x * 32 + c] * ldf<BF>(Wpv, c * 32 + dd);
        stf<BF>(out, (size_t)n * 160 + 64 + idx, a);
    }
    if (lane < 32) {
        int idx = 64 + lane; int dd = idx / 3, x = idx - dd * 3;
        float a = ldf<BF>(node, (size_t)n * 160 + 64 + idx);
        for (int c = 0; c < 32; ++c) a += shv[x * 32 + c] * ldf<BF>(Wpv, c * 32 + dd);
        stf<BF>(out, (size_t)n * 160 + 64 + idx, a);
    }
}

__global__ __launch_bounds__(256) void k_out(
    const void* node, const float* den, const float* agg,
    const void* Wps, const void* Wpv, void* out,
    const int* flags, int N)
{
    __shared__ float shs[4][64];
    __shared__ float shv[4][96];
    __shared__ float sinv[4][4];
    int wv = threadIdx.x >> 6, lane = threadIdx.x & 63;
    int n = blockIdx.x * 4 + wv; if (n >= N) return;
    if (flags[0])
        out_impl<1>(node, den, agg, Wps, Wpv, out, shs[wv], shv[wv], sinv[wv], n, lane);
    else
        out_impl<0>(node, den, agg, Wps, Wpv, out, shs[wv], shv[wv], sinv[wv], n, lane);
}

// ---------------- Launch ----------------
extern "C" void kernel_launch(void* const* d_in, const int* in_sizes, int n_in,
                              void* d_out, int out_size, void* d_ws, size_t ws_size,
                              hipStream_t stream)
{
    const void* node   = d_in[0];
    const void* eidx   = d_in[1];
    const void* rbf    = d_in[2];
    const void* rsh    = d_in[3];
    const void* gs     = d_in[4];
    const void* bs     = d_in[5];
    const void* gv     = d_in[6];
    const void* Wss    = d_in[7];
    const void* Wvs    = d_in[8];
    const void* Wsd    = d_in[9];
    const void* Wvd    = d_in[10];
    const void* Wrbf   = d_in[11];
    const void* Walpha = d_in[12];
    const void* adot   = d_in[13];
    const void* Wsval  = d_in[14];
    const void* Wvval  = d_in[15];
    const void* Wg     = d_in[16];
    const void* w2ss   = d_in[17];
    const void* w2sv   = d_in[18];
    const void* w2vs   = d_in[19];
    const void* w2vv0  = d_in[20];
    const void* w2vv1  = d_in[21];
    const void* Wsvlin = d_in[22];
    const void* Wvvlin = d_in[23];
    const void* Wps    = d_in[24];
    const void* Wpv    = d_in[25];

    int N = in_sizes[0] / 160;
    int E = in_sizes[1] / 2;

    char* base = (char*)d_ws;
    int*  flags   = (int*)base;                  // 16 B
    bf16* WalphaT = (bf16*)(base + 16);
    bf16* WsvalT  = WalphaT + 6144;
    bf16* WsvlinT = WsvalT  + 6144;
    bf16* WvvalT  = WsvlinT + 6144;
    bf16* WvvlinT = WvvalT  + 4096;
    bf16* WgT     = WvvlinT + 4096;
    bf16* WrbfT   = WgT     + 2048;
    bf16* adotB   = WrbfT   + 7168;              // 224 x 32 zero-padded
    bf16* w2B     = adotB   + 64;
    bf16* ssrc    = w2B     + 224;
    bf16* sdst    = ssrc  + (size_t)N * 64;
    bf16* vsrcA   = sdst  + (size_t)N * 64;      // packed v: x in {0,1}
    bf16* vdstA   = vsrcA + (size_t)N * 64;
    bf16* vsrcB   = vdstA + (size_t)N * 64;      // packed v: x == 2
    bf16* vdstB   = vsrcB + (size_t)N * 32;
    float* den    = (float*)(vdstB + (size_t)N * 32);
    float* agg    = den + (size_t)N * 4;
    int*  cnt     = (int*)(agg + (size_t)N * 160);
    int*  perm    = cnt + N;

    k_sniff<<<1, 256, 0, stream>>>(node, eidx, flags);
    // den (4N) + agg (160N) + cnt (N) are contiguous: zero all in one launch
    int zn = N * 165;
    k_zero<<<(zn + 255) / 256, 256, 0, stream>>>(den, zn);

    // counting sort of edges by dst
    int nbe = (E + 255) / 256;
    k_hist<<<nbe, 256, 0, stream>>>(eidx, cnt, flags, E);
    k_scan<<<1, 1024, 0, stream>>>(cnt, N);
    k_perm<<<nbe, 256, 0, stream>>>(eidx, cnt, perm, flags, E);

    k_prep<<<16, 256, 0, stream>>>(Walpha, Wsval, Wsvlin, Wvval, Wvvlin, Wg, Wrbf, adot,
                                   w2ss, w2sv, w2vs, w2vv0, w2vv1,
                                   WalphaT, WsvalT, WsvlinT, WvvalT, WvvlinT, WgT, WrbfT,
                                   adotB, w2B, flags);

    int nbn = (N + 3) / 4;
    k_node<<<nbn, 256, 0, stream>>>(node, gs, bs, gv, Wss, Wvs, Wsd, Wvd,
                                    ssrc, sdst, vsrcA, vdstA, vsrcB, vdstB, flags, N);

    int nb = (E + 63) / 64;
    k_edge<<<nb, 256, 0, stream>>>(eidx, rbf, rsh,
                                   WalphaT, WsvalT, WsvlinT, WvvalT, WvvlinT, WgT, WrbfT,
                                   adotB, w2B, ssrc, sdst, vsrcA, vdstA, vsrcB, vdstB,
                                   perm, den, agg, flags, E);

    int nbo = (N + 3) / 4;
    k_out<<<nbo, 256, 0, stream>>>(node, den, agg, Wps, Wpv, d_out, flags, N);
}

// Round 6
// 446.227 us; speedup vs baseline: 1.7642x; 1.0501x over previous
//
#include <hip/hip_runtime.h>
#include <hip/hip_bf16.h>
#include <cstddef>

typedef __hip_bfloat16 bf16;
typedef __bf16 bfv8 __attribute__((ext_vector_type(8)));
typedef __bf16 bfv4 __attribute__((ext_vector_type(4)));
typedef __bf16 bfv2 __attribute__((ext_vector_type(2)));
typedef float f4 __attribute__((ext_vector_type(4)));

#define EPSN 1e-5f
#define SQRT3_INV 0.57735026918962576f
#define SQRT2_INV 0.70710678118654752f

__device__ __forceinline__ float b2f(bf16 x) { return __bfloat162float(x); }

template<int BF> __device__ __forceinline__ float ldf(const void* p, size_t i) {
    if (BF) return __bfloat162float(((const bf16*)p)[i]);
    return ((const float*)p)[i];
}
__device__ __forceinline__ float ldr(const void* p, size_t i, int bfm) {
    return bfm ? __bfloat162float(((const bf16*)p)[i]) : ((const float*)p)[i];
}
template<int BF> __device__ __forceinline__ void stf(void* p, size_t i, float v) {
    if (BF) ((bf16*)p)[i] = __float2bfloat16(v);
    else    ((float*)p)[i] = v;
}

__device__ __forceinline__ float wave_sum64(float x) {
    #pragma unroll
    for (int m = 1; m < 64; m <<= 1) x += __shfl_xor(x, m, 64);
    return x;
}

__device__ __forceinline__ f4 mf(bfv8 a, bfv8 b, f4 c) {
    return __builtin_amdgcn_mfma_f32_16x16x32_bf16(a, b, c, 0, 0, 0);
}

// ---------------- Sniffer + bulk zero (merged: saves one launch) ----------------
__global__ __launch_bounds__(256) void k_sniff_zero(const void* node, const void* eidx,
                                                    int* flags, float* zp, int zn)
{
    int t = threadIdx.x;
    if (blockIdx.x == 0) {
        __shared__ int cnt;
        __shared__ unsigned orr;
        if (t == 0) { cnt = 0; orr = 0u; }
        __syncthreads();
        unsigned w  = ((const unsigned*)node)[t];
        unsigned lo = w & 0xFFFFu;
        int e_lo = (int)((lo >> 7) & 0xFF);
        if (e_lo >= 96 && e_lo <= 140) atomicAdd(&cnt, 1);
        unsigned odd = ((const unsigned*)eidx)[2 * t + 1];
        atomicOr(&orr, odd);
        __syncthreads();
        if (t == 0) {
            flags[0] = (cnt >= 128) ? 1 : 0;   // 1 = bf16 inputs
            flags[1] = (orr == 0u) ? 1 : 0;    // 1 = int64 edge_index
        }
    }
    int i = blockIdx.x * 256 + t;
    if (i < zn) zp[i] = 0.f;
}

// ---------------- Counting sort by dst ----------------
__global__ __launch_bounds__(256) void k_hist(const void* eidx, int* cnt,
                                              const int* flags, int E)
{
    int e = blockIdx.x * 256 + threadIdx.x;
    if (e >= E) return;
    int d = flags[1] ? (int)((const long long*)eidx)[(long long)E + e]
                     : ((const int*)eidx)[(size_t)E + e];
    atomicAdd(&cnt[d], 1);
}

__global__ __launch_bounds__(1024) void k_scan(int* cnt, int N)
{
    __shared__ int wsum[16];
    int t = threadIdx.x;
    int lane = t & 63, w = t >> 6;
    int chunk = (N + 1023) >> 10;
    int lo = t * chunk, hi = lo + chunk;
    if (hi > N) hi = N; if (lo > N) lo = N;
    int sum = 0;
    for (int i = lo; i < hi; ++i) sum += cnt[i];
    int x = sum;
    #pragma unroll
    for (int off = 1; off < 64; off <<= 1) {
        int y = __shfl_up(x, off, 64);
        if (lane >= off) x += y;
    }
    if (lane == 63) wsum[w] = x;
    __syncthreads();
    if (t < 64) {
        int v = (lane < 16) ? wsum[lane] : 0;
        #pragma unroll
        for (int off = 1; off < 16; off <<= 1) {
            int y = __shfl_up(v, off, 64);
            if (lane >= off) v += y;
        }
        if (lane < 16) wsum[lane] = v;
    }
    __syncthreads();
    int acc = x - sum + (w ? wsum[w - 1] : 0);
    for (int i = lo; i < hi; ++i) { int v = cnt[i]; cnt[i] = acc; acc += v; }
}

__global__ __launch_bounds__(256) void k_perm(const void* eidx, int* cnt, int* perm,
                                              const int* flags, int E)
{
    int e = blockIdx.x * 256 + threadIdx.x;
    if (e >= E) return;
    int d = flags[1] ? (int)((const long long*)eidx)[(long long)E + e]
                     : ((const int*)eidx)[(size_t)E + e];
    int pos = atomicAdd(&cnt[d], 1);
    perm[pos] = e;
}

// ---------------- Prep body: transpose weights to bf16 [n][k] ----------------
template<int BF>
__device__ __forceinline__ void prep_body(int t, int T,
    const void* Walpha, const void* Wsval, const void* Wsvlin,
    const void* Wvval, const void* Wvvlin, const void* Wg,
    const void* Wrbf, const void* adot,
    const void* w2ss, const void* w2sv, const void* w2vs,
    const void* w2vv0, const void* w2vv1,
    bf16* WalphaT, bf16* WsvalT, bf16* WsvlinT,
    bf16* WvvalT, bf16* WvvlinT, bf16* WgT,
    bf16* WrbfT, bf16* adotB, bf16* w2B)
{
    for (int i = t; i < 96 * 64; i += T) {
        int c = i >> 6, n = i & 63;
        WalphaT[n * 96 + c] = __float2bfloat16(ldf<BF>(Walpha, i));
        WsvalT [n * 96 + c] = __float2bfloat16(ldf<BF>(Wsval,  i));
        WsvlinT[n * 96 + c] = __float2bfloat16(ldf<BF>(Wsvlin, i));
    }
    for (int i = t; i < 128 * 32; i += T) {
        int c = i >> 5, n = i & 31;
        WvvalT [n * 128 + c] = __float2bfloat16(ldf<BF>(Wvval,  i));
        WvvlinT[n * 128 + c] = __float2bfloat16(ldf<BF>(Wvvlin, i));
    }
    for (int i = t; i < 64 * 32; i += T) {
        int c = i >> 5, n = i & 31;
        WgT[n * 64 + c] = __float2bfloat16(ldf<BF>(Wg, i));
    }
    for (int i = t; i < 224 * 32; i += T) {
        int c = i >> 5, b = i & 31;
        WrbfT[i] = __float2bfloat16(b < 16 ? ldf<BF>(Wrbf, b * 224 + c) : 0.f);
    }
    if (t < 64) adotB[t] = __float2bfloat16(ldf<BF>(adot, t));
    if (t < 64) w2B[t]      = __float2bfloat16(ldf<BF>(w2ss, t));
    if (t < 64) w2B[64 + t] = __float2bfloat16(ldf<BF>(w2sv, t));
    if (t < 32) {
        w2B[128 + t] = __float2bfloat16(ldf<BF>(w2vs, t));
        w2B[160 + t] = __float2bfloat16(ldf<BF>(w2vv0, t));
        w2B[192 + t] = __float2bfloat16(ldf<BF>(w2vv1, t));
    }
}

// ---------------- Kernel 1: node layernorm+projections, prep folded in ----------------
// blocks [0,nbn): 4 nodes/block; blocks [nbn,nbn+16): weight prep (independent work,
// merged to save a launch -- both only need to finish before k_edge).
// Outputs are stored SWIZZLED for vectorized gather in k_edge:
//   ssrc/sdst [n][64]: channel c at position (c&15)*4 + (c>>4)          (bfv4 per lane)
//   vA [n][64]: x in {0,1}: channel x*32+cc at (cc&15)*4 + x*2 + (cc>>4) (bfv4 per lane)
//   vB [n][32]: x == 2:     channel 64+cc   at (cc&15)*2 + (cc>>4)       (bfv2 per lane)
template<int BF>
__device__ __forceinline__ void node_body(
    const void* node, const void* gs, const void* bs, const void* gv,
    const void* Wss, const void* Wvs, const void* Wsd, const void* Wvd,
    bf16* ssrc, bf16* sdst, bf16* vsrcA, bf16* vdstA, bf16* vsrcB, bf16* vdstB,
    float* shs, float* shv, int n, int lane)
{
    size_t nb = (size_t)n * 160;

    float s  = ldf<BF>(node, nb + lane);
    float mu = wave_sum64(s) * (1.f / 64.f);
    float d  = s - mu;
    float var = wave_sum64(d * d) * (1.f / 64.f);
    float sn  = d * rsqrtf(var + EPSN) * ldf<BF>(gs, lane) + ldf<BF>(bs, lane);
    shs[lane] = sn;

    float v0 = 0.f, v1 = 0.f, v2 = 0.f, qq = 0.f;
    if (lane < 32) {
        v0 = ldf<BF>(node, nb + 64 + lane * 3 + 0);
        v1 = ldf<BF>(node, nb + 64 + lane * 3 + 1);
        v2 = ldf<BF>(node, nb + 64 + lane * 3 + 2);
        qq = v0 * v0 + v1 * v1 + v2 * v2;
    }
    float msq = wave_sum64(qq) * (1.f / 32.f);
    float inv = rsqrtf(msq + EPSN);
    if (lane < 32) {
        float g = ldf<BF>(gv, lane);
        shv[0 * 32 + lane] = v0 * inv * g;
        shv[1 * 32 + lane] = v1 * inv * g;
        shv[2 * 32 + lane] = v2 * inv * g;
    }
    // same-wave LDS write->read: in-order, no barrier needed

    float a1 = 0.f, a2 = 0.f;
    for (int c = 0; c < 64; ++c) {
        float sc = shs[c];
        a1 += sc * ldf<BF>(Wss, c * 64 + lane);
        a2 += sc * ldf<BF>(Wsd, c * 64 + lane);
    }
    {
        int cs = lane;
        int pos = (cs & 15) * 4 + (cs >> 4);
        ssrc[(size_t)n * 64 + pos] = __float2bfloat16(a1);
        sdst[(size_t)n * 64 + pos] = __float2bfloat16(a2);
    }

    {
        int x = lane >> 5, dd = lane & 31;
        float p1 = 0.f, p2 = 0.f;
        for (int c = 0; c < 32; ++c) {
            float vc = shv[x * 32 + c];
            p1 += vc * ldf<BF>(Wvs, c * 32 + dd);
            p2 += vc * ldf<BF>(Wvd, c * 32 + dd);
        }
        int mm = dd & 15, n2 = dd >> 4;
        int pos = mm * 4 + x * 2 + n2;
        vsrcA[(size_t)n * 64 + pos] = __float2bfloat16(p1);
        vdstA[(size_t)n * 64 + pos] = __float2bfloat16(p2);
    }
    if (lane < 32) {
        int dd = lane;
        float p1 = 0.f, p2 = 0.f;
        for (int c = 0; c < 32; ++c) {
            float vc = shv[2 * 32 + c];
            p1 += vc * ldf<BF>(Wvs, c * 32 + dd);
            p2 += vc * ldf<BF>(Wvd, c * 32 + dd);
        }
        int mm = dd & 15, n2 = dd >> 4;
        int pos = mm * 2 + n2;
        vsrcB[(size_t)n * 32 + pos] = __float2bfloat16(p1);
        vdstB[(size_t)n * 32 + pos] = __float2bfloat16(p2);
    }
}

__global__ __launch_bounds__(256) void k_node(
    const void* node, const void* gs, const void* bs, const void* gv,
    const void* Wss, const void* Wvs, const void* Wsd, const void* Wvd,
    bf16* ssrc, bf16* sdst, bf16* vsrcA, bf16* vdstA, bf16* vsrcB, bf16* vdstB,
    const void* Walpha, const void* Wsval, const void* Wsvlin,
    const void* Wvval, const void* Wvvlin, const void* Wg,
    const void* Wrbf, const void* adot,
    const void* w2ss, const void* w2sv, const void* w2vs,
    const void* w2vv0, const void* w2vv1,
    bf16* WalphaT, bf16* WsvalT, bf16* WsvlinT,
    bf16* WvvalT, bf16* WvvlinT, bf16* WgT,
    bf16* WrbfT, bf16* adotB, bf16* w2B,
    const int* flags, int nbn, int N)
{
    if ((int)blockIdx.x >= nbn) {
        int t = (blockIdx.x - nbn) * 256 + threadIdx.x;
        int T = 16 * 256;
        if (flags[0])
            prep_body<1>(t, T, Walpha, Wsval, Wsvlin, Wvval, Wvvlin, Wg, Wrbf, adot,
                         w2ss, w2sv, w2vs, w2vv0, w2vv1,
                         WalphaT, WsvalT, WsvlinT, WvvalT, WvvlinT, WgT, WrbfT, adotB, w2B);
        else
            prep_body<0>(t, T, Walpha, Wsval, Wsvlin, Wvval, Wvvlin, Wg, Wrbf, adot,
                         w2ss, w2sv, w2vs, w2vv0, w2vv1,
                         WalphaT, WsvalT, WsvlinT, WvvalT, WvvlinT, WgT, WrbfT, adotB, w2B);
        return;
    }
    __shared__ float shs[4][64];
    __shared__ float shv[4][96];
    int wv = threadIdx.x >> 6, lane = threadIdx.x & 63;
    int n = blockIdx.x * 4 + wv; if (n >= N) return;
    if (flags[0])
        node_body<1>(node, gs, bs, gv, Wss, Wvs, Wsd, Wvd,
                     ssrc, sdst, vsrcA, vdstA, vsrcB, vdstB, shs[wv], shv[wv], n, lane);
    else
        node_body<0>(node, gs, bs, gv, Wss, Wvs, Wsd, Wvd,
                     ssrc, sdst, vsrcA, vdstA, vsrcB, vdstB, shs[wv], shv[wv], n, lane);
}

// ---------------- Kernel 2: fused MFMA edge pass over dst-sorted edges ----------------
// 4 waves/block, 16 edges/wave. SINGLE plane buffer (strict W->MMA serialization;
// cross-wave overlap does the hiding at higher occupancy) + S8 fp32 staging split
// into two 8-edge passes ([8][168]x4B = 5,376 <= 7,680 B of H).
// Per-wave LDS: A1S [16][104] + P0 [16][136] = 7,680 B; block total 32,512 B
// -> 5 blocks/CU = 20 waves (62%) if VGPR <= 102 (R5 measured 84 on the same
// liveness structure), else 4 blocks (50%). (256,3): NO tight VGPR cap --
// R3/R4 proved forced caps spill catastrophically.
static constexpr int SS  = 104;
static constexpr int A1S = 0;
static constexpr int SV  = 136;
static constexpr int P0  = 16 * SS;           // 1664
static constexpr int VAL = 0;                 // alias of A1S region (16x72 <= 16x104)
static constexpr int SA  = 72;
static constexpr int HSZ = P0 + 16 * SV;      // 3840 elems = 7,680 B

// m1_v plane X write into buffer PB (uses sv_, qv_, pv_, sY)
#define W_M1(X, PB) do { \
    constexpr int x_ = (X), x1_ = ((X)+1)%3, x2_ = ((X)+2)%3; \
    _Pragma("unroll") \
    for (int r = 0; r < 4; ++r) { \
        int e = q * 4 + r; \
        float4 yy = *(const float4*)&sY[wv][e][0]; \
        float y0 = yy.x; float yv[3] = {yy.y, yy.z, yy.w}; \
        _Pragma("unroll") \
        for (int nt = 0; nt < 4; ++nt) \
            H[(PB) + e * SV + nt * 16 + m] = (__bf16)(sv_[r][nt] * yv[x_]); \
        _Pragma("unroll") \
        for (int n2 = 0; n2 < 2; ++n2) { \
            int c = 64 + n2 * 16 + m; \
            H[(PB) + e * SV + c] = (__bf16)(qv_[r][n2][x_] * y0); \
            float cr = pv_[r][n2][x1_] * yv[x2_] - pv_[r][n2][x2_] * yv[x1_]; \
            H[(PB) + e * SV + 32 + c] = (__bf16)(cr * SQRT2_INV); \
        } \
    } \
} while (0)

// m2_v plane X write into buffer PB (uses vals, vv, c2*, sY)
#define W_M2(X, PB) do { \
    constexpr int x_ = (X), x1_ = ((X)+1)%3, x2_ = ((X)+2)%3; \
    _Pragma("unroll") \
    for (int r = 0; r < 4; ++r) { \
        int e = q * 4 + r; \
        float4 yy = *(const float4*)&sY[wv][e][0]; \
        float y0 = yy.x; float yv[3] = {yy.y, yy.z, yy.w}; \
        _Pragma("unroll") \
        for (int nt = 0; nt < 4; ++nt) \
            H[(PB) + e * SV + nt * 16 + m] = (__bf16)(c2sv[nt] * vals[nt][r] * yv[x_]); \
        _Pragma("unroll") \
        for (int n2 = 0; n2 < 2; ++n2) { \
            int c = 64 + n2 * 16 + m; \
            H[(PB) + e * SV + c] = (__bf16)(c2vs[n2] * vv[x_][n2][r] * y0); \
            float cr = vv[x1_][n2][r] * yv[x2_] - vv[x2_][n2][r] * yv[x1_]; \
            H[(PB) + e * SV + 32 + c] = (__bf16)(c2v1[n2] * cr * SQRT2_INV); \
        } \
    } \
} while (0)

// read A-frags from plane buffer PB, accumulate with HELD weight fragments WH[8]
#define MMA_H(PB, WH, O0, O1) do { \
    bfv8 fg_[4]; \
    _Pragma("unroll") \
    for (int kt = 0; kt < 4; ++kt) \
        fg_[kt] = *(const bfv8*)(H + (PB) + m * SV + kt * 32 + kq); \
    _Pragma("unroll") \
    for (int kt = 0; kt < 4; ++kt) { \
        O0 = mf(fg_[kt], WH[kt],     O0); \
        O1 = mf(fg_[kt], WH[4 + kt], O1); \
    } \
} while (0)

__global__ __launch_bounds__(256, 3) void k_edge(
    const void* __restrict__ eidx, const void* __restrict__ rbf, const void* __restrict__ rsh,
    const bf16* __restrict__ WalphaT, const bf16* __restrict__ WsvalT, const bf16* __restrict__ WsvlinT,
    const bf16* __restrict__ WvvalT, const bf16* __restrict__ WvvlinT, const bf16* __restrict__ WgT,
    const bf16* __restrict__ WrbfT, const bf16* __restrict__ adotB, const bf16* __restrict__ w2B,
    const bf16* __restrict__ ssrc, const bf16* __restrict__ sdst,
    const bf16* __restrict__ vsrcA, const bf16* __restrict__ vdstA,
    const bf16* __restrict__ vsrcB, const bf16* __restrict__ vdstB,
    const int* __restrict__ perm,
    float* __restrict__ den, float* __restrict__ agg,
    const int* __restrict__ flags, int E)
{
    const int bfm = flags[0];
    const int i64 = flags[1];

    __shared__ __align__(16) __bf16 sH[4][HSZ];
    __shared__ __align__(16) float sY[4][16][4];
    __shared__ int sSD[4][48];   // [0..15]=src, [16..31]=dst, [32..47]=permuted edge id

    int wv = threadIdx.x >> 6, l = threadIdx.x & 63;
    int q = l >> 4, m = l & 15;
    const int kq = q * 8;

    // XCD-chunked bijective block swizzle (T1, m204): contiguous sorted-dst
    // ranges per XCD -> dst-side gather slice (~1 MB) becomes L2-resident per XCD.
    int bid;
    {
        int nwg = gridDim.x, orig = blockIdx.x;
        int qq_ = nwg >> 3, rr_ = nwg & 7;
        int xcd = orig & 7, off = orig >> 3;
        bid = (xcd < rr_ ? xcd * (qq_ + 1) : rr_ * (qq_ + 1) + (xcd - rr_) * qq_) + off;
    }
    long long eb = ((long long)bid * 4 + wv) * 16;
    if (eb >= E) return;        // wave-uniform; no barriers in this kernel
    __bf16* H = &sH[wv][0];

    // ---- edge metadata (sorted position -> edge id via perm) ----
    if (l < 16) {
        long long p = eb + l; if (p > (long long)E - 1) p = E - 1;
        sSD[wv][32 + l] = perm[p];
    }
    if (l < 32) {
        int pe = sSD[wv][32 + (l & 15)];
        long long off = (l < 16) ? (long long)pe : ((long long)E + pe);
        sSD[wv][l] = i64 ? (int)((const long long*)eidx)[off] : ((const int*)eidx)[off];
    }
    {
        int pe = sSD[wv][32 + (l >> 2)];
        sY[wv][l >> 2][l & 3] = ldr(rsh, (size_t)pe * 4 + (l & 3), bfm);
    }

    // ---- S1a: w1 = rbf @ Wrbf via 14 MFMAs (K=32, k>=16 zero-padded) ----
    // D layout: lane(q,m), reg r -> w1[edge q*4+r][channel nt*16+m]
    // channels: nt 0-3 wss | 4-7 wsv | 8-9 wvs | 10-11 wv0 | 12-13 wv1
    f4 w1f[14];
    {
        bfv8 arb;
        #pragma unroll
        for (int i = 0; i < 8; ++i) arb[i] = (__bf16)0.f;
        if (q < 2) {
            int pe = sSD[wv][32 + m];
            if (bfm) {
                arb = *(const bfv8*)((const __bf16*)rbf + (size_t)pe * 16 + kq);
            } else {
                const float* rp = (const float*)rbf + (size_t)pe * 16 + kq;
                #pragma unroll
                for (int i = 0; i < 8; ++i) arb[i] = (__bf16)rp[i];
            }
        }
        const __bf16* wb = (const __bf16*)WrbfT;
        #pragma unroll
        for (int nt = 0; nt < 14; ++nt) {
            bfv8 bb = *(const bfv8*)(wb + (size_t)(nt * 16 + m) * 32 + kq);
            f4 z = {0.f, 0.f, 0.f, 0.f};
            w1f[nt] = mf(arb, bb, z);
        }
    }

    // ---- gather messages (vectorized via swizzled node arrays, batched) ----
    bfv4 gs_[4], gd_[4], gvA[4], gwA[4];
    bfv2 gvB[4], gwB[4];
    #pragma unroll
    for (int r = 0; r < 4; ++r) {
        int e = q * 4 + r;
        int s = sSD[wv][e], d = sSD[wv][16 + e];
        gs_[r] = *(const bfv4*)((const __bf16*)ssrc  + (size_t)s * 64 + m * 4);
        gd_[r] = *(const bfv4*)((const __bf16*)sdst  + (size_t)d * 64 + m * 4);
        gvA[r] = *(const bfv4*)((const __bf16*)vsrcA + (size_t)s * 64 + m * 4);
        gwA[r] = *(const bfv4*)((const __bf16*)vdstA + (size_t)d * 64 + m * 4);
        gvB[r] = *(const bfv2*)((const __bf16*)vsrcB + (size_t)s * 32 + m * 2);
        gwB[r] = *(const bfv2*)((const __bf16*)vdstB + (size_t)d * 32 + m * 2);
    }
    float ms_[4][4], mv_[4][2][3];
    #pragma unroll
    for (int r = 0; r < 4; ++r) {
        #pragma unroll
        for (int nt = 0; nt < 4; ++nt)
            ms_[r][nt] = (float)gs_[r][nt] + (float)gd_[r][nt];
        #pragma unroll
        for (int n2 = 0; n2 < 2; ++n2) {
            mv_[r][n2][0] = (float)gvA[r][0 * 2 + n2] + (float)gwA[r][0 * 2 + n2];
            mv_[r][n2][1] = (float)gvA[r][1 * 2 + n2] + (float)gwA[r][1 * 2 + n2];
            mv_[r][n2][2] = (float)gvB[r][n2]         + (float)gwB[r][n2];
        }
    }

    // ---- m1_s -> A1S; precompute plane products ----
    float sv_[4][4], qv_[4][2][3], pv_[4][2][3];
    #pragma unroll
    for (int r = 0; r < 4; ++r) {
        int e = q * 4 + r;
        float4 yy = *(const float4*)&sY[wv][e][0];
        float y0 = yy.x, yx = yy.y, yh = yy.z, yz = yy.w;
        #pragma unroll
        for (int nt = 0; nt < 4; ++nt) {
            H[A1S + e * SS + nt * 16 + m] = (__bf16)(w1f[nt][r] * ms_[r][nt] * y0);
            sv_[r][nt] = w1f[4 + nt][r] * ms_[r][nt];
        }
        #pragma unroll
        for (int n2 = 0; n2 < 2; ++n2) {
            float dot = mv_[r][n2][0] * yx + mv_[r][n2][1] * yh + mv_[r][n2][2] * yz;
            H[A1S + e * SS + 64 + n2 * 16 + m] = (__bf16)(w1f[10 + n2][r] * dot * SQRT3_INV);
            #pragma unroll
            for (int x = 0; x < 3; ++x) {
                qv_[r][n2][x] = w1f[8 + n2][r]  * mv_[r][n2][x];
                pv_[r][n2][x] = w1f[12 + n2][r] * mv_[r][n2][x];
            }
        }
    }

    // ---- a1s fragments (A1S region then reusable) ----
    bfv8 a1s0 = *(const bfv8*)(H + A1S + m * SS + 0  + kq);
    bfv8 a1s1 = *(const bfv8*)(H + A1S + m * SS + 32 + kq);
    bfv8 a1s2 = *(const bfv8*)(H + A1S + m * SS + 64 + kq);

    // ---- S2: val_s = m1_s @ Ws_val; PRE-sigmoid -> VAL (alias A1S), sigmoid -> regs ----
    f4 vals[4];
    #pragma unroll
    for (int nt = 0; nt < 4; ++nt) {
        const __bf16* bp = (const __bf16*)WsvalT + (size_t)(nt * 16 + m) * 96 + kq;
        f4 acc = {0.f, 0.f, 0.f, 0.f};
        acc = mf(a1s0, *(const bfv8*)(bp),      acc);
        acc = mf(a1s1, *(const bfv8*)(bp + 32), acc);
        acc = mf(a1s2, *(const bfv8*)(bp + 64), acc);
        vals[nt] = acc;
    }
    #pragma unroll
    for (int nt = 0; nt < 4; ++nt)
        #pragma unroll
        for (int r = 0; r < 4; ++r) {
            float v = vals[nt][r];
            H[VAL + (q * 4 + r) * SA + nt * 16 + m] = (__bf16)v;   // PRE-sigmoid
            vals[nt][r] = 1.f / (1.f + __expf(-v));
        }

    // ---- S3: gate = sigmoid(val_s_pre @ Wg) ----
    f4 gate[2];
    {
        bfv8 av0 = *(const bfv8*)(H + VAL + m * SA + 0  + kq);
        bfv8 av1 = *(const bfv8*)(H + VAL + m * SA + 32 + kq);
        #pragma unroll
        for (int nt = 0; nt < 2; ++nt) {
            const __bf16* bp = (const __bf16*)WgT + (size_t)(nt * 16 + m) * 64 + kq;
            f4 acc = {0.f, 0.f, 0.f, 0.f};
            acc = mf(av0, *(const bfv8*)(bp),      acc);
            acc = mf(av1, *(const bfv8*)(bp + 32), acc);
            gate[nt] = acc;
        }
        #pragma unroll
        for (int nt = 0; nt < 2; ++nt)
            #pragma unroll
            for (int r = 0; r < 4; ++r)
                gate[nt][r] = 1.f / (1.f + __expf(-gate[nt][r]));
    }

    // ---- S4: attention logits + ex ----
    float ex_[4][4];
    #pragma unroll
    for (int nt = 0; nt < 4; ++nt) {
        const __bf16* bp = (const __bf16*)WalphaT + (size_t)(nt * 16 + m) * 96 + kq;
        f4 acc = {0.f, 0.f, 0.f, 0.f};
        acc = mf(a1s0, *(const bfv8*)(bp),      acc);
        acc = mf(a1s1, *(const bfv8*)(bp + 32), acc);
        acc = mf(a1s2, *(const bfv8*)(bp + 64), acc);
        float ad = b2f(adotB[nt * 16 + m]);
        #pragma unroll
        for (int r = 0; r < 4; ++r) {
            float tv = acc[r];
            tv = tv > 0.f ? tv : 0.2f * tv;
            tv *= ad;
            tv += __shfl_xor(tv, 1); tv += __shfl_xor(tv, 2);
            tv += __shfl_xor(tv, 4); tv += __shfl_xor(tv, 8);
            tv = fminf(fmaxf(tv, -60.f), 60.f);
            ex_[nt][r] = __expf(tv);
        }
    }

    // ---- S5: m1_v planes through SINGLE buffer; WvvalT fragments HELD in regs ----
    f4 vv[3][2];
    #pragma unroll
    for (int x = 0; x < 3; ++x)
        #pragma unroll
        for (int nt = 0; nt < 2; ++nt)
            vv[x][nt] = (f4){0.f, 0.f, 0.f, 0.f};
    {
        bfv8 wh[8];
        #pragma unroll
        for (int nt = 0; nt < 2; ++nt)
            #pragma unroll
            for (int kt = 0; kt < 4; ++kt)
                wh[nt * 4 + kt] = *(const bfv8*)((const __bf16*)WvvalT
                                   + (size_t)(nt * 16 + m) * 128 + kt * 32 + kq);
        W_M1(0, P0);
        MMA_H(P0, wh, vv[0][0], vv[0][1]);
        W_M1(1, P0);
        MMA_H(P0, wh, vv[1][0], vv[1][1]);
        W_M1(2, P0);
        MMA_H(P0, wh, vv[2][0], vv[2][1]);
    }
    #pragma unroll
    for (int x = 0; x < 3; ++x)
        #pragma unroll
        for (int nt = 0; nt < 2; ++nt)
            #pragma unroll
            for (int r = 0; r < 4; ++r)
                vv[x][nt][r] *= gate[nt][r];

    // ---- S6/S7 scalar part: m2_s -> A1S (VAL now dead), project -> hs ----
    float c2ss[4], c2sv[4];
    #pragma unroll
    for (int nt = 0; nt < 4; ++nt) {
        c2ss[nt] = b2f(w2B[nt * 16 + m]);
        c2sv[nt] = b2f(w2B[64 + nt * 16 + m]);
    }
    float c2vs[2], c2v0[2], c2v1[2];
    #pragma unroll
    for (int nt = 0; nt < 2; ++nt) {
        c2vs[nt] = b2f(w2B[128 + nt * 16 + m]);
        c2v0[nt] = b2f(w2B[160 + nt * 16 + m]);
        c2v1[nt] = b2f(w2B[192 + nt * 16 + m]);
    }
    #pragma unroll
    for (int r = 0; r < 4; ++r) {
        int e = q * 4 + r;
        float4 yy = *(const float4*)&sY[wv][e][0];
        float y0 = yy.x, yx = yy.y, yh = yy.z, yz = yy.w;
        #pragma unroll
        for (int nt = 0; nt < 4; ++nt)
            H[A1S + e * SS + nt * 16 + m] = (__bf16)(c2ss[nt] * vals[nt][r] * y0);
        #pragma unroll
        for (int n2 = 0; n2 < 2; ++n2) {
            float dotv = vv[0][n2][r] * yx + vv[1][n2][r] * yh + vv[2][n2][r] * yz;
            H[A1S + e * SS + 64 + n2 * 16 + m] = (__bf16)(c2v0[n2] * dotv * SQRT3_INV);
        }
    }
    f4 hs[4];
    {
        bfv8 a2s0 = *(const bfv8*)(H + A1S + m * SS + 0  + kq);
        bfv8 a2s1 = *(const bfv8*)(H + A1S + m * SS + 32 + kq);
        bfv8 a2s2 = *(const bfv8*)(H + A1S + m * SS + 64 + kq);
        #pragma unroll
        for (int nt = 0; nt < 4; ++nt) {
            const __bf16* bp = (const __bf16*)WsvlinT + (size_t)(nt * 16 + m) * 96 + kq;
            f4 acc = {0.f, 0.f, 0.f, 0.f};
            acc = mf(a2s0, *(const bfv8*)(bp),      acc);
            acc = mf(a2s1, *(const bfv8*)(bp + 32), acc);
            acc = mf(a2s2, *(const bfv8*)(bp + 64), acc);
            hs[nt] = acc;
        }
    }

    // ---- S6/S7 vector part: m2_v planes through SINGLE buffer; WvvlinT HELD ----
    f4 hv[3][2];
    #pragma unroll
    for (int x = 0; x < 3; ++x)
        #pragma unroll
        for (int nt = 0; nt < 2; ++nt)
            hv[x][nt] = (f4){0.f, 0.f, 0.f, 0.f};
    {
        bfv8 wh[8];
        #pragma unroll
        for (int nt = 0; nt < 2; ++nt)
            #pragma unroll
            for (int kt = 0; kt < 4; ++kt)
                wh[nt * 4 + kt] = *(const bfv8*)((const __bf16*)WvvlinT
                                   + (size_t)(nt * 16 + m) * 128 + kt * 32 + kq);
        W_M2(0, P0);
        MMA_H(P0, wh, hv[0][0], hv[0][1]);
        W_M2(1, P0);
        MMA_H(P0, wh, hv[1][0], hv[1][1]);
        W_M2(2, P0);
        MMA_H(P0, wh, hv[2][0], hv[2][1]);
    }

    // ---- S8: segmented reduction over sorted dst, TWO 8-edge passes through
    // fp32 staging [8][168] (5,376 B <= 7,680 B of H). Runs spanning the e=8
    // boundary flush twice (extra atomic, still correct). Same-wave LDS
    // ordering guarantees write->read->overwrite sequencing without barriers.
    {
        float* Hf = (float*)H;
        int nval = (int)((E - eb) < 16 ? (E - eb) : 16);
        #pragma unroll
        for (int half = 0; half < 2; ++half) {
            if ((q >> 1) == half) {
                #pragma unroll
                for (int r = 0; r < 4; ++r) {
                    int er = (q & 1) * 4 + r;        // row within this half, 0..7
                    float* row = Hf + er * 168;
                    #pragma unroll
                    for (int nt = 0; nt < 4; ++nt)
                        row[nt * 40 + m] = ex_[nt][r] * hs[nt][r];
                    #pragma unroll
                    for (int nt = 0; nt < 2; ++nt) {
                        int c = nt * 16 + m;
                        int hh = c >> 3, dd = c & 7;
                        float exv = (m >= 8) ? ex_[2 * nt + 1][r] : ex_[2 * nt][r];
                        float* vb = row + hh * 40 + 16 + dd * 3;
                        vb[0] = exv * hv[0][nt][r];
                        vb[1] = exv * hv[1][nt][r];
                        vb[2] = exv * hv[2][nt][r];
                    }
                    if (m < 4) row[160 + m] = ex_[m][r];
                }
            }
            int lo = half * 8;
            int hi = nval < lo + 8 ? nval : lo + 8;
            int s = lo;
            while (s < hi) {
                int d = sSD[wv][16 + s];
                int t2 = s + 1;
                while (t2 < hi && sSD[wv][16 + t2] == d) ++t2;
                float s0 = 0.f, s1 = 0.f, s2 = 0.f;
                for (int e = s; e < t2; ++e) {
                    const float* row = Hf + (e - lo) * 168;
                    s0 += row[l];
                    s1 += row[64 + l];
                    if (l < 36) s2 += row[128 + l];
                }
                float* rowp = agg + (size_t)d * 160;
                unsafeAtomicAdd(rowp + l, s0);
                unsafeAtomicAdd(rowp + 64 + l, s1);
                if (l < 32)      unsafeAtomicAdd(rowp + 128 + l, s2);
                else if (l < 36) unsafeAtomicAdd(den + (size_t)d * 4 + (l - 32), s2);
                s = t2;
            }
        }
    }
}

// ---------------- Kernel 3: normalize + output projection + residual (4 nodes/block) ----------------
template<int BF>
__device__ __forceinline__ void out_impl(
    const void* node, const float* den, const float* agg,
    const void* Wps, const void* Wpv, void* out,
    float* shs, float* shv, float* sinv, int n, int lane)
{
    if (lane < 4) sinv[lane] = 1.f / (den[(size_t)n * 4 + lane] + 1e-16f);
    for (int idx = lane; idx < 160; idx += 64) {
        int h = idx / 40, r = idx - h * 40;
        float val = agg[(size_t)n * 160 + idx] * sinv[h];
        if (r < 16) shs[h * 16 + r] = val;
        else { int rr = r - 16; int dd = rr / 3, x = rr - dd * 3; shv[x * 32 + h * 8 + dd] = val; }
    }

    float acc = ldf<BF>(node, (size_t)n * 160 + lane);
    for (int c = 0; c < 64; ++c) acc += shs[c] * ldf<BF>(Wps, c * 64 + lane);
    stf<BF>(out, (size_t)n * 160 + lane, acc);

    {
        int idx = lane; int dd = idx / 3, x = idx - dd * 3;
        float a = ldf<BF>(node, (size_t)n * 160 + 64 + idx);
        for (int c = 0; c < 32; ++c) a += shv[x * 32 + c] * ldf<BF>(Wpv, c * 32 + dd);
        stf<BF>(out, (size_t)n * 160 + 64 + idx, a);
    }
    if (lane < 32) {
        int idx = 64 + lane; int dd = idx / 3, x = idx - dd * 3;
        float a = ldf<BF>(node, (size_t)n * 160 + 64 + idx);
        for (int c = 0; c < 32; ++c) a += shv[x * 32 + c] * ldf<BF>(Wpv, c * 32 + dd);
        stf<BF>(out, (size_t)n * 160 + 64 + idx, a);
    }
}

__global__ __launch_bounds__(256) void k_out(
    const void* node, const float* den, const float* agg,
    const void* Wps, const void* Wpv, void* out,
    const int* flags, int N)
{
    __shared__ float shs[4][64];
    __shared__ float shv[4][96];
    __shared__ float sinv[4][4];
    int wv = threadIdx.x >> 6, lane = threadIdx.x & 63;
    int n = blockIdx.x * 4 + wv; if (n >= N) return;
    if (flags[0])
        out_impl<1>(node, den, agg, Wps, Wpv, out, shs[wv], shv[wv], sinv[wv], n, lane);
    else
        out_impl<0>(node, den, agg, Wps, Wpv, out, shs[wv], shv[wv], sinv[wv], n, lane);
}

// ---------------- Launch ----------------
extern "C" void kernel_launch(void* const* d_in, const int* in_sizes, int n_in,
                              void* d_out, int out_size, void* d_ws, size_t ws_size,
                              hipStream_t stream)
{
    const void* node   = d_in[0];
    const void* eidx   = d_in[1];
    const void* rbf    = d_in[2];
    const void* rsh    = d_in[3];
    const void* gs     = d_in[4];
    const void* bs     = d_in[5];
    const void* gv     = d_in[6];
    const void* Wss    = d_in[7];
    const void* Wvs    = d_in[8];
    const void* Wsd    = d_in[9];
    const void* Wvd    = d_in[10];
    const void* Wrbf   = d_in[11];
    const void* Walpha = d_in[12];
    const void* adot   = d_in[13];
    const void* Wsval  = d_in[14];
    const void* Wvval  = d_in[15];
    const void* Wg     = d_in[16];
    const void* w2ss   = d_in[17];
    const void* w2sv   = d_in[18];
    const void* w2vs   = d_in[19];
    const void* w2vv0  = d_in[20];
    const void* w2vv1  = d_in[21];
    const void* Wsvlin = d_in[22];
    const void* Wvvlin = d_in[23];
    const void* Wps    = d_in[24];
    const void* Wpv    = d_in[25];

    int N = in_sizes[0] / 160;
    int E = in_sizes[1] / 2;

    char* base = (char*)d_ws;
    int*  flags   = (int*)base;                  // 16 B
    bf16* WalphaT = (bf16*)(base + 16);
    bf16* WsvalT  = WalphaT + 6144;
    bf16* WsvlinT = WsvalT  + 6144;
    bf16* WvvalT  = WsvlinT + 6144;
    bf16* WvvlinT = WvvalT  + 4096;
    bf16* WgT     = WvvlinT + 4096;
    bf16* WrbfT   = WgT     + 2048;
    bf16* adotB   = WrbfT   + 7168;              // 224 x 32 zero-padded
    bf16* w2B     = adotB   + 64;
    bf16* ssrc    = w2B     + 224;
    bf16* sdst    = ssrc  + (size_t)N * 64;
    bf16* vsrcA   = sdst  + (size_t)N * 64;      // packed v: x in {0,1}
    bf16* vdstA   = vsrcA + (size_t)N * 64;
    bf16* vsrcB   = vdstA + (size_t)N * 64;      // packed v: x == 2
    bf16* vdstB   = vsrcB + (size_t)N * 32;
    float* den    = (float*)(vdstB + (size_t)N * 32);
    float* agg    = den + (size_t)N * 4;
    int*  cnt     = (int*)(agg + (size_t)N * 160);
    int*  perm    = cnt + N;

    // sniff + zero den(4N)+agg(160N)+cnt(N) in one launch
    int zn = N * 165;
    k_sniff_zero<<<(zn + 255) / 256, 256, 0, stream>>>(node, eidx, flags, den, zn);

    // counting sort of edges by dst
    int nbe = (E + 255) / 256;
    k_hist<<<nbe, 256, 0, stream>>>(eidx, cnt, flags, E);
    k_scan<<<1, 1024, 0, stream>>>(cnt, N);
    k_perm<<<nbe, 256, 0, stream>>>(eidx, cnt, perm, flags, E);

    // node layernorm/projections + weight prep (merged; both precede k_edge)
    int nbn = (N + 3) / 4;
    k_node<<<nbn + 16, 256, 0, stream>>>(node, gs, bs, gv, Wss, Wvs, Wsd, Wvd,
                                         ssrc, sdst, vsrcA, vdstA, vsrcB, vdstB,
                                         Walpha, Wsval, Wsvlin, Wvval, Wvvlin, Wg,
                                         Wrbf, adot, w2ss, w2sv, w2vs, w2vv0, w2vv1,
                                         WalphaT, WsvalT, WsvlinT, WvvalT, WvvlinT,
                                         WgT, WrbfT, adotB, w2B, flags, nbn, N);

    int nb = (E + 63) / 64;
    k_edge<<<nb, 256, 0, stream>>>(eidx, rbf, rsh,
                                   WalphaT, WsvalT, WsvlinT, WvvalT, WvvlinT, WgT, WrbfT,
                                   adotB, w2B, ssrc, sdst, vsrcA, vdstA, vsrcB, vdstB,
                                   perm, den, agg, flags, E);

    int nbo = (N + 3) / 4;
    k_out<<<nbo, 256, 0, stream>>>(node, den, agg, Wps, Wpv, d_out, flags, N);
}

// Round 7
// 406.416 us; speedup vs baseline: 1.9370x; 1.0980x over previous
//
#include <hip/hip_runtime.h>
#include <hip/hip_bf16.h>
#include <cstddef>

typedef __hip_bfloat16 bf16;
typedef __bf16 bfv8 __attribute__((ext_vector_type(8)));
typedef __bf16 bfv4 __attribute__((ext_vector_type(4)));
typedef __bf16 bfv2 __attribute__((ext_vector_type(2)));
typedef float f4 __attribute__((ext_vector_type(4)));

#define EPSN 1e-5f
#define SQRT3_INV 0.57735026918962576f
#define SQRT2_INV 0.70710678118654752f

__device__ __forceinline__ float b2f(bf16 x) { return __bfloat162float(x); }

template<int BF> __device__ __forceinline__ float ldf(const void* p, size_t i) {
    if (BF) return __bfloat162float(((const bf16*)p)[i]);
    return ((const float*)p)[i];
}
__device__ __forceinline__ float ldr(const void* p, size_t i, int bfm) {
    return bfm ? __bfloat162float(((const bf16*)p)[i]) : ((const float*)p)[i];
}
template<int BF> __device__ __forceinline__ void stf(void* p, size_t i, float v) {
    if (BF) ((bf16*)p)[i] = __float2bfloat16(v);
    else    ((float*)p)[i] = v;
}

__device__ __forceinline__ f4 mf(bfv8 a, bfv8 b, f4 c) {
    return __builtin_amdgcn_mfma_f32_16x16x32_bf16(a, b, c, 0, 0, 0);
}

// ---------------- Sniffer + bulk zero (merged) ----------------
__global__ __launch_bounds__(256) void k_sniff_zero(const void* node, const void* eidx,
                                                    int* flags, float* zp, int zn)
{
    int t = threadIdx.x;
    if (blockIdx.x == 0) {
        __shared__ int cnt;
        __shared__ unsigned orr;
        if (t == 0) { cnt = 0; orr = 0u; }
        __syncthreads();
        unsigned w  = ((const unsigned*)node)[t];
        unsigned lo = w & 0xFFFFu;
        int e_lo = (int)((lo >> 7) & 0xFF);
        if (e_lo >= 96 && e_lo <= 140) atomicAdd(&cnt, 1);
        unsigned odd = ((const unsigned*)eidx)[2 * t + 1];
        atomicOr(&orr, odd);
        __syncthreads();
        if (t == 0) {
            flags[0] = (cnt >= 128) ? 1 : 0;   // 1 = bf16 inputs
            flags[1] = (orr == 0u) ? 1 : 0;    // 1 = int64 edge_index
        }
    }
    int i = blockIdx.x * 256 + t;
    if (i < zn) zp[i] = 0.f;
}

// ---------------- Prep body: transpose weights to bf16 [n][k] ----------------
template<int BF>
__device__ __forceinline__ void prep_body(int t, int T,
    const void* Walpha, const void* Wsval, const void* Wsvlin,
    const void* Wvval, const void* Wvvlin, const void* Wg,
    const void* Wrbf, const void* adot,
    const void* w2ss, const void* w2sv, const void* w2vs,
    const void* w2vv0, const void* w2vv1,
    const void* Wss, const void* Wsd, const void* Wvs, const void* Wvd,
    const void* Wps, const void* Wpv,
    bf16* WalphaT, bf16* WsvalT, bf16* WsvlinT,
    bf16* WvvalT, bf16* WvvlinT, bf16* WgT,
    bf16* WrbfT, bf16* adotB, bf16* w2B,
    bf16* WssT, bf16* WsdT, bf16* WvsT, bf16* WvdT, bf16* WpsT, bf16* WpvT)
{
    for (int i = t; i < 96 * 64; i += T) {
        int c = i >> 6, n = i & 63;
        WalphaT[n * 96 + c] = __float2bfloat16(ldf<BF>(Walpha, i));
        WsvalT [n * 96 + c] = __float2bfloat16(ldf<BF>(Wsval,  i));
        WsvlinT[n * 96 + c] = __float2bfloat16(ldf<BF>(Wsvlin, i));
    }
    for (int i = t; i < 128 * 32; i += T) {
        int c = i >> 5, n = i & 31;
        WvvalT [n * 128 + c] = __float2bfloat16(ldf<BF>(Wvval,  i));
        WvvlinT[n * 128 + c] = __float2bfloat16(ldf<BF>(Wvvlin, i));
    }
    for (int i = t; i < 64 * 32; i += T) {
        int c = i >> 5, n = i & 31;
        WgT[n * 64 + c] = __float2bfloat16(ldf<BF>(Wg, i));
    }
    for (int i = t; i < 224 * 32; i += T) {
        int c = i >> 5, b = i & 31;
        WrbfT[i] = __float2bfloat16(b < 16 ? ldf<BF>(Wrbf, b * 224 + c) : 0.f);
    }
    // [in][out] -> [out][in] transposes for MFMA B-fragments in k_node / k_out
    for (int i = t; i < 64 * 64; i += T) {
        int k = i >> 6, n = i & 63;
        WssT[n * 64 + k] = __float2bfloat16(ldf<BF>(Wss, i));
        WsdT[n * 64 + k] = __float2bfloat16(ldf<BF>(Wsd, i));
        WpsT[n * 64 + k] = __float2bfloat16(ldf<BF>(Wps, i));
    }
    for (int i = t; i < 32 * 32; i += T) {
        int k = i >> 5, n = i & 31;
        WvsT[n * 32 + k] = __float2bfloat16(ldf<BF>(Wvs, i));
        WvdT[n * 32 + k] = __float2bfloat16(ldf<BF>(Wvd, i));
        WpvT[n * 32 + k] = __float2bfloat16(ldf<BF>(Wpv, i));
    }
    if (t < 64) adotB[t] = __float2bfloat16(ldf<BF>(adot, t));
    if (t < 64) w2B[t]      = __float2bfloat16(ldf<BF>(w2ss, t));
    if (t < 64) w2B[64 + t] = __float2bfloat16(ldf<BF>(w2sv, t));
    if (t < 32) {
        w2B[128 + t] = __float2bfloat16(ldf<BF>(w2vs, t));
        w2B[160 + t] = __float2bfloat16(ldf<BF>(w2vv0, t));
        w2B[192 + t] = __float2bfloat16(ldf<BF>(w2vv1, t));
    }
}

// ---------------- k_histprep: edge histogram + weight prep (merged launch) ----------------
__global__ __launch_bounds__(256) void k_histprep(
    const void* eidx, int* cnt,
    const void* Walpha, const void* Wsval, const void* Wsvlin,
    const void* Wvval, const void* Wvvlin, const void* Wg,
    const void* Wrbf, const void* adot,
    const void* w2ss, const void* w2sv, const void* w2vs,
    const void* w2vv0, const void* w2vv1,
    const void* Wss, const void* Wsd, const void* Wvs, const void* Wvd,
    const void* Wps, const void* Wpv,
    bf16* WalphaT, bf16* WsvalT, bf16* WsvlinT,
    bf16* WvvalT, bf16* WvvlinT, bf16* WgT,
    bf16* WrbfT, bf16* adotB, bf16* w2B,
    bf16* WssT, bf16* WsdT, bf16* WvsT, bf16* WvdT, bf16* WpsT, bf16* WpvT,
    const int* flags, int E, int nbe)
{
    if ((int)blockIdx.x >= nbe) {
        int t = (blockIdx.x - nbe) * 256 + threadIdx.x;
        int T = 16 * 256;
        if (flags[0])
            prep_body<1>(t, T, Walpha, Wsval, Wsvlin, Wvval, Wvvlin, Wg, Wrbf, adot,
                         w2ss, w2sv, w2vs, w2vv0, w2vv1, Wss, Wsd, Wvs, Wvd, Wps, Wpv,
                         WalphaT, WsvalT, WsvlinT, WvvalT, WvvlinT, WgT, WrbfT, adotB, w2B,
                         WssT, WsdT, WvsT, WvdT, WpsT, WpvT);
        else
            prep_body<0>(t, T, Walpha, Wsval, Wsvlin, Wvval, Wvvlin, Wg, Wrbf, adot,
                         w2ss, w2sv, w2vs, w2vv0, w2vv1, Wss, Wsd, Wvs, Wvd, Wps, Wpv,
                         WalphaT, WsvalT, WsvlinT, WvvalT, WvvlinT, WgT, WrbfT, adotB, w2B,
                         WssT, WsdT, WvsT, WvdT, WpsT, WpvT);
        return;
    }
    int e = blockIdx.x * 256 + threadIdx.x;
    if (e >= E) return;
    int d = flags[1] ? (int)((const long long*)eidx)[(long long)E + e]
                     : ((const int*)eidx)[(size_t)E + e];
    atomicAdd(&cnt[d], 1);
}

__global__ __launch_bounds__(1024) void k_scan(int* cnt, int N)
{
    __shared__ int wsum[16];
    int t = threadIdx.x;
    int lane = t & 63, w = t >> 6;
    int chunk = (N + 1023) >> 10;
    int lo = t * chunk, hi = lo + chunk;
    if (hi > N) hi = N; if (lo > N) lo = N;
    int sum = 0;
    for (int i = lo; i < hi; ++i) sum += cnt[i];
    int x = sum;
    #pragma unroll
    for (int off = 1; off < 64; off <<= 1) {
        int y = __shfl_up(x, off, 64);
        if (lane >= off) x += y;
    }
    if (lane == 63) wsum[w] = x;
    __syncthreads();
    if (t < 64) {
        int v = (lane < 16) ? wsum[lane] : 0;
        #pragma unroll
        for (int off = 1; off < 16; off <<= 1) {
            int y = __shfl_up(v, off, 64);
            if (lane >= off) v += y;
        }
        if (lane < 16) wsum[lane] = v;
    }
    __syncthreads();
    int acc = x - sum + (w ? wsum[w - 1] : 0);
    for (int i = lo; i < hi; ++i) { int v = cnt[i]; cnt[i] = acc; acc += v; }
}

// ---------------- k_node MFMA body: 16 nodes/wave ----------------
// Uses k_edge's verified fragment mapping: lane(q,m): A row=m, k=8q+j;
// D row=q*4+reg, col=m. Layernorm/RMS stats reduced over q-lanes (shfl 16,32).
// Output packing into the swizzled gather layouts (single bfv4/bfv2 stores):
//   ssrc pos = m*4+nt; vA pos = m*4 + x*2 + nt; vB pos = m*2 + nt.
template<int BF>
__device__ __forceinline__ void node_mfma(
    const void* node, const void* gs, const void* bs, const void* gv,
    const bf16* WssT, const bf16* WsdT, const bf16* WvsT, const bf16* WvdT,
    bf16* ssrc, bf16* sdst, bf16* vsrcA, bf16* vdstA, bf16* vsrcB, bf16* vdstB,
    int n0, int q, int m, int N)
{
    int nm = n0 + m; if (nm > N - 1) nm = N - 1;
    size_t nb = (size_t)nm * 160;
    const int kq = q * 8;

    // ---- s: 16 values (channels kq..kq+7 and 32+kq..32+kq+7) ----
    float s0[8], s1[8];
    if (BF) {
        bfv8 r0 = *(const bfv8*)((const __bf16*)node + nb + kq);
        bfv8 r1 = *(const bfv8*)((const __bf16*)node + nb + 32 + kq);
        #pragma unroll
        for (int j = 0; j < 8; ++j) { s0[j] = (float)r0[j]; s1[j] = (float)r1[j]; }
    } else {
        #pragma unroll
        for (int j = 0; j < 8; ++j) {
            s0[j] = ((const float*)node)[nb + kq + j];
            s1[j] = ((const float*)node)[nb + 32 + kq + j];
        }
    }
    float sum = 0.f;
    #pragma unroll
    for (int j = 0; j < 8; ++j) sum += s0[j] + s1[j];
    sum += __shfl_xor(sum, 16); sum += __shfl_xor(sum, 32);
    float mu = sum * (1.f / 64.f);
    float d2 = 0.f;
    #pragma unroll
    for (int j = 0; j < 8; ++j) {
        float a = s0[j] - mu, b = s1[j] - mu;
        d2 += a * a + b * b;
    }
    d2 += __shfl_xor(d2, 16); d2 += __shfl_xor(d2, 32);
    float inv = rsqrtf(d2 * (1.f / 64.f) + EPSN);
    bfv8 as0, as1;
    #pragma unroll
    for (int j = 0; j < 8; ++j) {
        as0[j] = (__bf16)((s0[j] - mu) * inv * ldf<BF>(gs, kq + j) + ldf<BF>(bs, kq + j));
        as1[j] = (__bf16)((s1[j] - mu) * inv * ldf<BF>(gs, 32 + kq + j) + ldf<BF>(bs, 32 + kq + j));
    }

    // ---- v: 24 values (cv = kq..kq+7, x = 0..2, interleaved stride 3) ----
    float raw[24];
    if (BF) {
        bfv8 r0 = *(const bfv8*)((const __bf16*)node + nb + 64 + 24 * q);
        bfv8 r1 = *(const bfv8*)((const __bf16*)node + nb + 64 + 24 * q + 8);
        bfv8 r2 = *(const bfv8*)((const __bf16*)node + nb + 64 + 24 * q + 16);
        #pragma unroll
        for (int j = 0; j < 8; ++j) {
            raw[j] = (float)r0[j]; raw[8 + j] = (float)r1[j]; raw[16 + j] = (float)r2[j];
        }
    } else {
        #pragma unroll
        for (int j = 0; j < 24; ++j) raw[j] = ((const float*)node)[nb + 64 + 24 * q + j];
    }
    float q2 = 0.f;
    #pragma unroll
    for (int j = 0; j < 24; ++j) q2 += raw[j] * raw[j];
    q2 += __shfl_xor(q2, 16); q2 += __shfl_xor(q2, 32);
    float invv = rsqrtf(q2 * (1.f / 32.f) + EPSN);
    bfv8 av0, av1, av2;
    #pragma unroll
    for (int j = 0; j < 8; ++j) {
        float g = ldf<BF>(gv, kq + j) * invv;
        av0[j] = (__bf16)(raw[3 * j + 0] * g);
        av1[j] = (__bf16)(raw[3 * j + 1] * g);
        av2[j] = (__bf16)(raw[3 * j + 2] * g);
    }

    // ---- v projections: 2 matrices x (2 nt x 3 x) MFMAs, packed stores ----
    #pragma unroll
    for (int mat = 0; mat < 2; ++mat) {
        const bf16* WT = mat ? WvdT : WvsT;
        bf16* A_ = mat ? vdstA : vsrcA;
        bf16* B_ = mat ? vdstB : vsrcB;
        f4 dv[3][2];
        #pragma unroll
        for (int nt = 0; nt < 2; ++nt) {
            bfv8 b = *(const bfv8*)((const __bf16*)WT + (nt * 16 + m) * 32 + kq);
            f4 z = {0.f, 0.f, 0.f, 0.f};
            dv[0][nt] = mf(av0, b, z);
            dv[1][nt] = mf(av1, b, z);
            dv[2][nt] = mf(av2, b, z);
        }
        #pragma unroll
        for (int rr = 0; rr < 4; ++rr) {
            int nr = n0 + q * 4 + rr;
            if (nr < N) {
                bfv4 pa;
                pa[0] = (__bf16)dv[0][0][rr]; pa[1] = (__bf16)dv[0][1][rr];
                pa[2] = (__bf16)dv[1][0][rr]; pa[3] = (__bf16)dv[1][1][rr];
                *(bfv4*)((__bf16*)A_ + (size_t)nr * 64 + m * 4) = pa;
                bfv2 pb;
                pb[0] = (__bf16)dv[2][0][rr]; pb[1] = (__bf16)dv[2][1][rr];
                *(bfv2*)((__bf16*)B_ + (size_t)nr * 32 + m * 2) = pb;
            }
        }
    }

    // ---- s projections: 2 matrices x 4 nt x 2 kt MFMAs, packed stores ----
    #pragma unroll
    for (int mat = 0; mat < 2; ++mat) {
        const bf16* WT = mat ? WsdT : WssT;
        bf16* S_ = mat ? sdst : ssrc;
        f4 ds_[4];
        #pragma unroll
        for (int nt = 0; nt < 4; ++nt) {
            bfv8 b0 = *(const bfv8*)((const __bf16*)WT + (nt * 16 + m) * 64 + kq);
            bfv8 b1 = *(const bfv8*)((const __bf16*)WT + (nt * 16 + m) * 64 + 32 + kq);
            f4 acc = {0.f, 0.f, 0.f, 0.f};
            acc = mf(as0, b0, acc);
            acc = mf(as1, b1, acc);
            ds_[nt] = acc;
        }
        #pragma unroll
        for (int rr = 0; rr < 4; ++rr) {
            int nr = n0 + q * 4 + rr;
            if (nr < N) {
                bfv4 pa;
                pa[0] = (__bf16)ds_[0][rr]; pa[1] = (__bf16)ds_[1][rr];
                pa[2] = (__bf16)ds_[2][rr]; pa[3] = (__bf16)ds_[3][rr];
                *(bfv4*)((__bf16*)S_ + (size_t)nr * 64 + m * 4) = pa;
            }
        }
    }
}

// ---------------- k_permnode: perm scatter + node MFMA (merged launch) ----------------
__global__ __launch_bounds__(256) void k_permnode(
    const void* eidx, int* cnt, int* perm,
    const void* node, const void* gs, const void* bs, const void* gv,
    const bf16* WssT, const bf16* WsdT, const bf16* WvsT, const bf16* WvdT,
    bf16* ssrc, bf16* sdst, bf16* vsrcA, bf16* vdstA, bf16* vsrcB, bf16* vdstB,
    const int* flags, int E, int N, int nbe)
{
    if ((int)blockIdx.x >= nbe) {
        int wv = threadIdx.x >> 6, l = threadIdx.x & 63;
        int q = l >> 4, m = l & 15;
        int n0 = (blockIdx.x - nbe) * 64 + wv * 16;
        if (n0 >= N) return;
        if (flags[0])
            node_mfma<1>(node, gs, bs, gv, WssT, WsdT, WvsT, WvdT,
                         ssrc, sdst, vsrcA, vdstA, vsrcB, vdstB, n0, q, m, N);
        else
            node_mfma<0>(node, gs, bs, gv, WssT, WsdT, WvsT, WvdT,
                         ssrc, sdst, vsrcA, vdstA, vsrcB, vdstB, n0, q, m, N);
        return;
    }
    int e = blockIdx.x * 256 + threadIdx.x;
    if (e >= E) return;
    int d = flags[1] ? (int)((const long long*)eidx)[(long long)E + e]
                     : ((const int*)eidx)[(size_t)E + e];
    int pos = atomicAdd(&cnt[d], 1);
    perm[pos] = e;
}

// ---------------- Kernel 2: fused MFMA edge pass over dst-sorted edges ----------------
// (unchanged from R6 -- proven 210 us)
static constexpr int SS  = 104;
static constexpr int A1S = 0;
static constexpr int SV  = 136;
static constexpr int P0  = 16 * SS;           // 1664
static constexpr int VAL = 0;                 // alias of A1S region
static constexpr int SA  = 72;
static constexpr int HSZ = P0 + 16 * SV;      // 3840 elems = 7,680 B

#define W_M1(X, PB) do { \
    constexpr int x_ = (X), x1_ = ((X)+1)%3, x2_ = ((X)+2)%3; \
    _Pragma("unroll") \
    for (int r = 0; r < 4; ++r) { \
        int e = q * 4 + r; \
        float4 yy = *(const float4*)&sY[wv][e][0]; \
        float y0 = yy.x; float yv[3] = {yy.y, yy.z, yy.w}; \
        _Pragma("unroll") \
        for (int nt = 0; nt < 4; ++nt) \
            H[(PB) + e * SV + nt * 16 + m] = (__bf16)(sv_[r][nt] * yv[x_]); \
        _Pragma("unroll") \
        for (int n2 = 0; n2 < 2; ++n2) { \
            int c = 64 + n2 * 16 + m; \
            H[(PB) + e * SV + c] = (__bf16)(qv_[r][n2][x_] * y0); \
            float cr = pv_[r][n2][x1_] * yv[x2_] - pv_[r][n2][x2_] * yv[x1_]; \
            H[(PB) + e * SV + 32 + c] = (__bf16)(cr * SQRT2_INV); \
        } \
    } \
} while (0)

#define W_M2(X, PB) do { \
    constexpr int x_ = (X), x1_ = ((X)+1)%3, x2_ = ((X)+2)%3; \
    _Pragma("unroll") \
    for (int r = 0; r < 4; ++r) { \
        int e = q * 4 + r; \
        float4 yy = *(const float4*)&sY[wv][e][0]; \
        float y0 = yy.x; float yv[3] = {yy.y, yy.z, yy.w}; \
        _Pragma("unroll") \
        for (int nt = 0; nt < 4; ++nt) \
            H[(PB) + e * SV + nt * 16 + m] = (__bf16)(c2sv[nt] * vals[nt][r] * yv[x_]); \
        _Pragma("unroll") \
        for (int n2 = 0; n2 < 2; ++n2) { \
            int c = 64 + n2 * 16 + m; \
            H[(PB) + e * SV + c] = (__bf16)(c2vs[n2] * vv[x_][n2][r] * y0); \
            float cr = vv[x1_][n2][r] * yv[x2_] - vv[x2_][n2][r] * yv[x1_]; \
            H[(PB) + e * SV + 32 + c] = (__bf16)(c2v1[n2] * cr * SQRT2_INV); \
        } \
    } \
} while (0)

#define MMA_H(PB, WH, O0, O1) do { \
    bfv8 fg_[4]; \
    _Pragma("unroll") \
    for (int kt = 0; kt < 4; ++kt) \
        fg_[kt] = *(const bfv8*)(H + (PB) + m * SV + kt * 32 + kq); \
    _Pragma("unroll") \
    for (int kt = 0; kt < 4; ++kt) { \
        O0 = mf(fg_[kt], WH[kt],     O0); \
        O1 = mf(fg_[kt], WH[4 + kt], O1); \
    } \
} while (0)

__global__ __launch_bounds__(256, 3) void k_edge(
    const void* __restrict__ eidx, const void* __restrict__ rbf, const void* __restrict__ rsh,
    const bf16* __restrict__ WalphaT, const bf16* __restrict__ WsvalT, const bf16* __restrict__ WsvlinT,
    const bf16* __restrict__ WvvalT, const bf16* __restrict__ WvvlinT, const bf16* __restrict__ WgT,
    const bf16* __restrict__ WrbfT, const bf16* __restrict__ adotB, const bf16* __restrict__ w2B,
    const bf16* __restrict__ ssrc, const bf16* __restrict__ sdst,
    const bf16* __restrict__ vsrcA, const bf16* __restrict__ vdstA,
    const bf16* __restrict__ vsrcB, const bf16* __restrict__ vdstB,
    const int* __restrict__ perm,
    float* __restrict__ den, float* __restrict__ agg,
    const int* __restrict__ flags, int E)
{
    const int bfm = flags[0];
    const int i64 = flags[1];

    __shared__ __align__(16) __bf16 sH[4][HSZ];
    __shared__ __align__(16) float sY[4][16][4];
    __shared__ int sSD[4][48];

    int wv = threadIdx.x >> 6, l = threadIdx.x & 63;
    int q = l >> 4, m = l & 15;
    const int kq = q * 8;

    int bid;
    {
        int nwg = gridDim.x, orig = blockIdx.x;
        int qq_ = nwg >> 3, rr_ = nwg & 7;
        int xcd = orig & 7, off = orig >> 3;
        bid = (xcd < rr_ ? xcd * (qq_ + 1) : rr_ * (qq_ + 1) + (xcd - rr_) * qq_) + off;
    }
    long long eb = ((long long)bid * 4 + wv) * 16;
    if (eb >= E) return;
    __bf16* H = &sH[wv][0];

    if (l < 16) {
        long long p = eb + l; if (p > (long long)E - 1) p = E - 1;
        sSD[wv][32 + l] = perm[p];
    }
    if (l < 32) {
        int pe = sSD[wv][32 + (l & 15)];
        long long off = (l < 16) ? (long long)pe : ((long long)E + pe);
        sSD[wv][l] = i64 ? (int)((const long long*)eidx)[off] : ((const int*)eidx)[off];
    }
    {
        int pe = sSD[wv][32 + (l >> 2)];
        sY[wv][l >> 2][l & 3] = ldr(rsh, (size_t)pe * 4 + (l & 3), bfm);
    }

    f4 w1f[14];
    {
        bfv8 arb;
        #pragma unroll
        for (int i = 0; i < 8; ++i) arb[i] = (__bf16)0.f;
        if (q < 2) {
            int pe = sSD[wv][32 + m];
            if (bfm) {
                arb = *(const bfv8*)((const __bf16*)rbf + (size_t)pe * 16 + kq);
            } else {
                const float* rp = (const float*)rbf + (size_t)pe * 16 + kq;
                #pragma unroll
                for (int i = 0; i < 8; ++i) arb[i] = (__bf16)rp[i];
            }
        }
        const __bf16* wb = (const __bf16*)WrbfT;
        #pragma unroll
        for (int nt = 0; nt < 14; ++nt) {
            bfv8 bb = *(const bfv8*)(wb + (size_t)(nt * 16 + m) * 32 + kq);
            f4 z = {0.f, 0.f, 0.f, 0.f};
            w1f[nt] = mf(arb, bb, z);
        }
    }

    bfv4 gs_[4], gd_[4], gvA[4], gwA[4];
    bfv2 gvB[4], gwB[4];
    #pragma unroll
    for (int r = 0; r < 4; ++r) {
        int e = q * 4 + r;
        int s = sSD[wv][e], d = sSD[wv][16 + e];
        gs_[r] = *(const bfv4*)((const __bf16*)ssrc  + (size_t)s * 64 + m * 4);
        gd_[r] = *(const bfv4*)((const __bf16*)sdst  + (size_t)d * 64 + m * 4);
        gvA[r] = *(const bfv4*)((const __bf16*)vsrcA + (size_t)s * 64 + m * 4);
        gwA[r] = *(const bfv4*)((const __bf16*)vdstA + (size_t)d * 64 + m * 4);
        gvB[r] = *(const bfv2*)((const __bf16*)vsrcB + (size_t)s * 32 + m * 2);
        gwB[r] = *(const bfv2*)((const __bf16*)vdstB + (size_t)d * 32 + m * 2);
    }
    float ms_[4][4], mv_[4][2][3];
    #pragma unroll
    for (int r = 0; r < 4; ++r) {
        #pragma unroll
        for (int nt = 0; nt < 4; ++nt)
            ms_[r][nt] = (float)gs_[r][nt] + (float)gd_[r][nt];
        #pragma unroll
        for (int n2 = 0; n2 < 2; ++n2) {
            mv_[r][n2][0] = (float)gvA[r][0 * 2 + n2] + (float)gwA[r][0 * 2 + n2];
            mv_[r][n2][1] = (float)gvA[r][1 * 2 + n2] + (float)gwA[r][1 * 2 + n2];
            mv_[r][n2][2] = (float)gvB[r][n2]         + (float)gwB[r][n2];
        }
    }

    float sv_[4][4], qv_[4][2][3], pv_[4][2][3];
    #pragma unroll
    for (int r = 0; r < 4; ++r) {
        int e = q * 4 + r;
        float4 yy = *(const float4*)&sY[wv][e][0];
        float y0 = yy.x, yx = yy.y, yh = yy.z, yz = yy.w;
        #pragma unroll
        for (int nt = 0; nt < 4; ++nt) {
            H[A1S + e * SS + nt * 16 + m] = (__bf16)(w1f[nt][r] * ms_[r][nt] * y0);
            sv_[r][nt] = w1f[4 + nt][r] * ms_[r][nt];
        }
        #pragma unroll
        for (int n2 = 0; n2 < 2; ++n2) {
            float dot = mv_[r][n2][0] * yx + mv_[r][n2][1] * yh + mv_[r][n2][2] * yz;
            H[A1S + e * SS + 64 + n2 * 16 + m] = (__bf16)(w1f[10 + n2][r] * dot * SQRT3_INV);
            #pragma unroll
            for (int x = 0; x < 3; ++x) {
                qv_[r][n2][x] = w1f[8 + n2][r]  * mv_[r][n2][x];
                pv_[r][n2][x] = w1f[12 + n2][r] * mv_[r][n2][x];
            }
        }
    }

    bfv8 a1s0 = *(const bfv8*)(H + A1S + m * SS + 0  + kq);
    bfv8 a1s1 = *(const bfv8*)(H + A1S + m * SS + 32 + kq);
    bfv8 a1s2 = *(const bfv8*)(H + A1S + m * SS + 64 + kq);

    f4 vals[4];
    #pragma unroll
    for (int nt = 0; nt < 4; ++nt) {
        const __bf16* bp = (const __bf16*)WsvalT + (size_t)(nt * 16 + m) * 96 + kq;
        f4 acc = {0.f, 0.f, 0.f, 0.f};
        acc = mf(a1s0, *(const bfv8*)(bp),      acc);
        acc = mf(a1s1, *(const bfv8*)(bp + 32), acc);
        acc = mf(a1s2, *(const bfv8*)(bp + 64), acc);
        vals[nt] = acc;
    }
    #pragma unroll
    for (int nt = 0; nt < 4; ++nt)
        #pragma unroll
        for (int r = 0; r < 4; ++r) {
            float v = vals[nt][r];
            H[VAL + (q * 4 + r) * SA + nt * 16 + m] = (__bf16)v;   // PRE-sigmoid
            vals[nt][r] = 1.f / (1.f + __expf(-v));
        }

    f4 gate[2];
    {
        bfv8 av0 = *(const bfv8*)(H + VAL + m * SA + 0  + kq);
        bfv8 av1 = *(const bfv8*)(H + VAL + m * SA + 32 + kq);
        #pragma unroll
        for (int nt = 0; nt < 2; ++nt) {
            const __bf16* bp = (const __bf16*)WgT + (size_t)(nt * 16 + m) * 64 + kq;
            f4 acc = {0.f, 0.f, 0.f, 0.f};
            acc = mf(av0, *(const bfv8*)(bp),      acc);
            acc = mf(av1, *(const bfv8*)(bp + 32), acc);
            gate[nt] = acc;
        }
        #pragma unroll
        for (int nt = 0; nt < 2; ++nt)
            #pragma unroll
            for (int r = 0; r < 4; ++r)
                gate[nt][r] = 1.f / (1.f + __expf(-gate[nt][r]));
    }

    float ex_[4][4];
    #pragma unroll
    for (int nt = 0; nt < 4; ++nt) {
        const __bf16* bp = (const __bf16*)WalphaT + (size_t)(nt * 16 + m) * 96 + kq;
        f4 acc = {0.f, 0.f, 0.f, 0.f};
        acc = mf(a1s0, *(const bfv8*)(bp),      acc);
        acc = mf(a1s1, *(const bfv8*)(bp + 32), acc);
        acc = mf(a1s2, *(const bfv8*)(bp + 64), acc);
        float ad = b2f(adotB[nt * 16 + m]);
        #pragma unroll
        for (int r = 0; r < 4; ++r) {
            float tv = acc[r];
            tv = tv > 0.f ? tv : 0.2f * tv;
            tv *= ad;
            tv += __shfl_xor(tv, 1); tv += __shfl_xor(tv, 2);
            tv += __shfl_xor(tv, 4); tv += __shfl_xor(tv, 8);
            tv = fminf(fmaxf(tv, -60.f), 60.f);
            ex_[nt][r] = __expf(tv);
        }
    }

    f4 vv[3][2];
    #pragma unroll
    for (int x = 0; x < 3; ++x)
        #pragma unroll
        for (int nt = 0; nt < 2; ++nt)
            vv[x][nt] = (f4){0.f, 0.f, 0.f, 0.f};
    {
        bfv8 wh[8];
        #pragma unroll
        for (int nt = 0; nt < 2; ++nt)
            #pragma unroll
            for (int kt = 0; kt < 4; ++kt)
                wh[nt * 4 + kt] = *(const bfv8*)((const __bf16*)WvvalT
                                   + (size_t)(nt * 16 + m) * 128 + kt * 32 + kq);
        W_M1(0, P0);
        MMA_H(P0, wh, vv[0][0], vv[0][1]);
        W_M1(1, P0);
        MMA_H(P0, wh, vv[1][0], vv[1][1]);
        W_M1(2, P0);
        MMA_H(P0, wh, vv[2][0], vv[2][1]);
    }
    #pragma unroll
    for (int x = 0; x < 3; ++x)
        #pragma unroll
        for (int nt = 0; nt < 2; ++nt)
            #pragma unroll
            for (int r = 0; r < 4; ++r)
                vv[x][nt][r] *= gate[nt][r];

    float c2ss[4], c2sv[4];
    #pragma unroll
    for (int nt = 0; nt < 4; ++nt) {
        c2ss[nt] = b2f(w2B[nt * 16 + m]);
        c2sv[nt] = b2f(w2B[64 + nt * 16 + m]);
    }
    float c2vs[2], c2v0[2], c2v1[2];
    #pragma unroll
    for (int nt = 0; nt < 2; ++nt) {
        c2vs[nt] = b2f(w2B[128 + nt * 16 + m]);
        c2v0[nt] = b2f(w2B[160 + nt * 16 + m]);
        c2v1[nt] = b2f(w2B[192 + nt * 16 + m]);
    }
    #pragma unroll
    for (int r = 0; r < 4; ++r) {
        int e = q * 4 + r;
        float4 yy = *(const float4*)&sY[wv][e][0];
        float y0 = yy.x, yx = yy.y, yh = yy.z, yz = yy.w;
        #pragma unroll
        for (int nt = 0; nt < 4; ++nt)
            H[A1S + e * SS + nt * 16 + m] = (__bf16)(c2ss[nt] * vals[nt][r] * y0);
        #pragma unroll
        for (int n2 = 0; n2 < 2; ++n2) {
            float dotv = vv[0][n2][r] * yx + vv[1][n2][r] * yh + vv[2][n2][r] * yz;
            H[A1S + e * SS + 64 + n2 * 16 + m] = (__bf16)(c2v0[n2] * dotv * SQRT3_INV);
        }
    }
    f4 hs[4];
    {
        bfv8 a2s0 = *(const bfv8*)(H + A1S + m * SS + 0  + kq);
        bfv8 a2s1 = *(const bfv8*)(H + A1S + m * SS + 32 + kq);
        bfv8 a2s2 = *(const bfv8*)(H + A1S + m * SS + 64 + kq);
        #pragma unroll
        for (int nt = 0; nt < 4; ++nt) {
            const __bf16* bp = (const __bf16*)WsvlinT + (size_t)(nt * 16 + m) * 96 + kq;
            f4 acc = {0.f, 0.f, 0.f, 0.f};
            acc = mf(a2s0, *(const bfv8*)(bp),      acc);
            acc = mf(a2s1, *(const bfv8*)(bp + 32), acc);
            acc = mf(a2s2, *(const bfv8*)(bp + 64), acc);
            hs[nt] = acc;
        }
    }

    f4 hv[3][2];
    #pragma unroll
    for (int x = 0; x < 3; ++x)
        #pragma unroll
        for (int nt = 0; nt < 2; ++nt)
            hv[x][nt] = (f4){0.f, 0.f, 0.f, 0.f};
    {
        bfv8 wh[8];
        #pragma unroll
        for (int nt = 0; nt < 2; ++nt)
            #pragma unroll
            for (int kt = 0; kt < 4; ++kt)
                wh[nt * 4 + kt] = *(const bfv8*)((const __bf16*)WvvlinT
                                   + (size_t)(nt * 16 + m) * 128 + kt * 32 + kq);
        W_M2(0, P0);
        MMA_H(P0, wh, hv[0][0], hv[0][1]);
        W_M2(1, P0);
        MMA_H(P0, wh, hv[1][0], hv[1][1]);
        W_M2(2, P0);
        MMA_H(P0, wh, hv[2][0], hv[2][1]);
    }

    {
        float* Hf = (float*)H;
        int nval = (int)((E - eb) < 16 ? (E - eb) : 16);
        #pragma unroll
        for (int half = 0; half < 2; ++half) {
            if ((q >> 1) == half) {
                #pragma unroll
                for (int r = 0; r < 4; ++r) {
                    int er = (q & 1) * 4 + r;
                    float* row = Hf + er * 168;
                    #pragma unroll
                    for (int nt = 0; nt < 4; ++nt)
                        row[nt * 40 + m] = ex_[nt][r] * hs[nt][r];
                    #pragma unroll
                    for (int nt = 0; nt < 2; ++nt) {
                        int c = nt * 16 + m;
                        int hh = c >> 3, dd = c & 7;
                        float exv = (m >= 8) ? ex_[2 * nt + 1][r] : ex_[2 * nt][r];
                        float* vb = row + hh * 40 + 16 + dd * 3;
                        vb[0] = exv * hv[0][nt][r];
                        vb[1] = exv * hv[1][nt][r];
                        vb[2] = exv * hv[2][nt][r];
                    }
                    if (m < 4) row[160 + m] = ex_[m][r];
                }
            }
            int lo = half * 8;
            int hi = nval < lo + 8 ? nval : lo + 8;
            int s = lo;
            while (s < hi) {
                int d = sSD[wv][16 + s];
                int t2 = s + 1;
                while (t2 < hi && sSD[wv][16 + t2] == d) ++t2;
                float s0 = 0.f, s1 = 0.f, s2 = 0.f;
                for (int e = s; e < t2; ++e) {
                    const float* row = Hf + (e - lo) * 168;
                    s0 += row[l];
                    s1 += row[64 + l];
                    if (l < 36) s2 += row[128 + l];
                }
                float* rowp = agg + (size_t)d * 160;
                unsafeAtomicAdd(rowp + l, s0);
                unsafeAtomicAdd(rowp + 64 + l, s1);
                if (l < 32)      unsafeAtomicAdd(rowp + 128 + l, s2);
                else if (l < 36) unsafeAtomicAdd(den + (size_t)d * 4 + (l - 32), s2);
                s = t2;
            }
        }
    }
}

// ---------------- Kernel 3: k_out via MFMA (16 nodes/wave) ----------------
// agg channel layout per node: s: c=h*16+i at h*40+i; v: cv=h*8+dd, x at h*40+16+dd*3+x.
// Lane(q,m): s ktile0 c=8q+j -> h=q>>1, contiguous 8 floats; ktile1 c=32+8q+j -> h=2+(q>>1);
// v cv=8q+j -> h=q, 24 contiguous floats at q*40+16.
template<int BF>
__device__ __forceinline__ void out_mfma(
    const void* node, const float* den, const float* agg,
    const bf16* WpsT, const bf16* WpvT, void* out,
    int n0, int q, int m, int N)
{
    int nm = n0 + m; if (nm > N - 1) nm = N - 1;
    size_t ab = (size_t)nm * 160;
    const int kq = q * 8;

    float i0 = 1.f / (den[(size_t)nm * 4 + (q >> 1)] + 1e-16f);
    float i1 = 1.f / (den[(size_t)nm * 4 + 2 + (q >> 1)] + 1e-16f);
    float iv = 1.f / (den[(size_t)nm * 4 + q] + 1e-16f);

    bfv8 as0, as1;
    {
        const float* p0 = agg + ab + (q >> 1) * 40 + 8 * (q & 1);
        const float* p1 = agg + ab + (2 + (q >> 1)) * 40 + 8 * (q & 1);
        #pragma unroll
        for (int j = 0; j < 8; ++j) {
            as0[j] = (__bf16)(p0[j] * i0);
            as1[j] = (__bf16)(p1[j] * i1);
        }
    }
    bfv8 av0, av1, av2;
    {
        const float* pv = agg + ab + q * 40 + 16;
        float raw[24];
        #pragma unroll
        for (int j = 0; j < 24; ++j) raw[j] = pv[j];
        #pragma unroll
        for (int j = 0; j < 8; ++j) {
            av0[j] = (__bf16)(raw[3 * j + 0] * iv);
            av1[j] = (__bf16)(raw[3 * j + 1] * iv);
            av2[j] = (__bf16)(raw[3 * j + 2] * iv);
        }
    }

    f4 ds_[4];
    #pragma unroll
    for (int nt = 0; nt < 4; ++nt) {
        bfv8 b0 = *(const bfv8*)((const __bf16*)WpsT + (nt * 16 + m) * 64 + kq);
        bfv8 b1 = *(const bfv8*)((const __bf16*)WpsT + (nt * 16 + m) * 64 + 32 + kq);
        f4 acc = {0.f, 0.f, 0.f, 0.f};
        acc = mf(as0, b0, acc);
        acc = mf(as1, b1, acc);
        ds_[nt] = acc;
    }
    f4 dv[3][2];
    #pragma unroll
    for (int nt = 0; nt < 2; ++nt) {
        bfv8 b = *(const bfv8*)((const __bf16*)WpvT + (nt * 16 + m) * 32 + kq);
        f4 z = {0.f, 0.f, 0.f, 0.f};
        dv[0][nt] = mf(av0, b, z);
        dv[1][nt] = mf(av1, b, z);
        dv[2][nt] = mf(av2, b, z);
    }

    #pragma unroll
    for (int rr = 0; rr < 4; ++rr) {
        int nr = n0 + q * 4 + rr;
        if (nr >= N) continue;
        size_t ob = (size_t)nr * 160;
        #pragma unroll
        for (int nt = 0; nt < 4; ++nt) {
            int c = nt * 16 + m;
            stf<BF>(out, ob + c, ldf<BF>(node, ob + c) + ds_[nt][rr]);
        }
        #pragma unroll
        for (int nt = 0; nt < 2; ++nt) {
            int cv = nt * 16 + m;
            #pragma unroll
            for (int x = 0; x < 3; ++x) {
                int c = 64 + cv * 3 + x;
                stf<BF>(out, ob + c, ldf<BF>(node, ob + c) + dv[x][nt][rr]);
            }
        }
    }
}

__global__ __launch_bounds__(256) void k_out(
    const void* node, const float* den, const float* agg,
    const bf16* WpsT, const bf16* WpvT, void* out,
    const int* flags, int N)
{
    int wv = threadIdx.x >> 6, l = threadIdx.x & 63;
    int q = l >> 4, m = l & 15;
    int n0 = blockIdx.x * 64 + wv * 16;
    if (n0 >= N) return;
    if (flags[0])
        out_mfma<1>(node, den, agg, WpsT, WpvT, out, n0, q, m, N);
    else
        out_mfma<0>(node, den, agg, WpsT, WpvT, out, n0, q, m, N);
}

// ---------------- Launch ----------------
extern "C" void kernel_launch(void* const* d_in, const int* in_sizes, int n_in,
                              void* d_out, int out_size, void* d_ws, size_t ws_size,
                              hipStream_t stream)
{
    const void* node   = d_in[0];
    const void* eidx   = d_in[1];
    const void* rbf    = d_in[2];
    const void* rsh    = d_in[3];
    const void* gs     = d_in[4];
    const void* bs     = d_in[5];
    const void* gv     = d_in[6];
    const void* Wss    = d_in[7];
    const void* Wvs    = d_in[8];
    const void* Wsd    = d_in[9];
    const void* Wvd    = d_in[10];
    const void* Wrbf   = d_in[11];
    const void* Walpha = d_in[12];
    const void* adot   = d_in[13];
    const void* Wsval  = d_in[14];
    const void* Wvval  = d_in[15];
    const void* Wg     = d_in[16];
    const void* w2ss   = d_in[17];
    const void* w2sv   = d_in[18];
    const void* w2vs   = d_in[19];
    const void* w2vv0  = d_in[20];
    const void* w2vv1  = d_in[21];
    const void* Wsvlin = d_in[22];
    const void* Wvvlin = d_in[23];
    const void* Wps    = d_in[24];
    const void* Wpv    = d_in[25];

    int N = in_sizes[0] / 160;
    int E = in_sizes[1] / 2;

    char* base = (char*)d_ws;
    int*  flags   = (int*)base;                  // 16 B
    bf16* WalphaT = (bf16*)(base + 16);
    bf16* WsvalT  = WalphaT + 6144;
    bf16* WsvlinT = WsvalT  + 6144;
    bf16* WvvalT  = WsvlinT + 6144;
    bf16* WvvlinT = WvvalT  + 4096;
    bf16* WgT     = WvvlinT + 4096;
    bf16* WrbfT   = WgT     + 2048;
    bf16* adotB   = WrbfT   + 7168;              // 224 x 32 zero-padded
    bf16* w2B     = adotB   + 64;
    bf16* WssT    = w2B     + 224;
    bf16* WsdT    = WssT    + 4096;
    bf16* WvsT    = WsdT    + 4096;
    bf16* WvdT    = WvsT    + 1024;
    bf16* WpsT    = WvdT    + 1024;
    bf16* WpvT    = WpsT    + 4096;
    bf16* ssrc    = WpvT    + 1024;
    bf16* sdst    = ssrc  + (size_t)N * 64;
    bf16* vsrcA   = sdst  + (size_t)N * 64;      // packed v: x in {0,1}
    bf16* vdstA   = vsrcA + (size_t)N * 64;
    bf16* vsrcB   = vdstA + (size_t)N * 64;      // packed v: x == 2
    bf16* vdstB   = vsrcB + (size_t)N * 32;
    float* den    = (float*)(vdstB + (size_t)N * 32);
    float* agg    = den + (size_t)N * 4;
    int*  cnt     = (int*)(agg + (size_t)N * 160);
    int*  perm    = cnt + N;

    // 1) sniff + zero den(4N)+agg(160N)+cnt(N)
    int zn = N * 165;
    k_sniff_zero<<<(zn + 255) / 256, 256, 0, stream>>>(node, eidx, flags, den, zn);

    // 2) edge histogram + weight prep (merged)
    int nbe = (E + 255) / 256;
    k_histprep<<<nbe + 16, 256, 0, stream>>>(eidx, cnt,
        Walpha, Wsval, Wsvlin, Wvval, Wvvlin, Wg, Wrbf, adot,
        w2ss, w2sv, w2vs, w2vv0, w2vv1, Wss, Wsd, Wvs, Wvd, Wps, Wpv,
        WalphaT, WsvalT, WsvlinT, WvvalT, WvvlinT, WgT, WrbfT, adotB, w2B,
        WssT, WsdT, WvsT, WvdT, WpsT, WpvT, flags, E, nbe);

    // 3) scan
    k_scan<<<1, 1024, 0, stream>>>(cnt, N);

    // 4) perm scatter + node MFMA (merged)
    int nbn64 = (N + 63) / 64;
    k_permnode<<<nbe + nbn64, 256, 0, stream>>>(eidx, cnt, perm,
        node, gs, bs, gv, WssT, WsdT, WvsT, WvdT,
        ssrc, sdst, vsrcA, vdstA, vsrcB, vdstB, flags, E, N, nbe);

    // 5) fused edge pass (unchanged R6)
    int nb = (E + 63) / 64;
    k_edge<<<nb, 256, 0, stream>>>(eidx, rbf, rsh,
                                   WalphaT, WsvalT, WsvlinT, WvvalT, WvvlinT, WgT, WrbfT,
                                   adotB, w2B, ssrc, sdst, vsrcA, vdstA, vsrcB, vdstB,
                                   perm, den, agg, flags, E);

    // 6) output projection via MFMA
    k_out<<<nbn64, 256, 0, stream>>>(node, den, agg, WpsT, WpvT, d_out, flags, N);
}